// Round 1
// baseline (451.003 us; speedup 1.0000x reference)
//
#include <hip/hip_runtime.h>

// ---------------- problem constants (match reference) ----------------
constexpr int F_IN = 256;
constexpr int H1 = 4, D1 = 32, F1 = H1 * D1;   // 128
constexpr int H2 = 1, D2 = 32, F2 = H2 * D2;   // 32
constexpr float NEG = 0.2f;

// ---------------- CSR build ----------------
__global__ void hist_kernel(const int* __restrict__ dst, int* __restrict__ deg, int E) {
    int e = blockIdx.x * 256 + threadIdx.x;
    if (e < E) atomicAdd(&deg[dst[e]], 1);
}

// single block, 1024 threads: exclusive scan of deg[0..n) -> off[0..n]
__global__ void scan_kernel(const int* __restrict__ deg, int* __restrict__ off, int n) {
    __shared__ int sums[1024];
    int tid = threadIdx.x;
    int chunk = (n + 1023) / 1024;
    int start = tid * chunk;
    int end = min(start + chunk, n);
    int local = 0;
    for (int i = start; i < end; ++i) local += deg[i];
    sums[tid] = local;
    __syncthreads();
    for (int o = 1; o < 1024; o <<= 1) {
        int v = (tid >= o) ? sums[tid - o] : 0;
        __syncthreads();
        sums[tid] += v;
        __syncthreads();
    }
    int run = sums[tid] - local;           // exclusive prefix
    for (int i = start; i < end; ++i) { off[i] = run; run += deg[i]; }
    if (tid == 0) off[n] = sums[1023];
}

__global__ void scatter_kernel(const int* __restrict__ src, const int* __restrict__ dst,
                               const int* __restrict__ off, int* __restrict__ pos,
                               int* __restrict__ csr_src, int E) {
    int e = blockIdx.x * 256 + threadIdx.x;
    if (e < E) {
        int d = dst[e];
        int p = off[d] + atomicAdd(&pos[d], 1);
        csr_src[p] = src[e];
    }
}

// ---------------- GEMM (feat = X @ W) fused with el/er = per-head dots ----------------
// block = 256 threads; each block does RB rows; each thread CPT consecutive cols of one row.
template <int IN, int OUT, int H, int CPT, int RB, int KT>
__global__ __launch_bounds__(256) void gemm_elr(
    const float* __restrict__ X, const float* __restrict__ W,
    const float* __restrict__ al, const float* __restrict__ ar,
    float* __restrict__ feat, float* __restrict__ el, float* __restrict__ er, int n)
{
    constexpr int TPR = OUT / CPT;       // threads per row
    static_assert(RB * TPR == 256, "block mapping");
    __shared__ float Ws[KT][OUT];
    __shared__ float xs[RB][KT + 1];

    int tid = threadIdx.x;
    int row0 = blockIdx.x * RB;
    int r = tid / TPR;
    int cseg = tid % TPR;
    int c0 = cseg * CPT;

    float acc[CPT];
#pragma unroll
    for (int j = 0; j < CPT; ++j) acc[j] = 0.f;

    for (int k0 = 0; k0 < IN; k0 += KT) {
        __syncthreads();
        for (int i = tid; i < KT * OUT; i += 256) {
            int kk = i / OUT, c = i % OUT;
            Ws[kk][c] = W[(size_t)(k0 + kk) * OUT + c];
        }
        for (int i = tid; i < RB * KT; i += 256) {
            int rr = i / KT, kk = i % KT;
            int row = row0 + rr;
            xs[rr][kk] = (row < n) ? X[(size_t)row * IN + k0 + kk] : 0.f;
        }
        __syncthreads();
#pragma unroll 16
        for (int kk = 0; kk < KT; ++kk) {
            float xv = xs[r][kk];
            const float* wr = &Ws[kk][c0];
#pragma unroll
            for (int j = 0; j < CPT; ++j) acc[j] = fmaf(xv, wr[j], acc[j]);
        }
    }

    int row = row0 + r;
    if (row < n) {
#pragma unroll
        for (int j = 0; j < CPT; ++j) feat[(size_t)row * OUT + c0 + j] = acc[j];
        // el/er partial for this thread's cols (all within one head since CPT | 32)
        int h = c0 / 32;
        int d0 = c0 & 31;
        float pel = 0.f, per = 0.f;
#pragma unroll
        for (int j = 0; j < CPT; ++j) {
            pel = fmaf(acc[j], al[h * 32 + d0 + j], pel);
            per = fmaf(acc[j], ar[h * 32 + d0 + j], per);
        }
        constexpr int G = 32 / CPT;   // threads covering one head (consecutive lanes)
#pragma unroll
        for (int o = 1; o < G; o <<= 1) {
            pel += __shfl_xor(pel, o);
            per += __shfl_xor(per, o);
        }
        if ((cseg & (G - 1)) == 0) {
            el[(size_t)row * H + h] = pel;
            er[(size_t)row * H + h] = per;
        }
    }
}

// ---------------- Aggregation layer 1: wave per node, 2 cols/lane (F1=128) ----------------
__global__ __launch_bounds__(256) void agg1_kernel(
    const int* __restrict__ off, const int* __restrict__ csr_src,
    const float* __restrict__ feat, const float* __restrict__ el,
    const float* __restrict__ er, const float* __restrict__ b,
    float* __restrict__ out, int n)
{
    int wid = (blockIdx.x * 256 + threadIdx.x) >> 6;   // node
    int lane = threadIdx.x & 63;
    if (wid >= n) return;
    int c0 = lane * 2;
    int h = lane >> 4;                // c0/32
    float erv = er[(size_t)wid * H1 + h];
    float sw = 0.f, a0 = 0.f, a1 = 0.f;
    int jb = off[wid], je = off[wid + 1];
    for (int j = jb; j < je; ++j) {
        int s = csr_src[j];
        float2 f = *(const float2*)(feat + (size_t)s * F1 + c0);
        float t = el[(size_t)s * H1 + h] + erv;
        float e = t > 0.f ? t : NEG * t;
        float w = __expf(e);
        sw += w;
        a0 = fmaf(w, f.x, a0);
        a1 = fmaf(w, f.y, a1);
    }
    float inv = 1.f / fmaxf(sw, 1e-16f);
    out[(size_t)wid * F1 + c0]     = a0 * inv + b[c0];
    out[(size_t)wid * F1 + c0 + 1] = a1 * inv + b[c0 + 1];
}

// ---------------- Aggregation layer 2: wave per node, lanes split over 2 edges (F2=32) ----------------
__global__ __launch_bounds__(256) void agg2_kernel(
    const int* __restrict__ off, const int* __restrict__ csr_src,
    const float* __restrict__ feat, const float* __restrict__ el,
    const float* __restrict__ er, const float* __restrict__ b,
    float* __restrict__ out, int n)
{
    int wid = (blockIdx.x * 256 + threadIdx.x) >> 6;   // node
    int lane = threadIdx.x & 63;
    if (wid >= n) return;
    int c = lane & 31;
    int half = lane >> 5;
    float erv = er[wid];
    float sw = 0.f, a = 0.f;
    int jb = off[wid], je = off[wid + 1];
    for (int j = jb + half; j < je; j += 2) {
        int s = csr_src[j];
        float f = feat[(size_t)s * F2 + c];
        float t = el[s] + erv;
        float e = t > 0.f ? t : NEG * t;
        float w = __expf(e);
        sw += w;
        a = fmaf(w, f, a);
    }
    a  += __shfl_xor(a, 32);
    sw += __shfl_xor(sw, 32);
    if (half == 0) out[(size_t)wid * F2 + c] = a / fmaxf(sw, 1e-16f) + b[c];
}

// ---------------- launch ----------------
extern "C" void kernel_launch(void* const* d_in, const int* in_sizes, int n_in,
                              void* d_out, int out_size, void* d_ws, size_t ws_size,
                              hipStream_t stream) {
    const float* x   = (const float*)d_in[0];
    const float* W1  = (const float*)d_in[1];
    const float* al1 = (const float*)d_in[2];
    const float* ar1 = (const float*)d_in[3];
    const float* b1  = (const float*)d_in[4];
    const float* W2  = (const float*)d_in[5];
    const float* al2 = (const float*)d_in[6];
    const float* ar2 = (const float*)d_in[7];
    const float* b2  = (const float*)d_in[8];
    const int*   src = (const int*)d_in[9];
    const int*   dst = (const int*)d_in[10];

    const int N = in_sizes[0] / F_IN;
    const int E = in_sizes[9];

    // workspace layout (256B-aligned regions)
    char* w = (char*)d_ws;
    size_t o = 0;
    auto alloc = [&](size_t bytes) { size_t cur = o; o += (bytes + 255) & ~255ULL; return cur; };
    int*   off   = (int*)  (w + alloc((size_t)(N + 1) * 4));
    int*   pos   = (int*)  (w + alloc((size_t)N * 4));
    int*   csr   = (int*)  (w + alloc((size_t)E * 4));
    float* feat1 = (float*)(w + alloc((size_t)N * F1 * 4));
    float* el1   = (float*)(w + alloc((size_t)N * H1 * 4));
    float* er1   = (float*)(w + alloc((size_t)N * H1 * 4));
    float* h1    = (float*)(w + alloc((size_t)N * F1 * 4));
    float* feat2 = (float*)(w + alloc((size_t)N * F2 * 4));
    float* el2   = (float*)(w + alloc((size_t)N * H2 * 4));
    float* er2   = (float*)(w + alloc((size_t)N * H2 * 4));
    (void)ws_size; (void)n_in; (void)out_size;

    // ---- CSR build (shared by both layers) ----
    hipMemsetAsync(pos, 0, (size_t)N * 4, stream);
    hist_kernel<<<(E + 255) / 256, 256, 0, stream>>>(dst, pos, E);
    scan_kernel<<<1, 1024, 0, stream>>>(pos, off, N);
    hipMemsetAsync(pos, 0, (size_t)N * 4, stream);
    scatter_kernel<<<(E + 255) / 256, 256, 0, stream>>>(src, dst, off, pos, csr, E);

    // ---- layer 1 ----
    gemm_elr<F_IN, F1, H1, 8, 16, 64><<<(N + 15) / 16, 256, 0, stream>>>(
        x, W1, al1, ar1, feat1, el1, er1, N);
    agg1_kernel<<<(N + 3) / 4, 256, 0, stream>>>(off, csr, feat1, el1, er1, b1, h1, N);

    // ---- layer 2 ----
    gemm_elr<F1, F2, H2, 4, 32, 64><<<(N + 31) / 32, 256, 0, stream>>>(
        h1, W2, al2, ar2, feat2, el2, er2, N);
    agg2_kernel<<<(N + 3) / 4, 256, 0, stream>>>(off, csr, feat2, el2, er2, b2, (float*)d_out, N);
}

// Round 2
// 389.461 us; speedup vs baseline: 1.1580x; 1.1580x over previous
//
#include <hip/hip_runtime.h>

// ---------------- problem constants (match reference) ----------------
constexpr int F_IN = 256;
constexpr int H1 = 4, D1 = 32, F1 = H1 * D1;   // 128
constexpr int H2 = 1, D2 = 32, F2 = H2 * D2;   // 32
constexpr float NEG = 0.2f;

// ---------------- CSR build ----------------
__global__ void hist_kernel(const int* __restrict__ dst, int* __restrict__ deg, int E) {
    int e = blockIdx.x * 256 + threadIdx.x;
    if (e < E) atomicAdd(&deg[dst[e]], 1);
}

__global__ void scan_kernel(const int* __restrict__ deg, int* __restrict__ off, int n) {
    __shared__ int sums[1024];
    int tid = threadIdx.x;
    int chunk = (n + 1023) / 1024;
    int start = tid * chunk;
    int end = min(start + chunk, n);
    int local = 0;
    for (int i = start; i < end; ++i) local += deg[i];
    sums[tid] = local;
    __syncthreads();
    for (int o = 1; o < 1024; o <<= 1) {
        int v = (tid >= o) ? sums[tid - o] : 0;
        __syncthreads();
        sums[tid] += v;
        __syncthreads();
    }
    int run = sums[tid] - local;           // exclusive prefix
    for (int i = start; i < end; ++i) { off[i] = run; run += deg[i]; }
    if (tid == 0) off[n] = sums[1023];
}

__global__ void scatter_kernel(const int* __restrict__ src, const int* __restrict__ dst,
                               const int* __restrict__ off, int* __restrict__ pos,
                               int* __restrict__ csr_src, int E) {
    int e = blockIdx.x * 256 + threadIdx.x;
    if (e < E) {
        int d = dst[e];
        int p = off[d] + atomicAdd(&pos[d], 1);
        csr_src[p] = src[e];
    }
}

// ---------------- Register-blocked f32 GEMM: out[n][OUT] = X[n][IN] @ W[IN][OUT] ----------------
// TM = 4 rows per thread (one contiguous ds_read_b128 from k-major xs).
// rblk varies fastest across lanes -> row reads land on contiguous 16B -> 2-way (free).
// W reads are 16-lane broadcasts -> conflict-free.
template <int IN, int OUT, int BM, int BN, int TN, int KT>
__global__ __launch_bounds__(256) void gemm_rb(const float* __restrict__ X,
                                               const float* __restrict__ W,
                                               float* __restrict__ out, int n)
{
    constexpr int TM = 4;
    constexpr int RBLK = BM / TM;
    constexpr int CBLK = BN / TN;
    static_assert(RBLK * CBLK == 256, "block mapping");
    static_assert(BN == OUT, "full-width tiles");
    __shared__ float xs[KT][BM];
    __shared__ float ws[KT][BN];

    const int tid = threadIdx.x;
    const int rblk = tid % RBLK;
    const int cblk = tid / RBLK;
    const int row0 = blockIdx.x * BM;

    float acc[TM][TN];
#pragma unroll
    for (int i = 0; i < TM; ++i)
#pragma unroll
        for (int j = 0; j < TN; ++j) acc[i][j] = 0.f;

    constexpr int XQ = BM * KT / 4 / 256;
    constexpr int WQ = KT * BN / 4 / 256;
    float4 xreg[XQ], wreg[WQ];

    auto load_slice = [&](int k0) {
#pragma unroll
        for (int i = 0; i < XQ; ++i) {
            int idx = tid + i * 256;
            int xrow = idx % BM, xkc = idx / BM;
            int grow = row0 + xrow;
            if (grow < n)
                xreg[i] = *(const float4*)(X + (size_t)grow * IN + k0 + xkc * 4);
            else
                xreg[i] = float4{0.f, 0.f, 0.f, 0.f};
        }
#pragma unroll
        for (int i = 0; i < WQ; ++i) {
            int idx = tid + i * 256;
            int wk = idx / (BN / 4), wc4 = idx % (BN / 4);
            wreg[i] = *(const float4*)(W + (size_t)(k0 + wk) * OUT + wc4 * 4);
        }
    };
    auto store_slice = [&]() {
#pragma unroll
        for (int i = 0; i < XQ; ++i) {
            int idx = tid + i * 256;
            int xrow = idx % BM, xkc = idx / BM;
            xs[xkc * 4 + 0][xrow] = xreg[i].x;
            xs[xkc * 4 + 1][xrow] = xreg[i].y;
            xs[xkc * 4 + 2][xrow] = xreg[i].z;
            xs[xkc * 4 + 3][xrow] = xreg[i].w;
        }
#pragma unroll
        for (int i = 0; i < WQ; ++i) {
            int idx = tid + i * 256;
            int wk = idx / (BN / 4), wc4 = idx % (BN / 4);
            *(float4*)&ws[wk][wc4 * 4] = wreg[i];
        }
    };

    load_slice(0);
    int k0 = 0;
    while (true) {
        __syncthreads();
        store_slice();
        __syncthreads();
        int knext = k0 + KT;
        if (knext < IN) load_slice(knext);
#pragma unroll
        for (int kk = 0; kk < KT; ++kk) {
            float4 xv = *(const float4*)&xs[kk][rblk * 4];
            float xa[TM] = {xv.x, xv.y, xv.z, xv.w};
            float wv[TN];
#pragma unroll
            for (int j = 0; j < TN; j += 4) {
                float4 t = *(const float4*)&ws[kk][cblk * TN + j];
                wv[j] = t.x; wv[j + 1] = t.y; wv[j + 2] = t.z; wv[j + 3] = t.w;
            }
#pragma unroll
            for (int i2 = 0; i2 < TM; ++i2)
#pragma unroll
                for (int j = 0; j < TN; ++j)
                    acc[i2][j] = fmaf(xa[i2], wv[j], acc[i2][j]);
        }
        k0 = knext;
        if (k0 >= IN) break;
    }

#pragma unroll
    for (int i2 = 0; i2 < TM; ++i2) {
        int row = row0 + rblk * TM + i2;
        if (row < n) {
#pragma unroll
            for (int j = 0; j < TN; j += 4) {
                float4 t = {acc[i2][j], acc[i2][j + 1], acc[i2][j + 2], acc[i2][j + 3]};
                *(float4*)(out + (size_t)row * OUT + cblk * TN + j) = t;
            }
        }
    }
}

// ---------------- el/er pass: per-head attention dots over feat ----------------
template <int F, int H>
__global__ __launch_bounds__(256) void elr_kernel(const float* __restrict__ feat,
                                                  const float* __restrict__ al,
                                                  const float* __restrict__ ar,
                                                  float* __restrict__ el,
                                                  float* __restrict__ er, int n)
{
    constexpr int LPN = F / 2;       // lanes per node
    constexpr int NPW = 64 / LPN;    // nodes per wave
    int wid = (blockIdx.x * 256 + threadIdx.x) >> 6;
    int lane = threadIdx.x & 63;
    int node = wid * NPW + lane / LPN;
    int l2 = lane % LPN;
    int c0 = l2 * 2;
    if (node >= n) return;
    float2 f = *(const float2*)(feat + (size_t)node * F + c0);
    float2 a = *(const float2*)(al + c0);
    float2 r = *(const float2*)(ar + c0);
    float pel = f.x * a.x + f.y * a.y;
    float per = f.x * r.x + f.y * r.y;
#pragma unroll
    for (int o = 1; o < 16; o <<= 1) {
        pel += __shfl_xor(pel, o);
        per += __shfl_xor(per, o);
    }
    if ((l2 & 15) == 0) {
        int h = c0 / 32;
        el[(size_t)node * H + h] = pel;
        er[(size_t)node * H + h] = per;
    }
}

// ---------------- Aggregation layer 1: wave per node, 2 cols/lane (F1=128) ----------------
__global__ __launch_bounds__(256) void agg1_kernel(
    const int* __restrict__ off, const int* __restrict__ csr_src,
    const float* __restrict__ feat, const float* __restrict__ el,
    const float* __restrict__ er, const float* __restrict__ b,
    float* __restrict__ out, int n)
{
    int wid = (blockIdx.x * 256 + threadIdx.x) >> 6;   // node
    int lane = threadIdx.x & 63;
    if (wid >= n) return;
    int c0 = lane * 2;
    int h = lane >> 4;                // c0/32
    float erv = er[(size_t)wid * H1 + h];
    float sw = 0.f, a0 = 0.f, a1 = 0.f;
    int jb = off[wid], je = off[wid + 1];
    for (int j = jb; j < je; ++j) {
        int s = csr_src[j];
        float2 f = *(const float2*)(feat + (size_t)s * F1 + c0);
        float t = el[(size_t)s * H1 + h] + erv;
        float e = t > 0.f ? t : NEG * t;
        float w = __expf(e);
        sw += w;
        a0 = fmaf(w, f.x, a0);
        a1 = fmaf(w, f.y, a1);
    }
    float inv = 1.f / fmaxf(sw, 1e-16f);
    out[(size_t)wid * F1 + c0]     = a0 * inv + b[c0];
    out[(size_t)wid * F1 + c0 + 1] = a1 * inv + b[c0 + 1];
}

// ---------------- Aggregation layer 2: wave per node, lanes split over 2 edges (F2=32) ----------------
__global__ __launch_bounds__(256) void agg2_kernel(
    const int* __restrict__ off, const int* __restrict__ csr_src,
    const float* __restrict__ feat, const float* __restrict__ el,
    const float* __restrict__ er, const float* __restrict__ b,
    float* __restrict__ out, int n)
{
    int wid = (blockIdx.x * 256 + threadIdx.x) >> 6;   // node
    int lane = threadIdx.x & 63;
    if (wid >= n) return;
    int c = lane & 31;
    int half = lane >> 5;
    float erv = er[wid];
    float sw = 0.f, a = 0.f;
    int jb = off[wid], je = off[wid + 1];
    for (int j = jb + half; j < je; j += 2) {
        int s = csr_src[j];
        float f = feat[(size_t)s * F2 + c];
        float t = el[s] + erv;
        float e = t > 0.f ? t : NEG * t;
        float w = __expf(e);
        sw += w;
        a = fmaf(w, f, a);
    }
    a  += __shfl_xor(a, 32);
    sw += __shfl_xor(sw, 32);
    if (half == 0) out[(size_t)wid * F2 + c] = a / fmaxf(sw, 1e-16f) + b[c];
}

// ---------------- launch ----------------
extern "C" void kernel_launch(void* const* d_in, const int* in_sizes, int n_in,
                              void* d_out, int out_size, void* d_ws, size_t ws_size,
                              hipStream_t stream) {
    const float* x   = (const float*)d_in[0];
    const float* W1  = (const float*)d_in[1];
    const float* al1 = (const float*)d_in[2];
    const float* ar1 = (const float*)d_in[3];
    const float* b1  = (const float*)d_in[4];
    const float* W2  = (const float*)d_in[5];
    const float* al2 = (const float*)d_in[6];
    const float* ar2 = (const float*)d_in[7];
    const float* b2  = (const float*)d_in[8];
    const int*   src = (const int*)d_in[9];
    const int*   dst = (const int*)d_in[10];

    const int N = in_sizes[0] / F_IN;
    const int E = in_sizes[9];

    // workspace layout (256B-aligned regions)
    char* w = (char*)d_ws;
    size_t o = 0;
    auto alloc = [&](size_t bytes) { size_t cur = o; o += (bytes + 255) & ~255ULL; return cur; };
    int*   off   = (int*)  (w + alloc((size_t)(N + 1) * 4));
    int*   pos   = (int*)  (w + alloc((size_t)N * 4));
    int*   csr   = (int*)  (w + alloc((size_t)E * 4));
    float* feat1 = (float*)(w + alloc((size_t)N * F1 * 4));
    float* el1   = (float*)(w + alloc((size_t)N * H1 * 4));
    float* er1   = (float*)(w + alloc((size_t)N * H1 * 4));
    float* h1    = (float*)(w + alloc((size_t)N * F1 * 4));
    float* feat2 = (float*)(w + alloc((size_t)N * F2 * 4));
    float* el2   = (float*)(w + alloc((size_t)N * H2 * 4));
    float* er2   = (float*)(w + alloc((size_t)N * H2 * 4));
    (void)ws_size; (void)n_in; (void)out_size;

    // ---- CSR build (shared by both layers) ----
    hipMemsetAsync(pos, 0, (size_t)N * 4, stream);
    hist_kernel<<<(E + 255) / 256, 256, 0, stream>>>(dst, pos, E);
    scan_kernel<<<1, 1024, 0, stream>>>(pos, off, N);
    hipMemsetAsync(pos, 0, (size_t)N * 4, stream);
    scatter_kernel<<<(E + 255) / 256, 256, 0, stream>>>(src, dst, off, pos, csr, E);

    // ---- layer 1: GEMM 50000x256x128, tile 64x128, micro 4x8 ----
    gemm_rb<F_IN, F1, 64, 128, 8, 32><<<(N + 63) / 64, 256, 0, stream>>>(x, W1, feat1, N);
    elr_kernel<F1, H1><<<(N + 3) / 4, 256, 0, stream>>>(feat1, al1, ar1, el1, er1, N);
    agg1_kernel<<<(N + 3) / 4, 256, 0, stream>>>(off, csr, feat1, el1, er1, b1, h1, N);

    // ---- layer 2: GEMM 50000x128x32, tile 128x32, micro 4x4 ----
    gemm_rb<F1, F2, 128, 32, 4, 32><<<(N + 127) / 128, 256, 0, stream>>>(h1, W2, feat2, N);
    elr_kernel<F2, H2><<<(N + 15) / 16, 256, 0, stream>>>(feat2, al2, ar2, el2, er2, N);
    agg2_kernel<<<(N + 3) / 4, 256, 0, stream>>>(off, csr, feat2, el2, er2, b2, (float*)d_out, N);
}

// Round 3
// 334.525 us; speedup vs baseline: 1.3482x; 1.1642x over previous
//
#include <hip/hip_runtime.h>

// ---------------- problem constants (match reference) ----------------
constexpr int F_IN = 256;
constexpr int H1 = 4, D1 = 32, F1 = H1 * D1;   // 128
constexpr int H2 = 1, D2 = 32, F2 = H2 * D2;   // 32
constexpr float NEG = 0.2f;

// ---------------- CSR build ----------------
__global__ void hist_kernel(const int* __restrict__ dst, int* __restrict__ deg, int E) {
    int e = blockIdx.x * 256 + threadIdx.x;
    if (e < E) atomicAdd(&deg[dst[e]], 1);
}

__global__ void scan_kernel(const int* __restrict__ deg, int* __restrict__ off, int n) {
    __shared__ int sums[1024];
    int tid = threadIdx.x;
    int chunk = (n + 1023) / 1024;
    int start = tid * chunk;
    int end = min(start + chunk, n);
    int local = 0;
    for (int i = start; i < end; ++i) local += deg[i];
    sums[tid] = local;
    __syncthreads();
    for (int o = 1; o < 1024; o <<= 1) {
        int v = (tid >= o) ? sums[tid - o] : 0;
        __syncthreads();
        sums[tid] += v;
        __syncthreads();
    }
    int run = sums[tid] - local;           // exclusive prefix
    for (int i = start; i < end; ++i) { off[i] = run; run += deg[i]; }
    if (tid == 0) off[n] = sums[1023];
}

__global__ void scatter_kernel(const int* __restrict__ src, const int* __restrict__ dst,
                               const int* __restrict__ off, int* __restrict__ pos,
                               int* __restrict__ csr_src, int E) {
    int e = blockIdx.x * 256 + threadIdx.x;
    if (e < E) {
        int d = dst[e];
        int p = off[d] + atomicAdd(&pos[d], 1);
        csr_src[p] = src[e];
    }
}

// ---------------- Register-blocked f32 GEMM: out[n][OUT] = X[n][IN] @ W[IN][OUT] ----------------
template <int IN, int OUT, int BM, int BN, int TN, int KT>
__global__ __launch_bounds__(256) void gemm_rb(const float* __restrict__ X,
                                               const float* __restrict__ W,
                                               float* __restrict__ out, int n)
{
    constexpr int TM = 4;
    constexpr int RBLK = BM / TM;
    constexpr int CBLK = BN / TN;
    static_assert(RBLK * CBLK == 256, "block mapping");
    static_assert(BN == OUT, "full-width tiles");
    __shared__ float xs[KT][BM];
    __shared__ float ws[KT][BN];

    const int tid = threadIdx.x;
    const int rblk = tid % RBLK;
    const int cblk = tid / RBLK;
    const int row0 = blockIdx.x * BM;

    float acc[TM][TN];
#pragma unroll
    for (int i = 0; i < TM; ++i)
#pragma unroll
        for (int j = 0; j < TN; ++j) acc[i][j] = 0.f;

    constexpr int XQ = BM * KT / 4 / 256;
    constexpr int WQ = KT * BN / 4 / 256;
    float4 xreg[XQ], wreg[WQ];

    auto load_slice = [&](int k0) {
#pragma unroll
        for (int i = 0; i < XQ; ++i) {
            int idx = tid + i * 256;
            int xrow = idx % BM, xkc = idx / BM;
            int grow = row0 + xrow;
            if (grow < n)
                xreg[i] = *(const float4*)(X + (size_t)grow * IN + k0 + xkc * 4);
            else
                xreg[i] = float4{0.f, 0.f, 0.f, 0.f};
        }
#pragma unroll
        for (int i = 0; i < WQ; ++i) {
            int idx = tid + i * 256;
            int wk = idx / (BN / 4), wc4 = idx % (BN / 4);
            wreg[i] = *(const float4*)(W + (size_t)(k0 + wk) * OUT + wc4 * 4);
        }
    };
    auto store_slice = [&]() {
#pragma unroll
        for (int i = 0; i < XQ; ++i) {
            int idx = tid + i * 256;
            int xrow = idx % BM, xkc = idx / BM;
            xs[xkc * 4 + 0][xrow] = xreg[i].x;
            xs[xkc * 4 + 1][xrow] = xreg[i].y;
            xs[xkc * 4 + 2][xrow] = xreg[i].z;
            xs[xkc * 4 + 3][xrow] = xreg[i].w;
        }
#pragma unroll
        for (int i = 0; i < WQ; ++i) {
            int idx = tid + i * 256;
            int wk = idx / (BN / 4), wc4 = idx % (BN / 4);
            *(float4*)&ws[wk][wc4 * 4] = wreg[i];
        }
    };

    load_slice(0);
    int k0 = 0;
    while (true) {
        __syncthreads();
        store_slice();
        __syncthreads();
        int knext = k0 + KT;
        if (knext < IN) load_slice(knext);
#pragma unroll
        for (int kk = 0; kk < KT; ++kk) {
            float4 xv = *(const float4*)&xs[kk][rblk * 4];
            float xa[TM] = {xv.x, xv.y, xv.z, xv.w};
            float wv[TN];
#pragma unroll
            for (int j = 0; j < TN; j += 4) {
                float4 t = *(const float4*)&ws[kk][cblk * TN + j];
                wv[j] = t.x; wv[j + 1] = t.y; wv[j + 2] = t.z; wv[j + 3] = t.w;
            }
#pragma unroll
            for (int i2 = 0; i2 < TM; ++i2)
#pragma unroll
                for (int j = 0; j < TN; ++j)
                    acc[i2][j] = fmaf(xa[i2], wv[j], acc[i2][j]);
        }
        k0 = knext;
        if (k0 >= IN) break;
    }

#pragma unroll
    for (int i2 = 0; i2 < TM; ++i2) {
        int row = row0 + rblk * TM + i2;
        if (row < n) {
#pragma unroll
            for (int j = 0; j < TN; j += 4) {
                float4 t = {acc[i2][j], acc[i2][j + 1], acc[i2][j + 2], acc[i2][j + 3]};
                *(float4*)(out + (size_t)row * OUT + cblk * TN + j) = t;
            }
        }
    }
}

// ---------------- el/er pass: per-head attention dots over feat ----------------
template <int F, int H>
__global__ __launch_bounds__(256) void elr_kernel(const float* __restrict__ feat,
                                                  const float* __restrict__ al,
                                                  const float* __restrict__ ar,
                                                  float* __restrict__ el,
                                                  float* __restrict__ er, int n)
{
    constexpr int LPN = F / 2;       // lanes per node
    constexpr int NPW = 64 / LPN;    // nodes per wave
    int wid = (blockIdx.x * 256 + threadIdx.x) >> 6;
    int lane = threadIdx.x & 63;
    int node = wid * NPW + lane / LPN;
    int l2 = lane % LPN;
    int c0 = l2 * 2;
    if (node >= n) return;
    float2 f = *(const float2*)(feat + (size_t)node * F + c0);
    float2 a = *(const float2*)(al + c0);
    float2 r = *(const float2*)(ar + c0);
    float pel = f.x * a.x + f.y * a.y;
    float per = f.x * r.x + f.y * r.y;
#pragma unroll
    for (int o = 1; o < 16; o <<= 1) {
        pel += __shfl_xor(pel, o);
        per += __shfl_xor(per, o);
    }
    if ((l2 & 15) == 0) {
        int h = c0 / 32;
        el[(size_t)node * H + h] = pel;
        er[(size_t)node * H + h] = per;
    }
}

// ---------------- Aggregation layer 1: wave per node, float4/lane, halves + unroll2 = 4 edges in flight ----------------
__global__ __launch_bounds__(256) void agg1_kernel(
    const int* __restrict__ off, const int* __restrict__ csr_src,
    const float* __restrict__ feat, const float* __restrict__ el,
    const float* __restrict__ er, const float* __restrict__ b,
    float* __restrict__ out, int n)
{
    int wid = (blockIdx.x * 256 + threadIdx.x) >> 6;   // node
    int lane = threadIdx.x & 63;
    if (wid >= n) return;
    int c0 = (lane & 31) * 4;         // 32 lanes cover 128 cols
    int h = (lane & 31) >> 3;         // c0 / 32
    int half = lane >> 5;
    float erv = er[(size_t)wid * H1 + h];
    float sw = 0.f;
    float4 acc = {0.f, 0.f, 0.f, 0.f};
    int jb = off[wid], je = off[wid + 1];
    int j = jb + half;
    for (; j + 2 < je; j += 4) {
        int s0 = csr_src[j];
        int s1 = csr_src[j + 2];
        float4 f0 = *(const float4*)(feat + (size_t)s0 * F1 + c0);
        float4 f1 = *(const float4*)(feat + (size_t)s1 * F1 + c0);
        float t0 = el[(size_t)s0 * H1 + h] + erv;
        float t1 = el[(size_t)s1 * H1 + h] + erv;
        t0 = t0 > 0.f ? t0 : NEG * t0;
        t1 = t1 > 0.f ? t1 : NEG * t1;
        float w0 = __expf(t0);
        float w1 = __expf(t1);
        sw += w0 + w1;
        acc.x = fmaf(w0, f0.x, fmaf(w1, f1.x, acc.x));
        acc.y = fmaf(w0, f0.y, fmaf(w1, f1.y, acc.y));
        acc.z = fmaf(w0, f0.z, fmaf(w1, f1.z, acc.z));
        acc.w = fmaf(w0, f0.w, fmaf(w1, f1.w, acc.w));
    }
    for (; j < je; j += 2) {
        int s = csr_src[j];
        float4 f = *(const float4*)(feat + (size_t)s * F1 + c0);
        float t = el[(size_t)s * H1 + h] + erv;
        t = t > 0.f ? t : NEG * t;
        float w = __expf(t);
        sw += w;
        acc.x = fmaf(w, f.x, acc.x);
        acc.y = fmaf(w, f.y, acc.y);
        acc.z = fmaf(w, f.z, acc.z);
        acc.w = fmaf(w, f.w, acc.w);
    }
    acc.x += __shfl_xor(acc.x, 32);
    acc.y += __shfl_xor(acc.y, 32);
    acc.z += __shfl_xor(acc.z, 32);
    acc.w += __shfl_xor(acc.w, 32);
    sw    += __shfl_xor(sw, 32);
    if (half == 0) {
        float inv = 1.f / fmaxf(sw, 1e-16f);
        float4 bb = *(const float4*)(b + c0);
        float4 t = {acc.x * inv + bb.x, acc.y * inv + bb.y,
                    acc.z * inv + bb.z, acc.w * inv + bb.w};
        *(float4*)(out + (size_t)wid * F1 + c0) = t;
    }
}

// ---------------- Aggregation layer 2: 8 lanes/edge, 8 edge-groups, unroll2 = 16 edges in flight ----------------
__global__ __launch_bounds__(256) void agg2_kernel(
    const int* __restrict__ off, const int* __restrict__ csr_src,
    const float* __restrict__ feat, const float* __restrict__ el,
    const float* __restrict__ er, const float* __restrict__ b,
    float* __restrict__ out, int n)
{
    int wid = (blockIdx.x * 256 + threadIdx.x) >> 6;   // node
    int lane = threadIdx.x & 63;
    if (wid >= n) return;
    int c0 = (lane & 7) * 4;          // 8 lanes cover 32 cols
    int grp = lane >> 3;              // 8 edge groups
    float erv = er[wid];
    float sw = 0.f;
    float4 acc = {0.f, 0.f, 0.f, 0.f};
    int jb = off[wid], je = off[wid + 1];
    int j = jb + grp;
    for (; j + 8 < je; j += 16) {
        int s0 = csr_src[j];
        int s1 = csr_src[j + 8];
        float4 f0 = *(const float4*)(feat + (size_t)s0 * F2 + c0);
        float4 f1 = *(const float4*)(feat + (size_t)s1 * F2 + c0);
        float t0 = el[s0] + erv;
        float t1 = el[s1] + erv;
        t0 = t0 > 0.f ? t0 : NEG * t0;
        t1 = t1 > 0.f ? t1 : NEG * t1;
        float w0 = __expf(t0);
        float w1 = __expf(t1);
        sw += w0 + w1;
        acc.x = fmaf(w0, f0.x, fmaf(w1, f1.x, acc.x));
        acc.y = fmaf(w0, f0.y, fmaf(w1, f1.y, acc.y));
        acc.z = fmaf(w0, f0.z, fmaf(w1, f1.z, acc.z));
        acc.w = fmaf(w0, f0.w, fmaf(w1, f1.w, acc.w));
    }
    for (; j < je; j += 8) {
        int s = csr_src[j];
        float4 f = *(const float4*)(feat + (size_t)s * F2 + c0);
        float t = el[s] + erv;
        t = t > 0.f ? t : NEG * t;
        float w = __expf(t);
        sw += w;
        acc.x = fmaf(w, f.x, acc.x);
        acc.y = fmaf(w, f.y, acc.y);
        acc.z = fmaf(w, f.z, acc.z);
        acc.w = fmaf(w, f.w, acc.w);
    }
#pragma unroll
    for (int o = 8; o < 64; o <<= 1) {
        acc.x += __shfl_xor(acc.x, o);
        acc.y += __shfl_xor(acc.y, o);
        acc.z += __shfl_xor(acc.z, o);
        acc.w += __shfl_xor(acc.w, o);
        sw    += __shfl_xor(sw, o);
    }
    if (lane < 8) {
        float inv = 1.f / fmaxf(sw, 1e-16f);
        float4 bb = *(const float4*)(b + c0);
        float4 t = {acc.x * inv + bb.x, acc.y * inv + bb.y,
                    acc.z * inv + bb.z, acc.w * inv + bb.w};
        *(float4*)(out + (size_t)wid * F2 + c0) = t;
    }
}

// ---------------- launch ----------------
extern "C" void kernel_launch(void* const* d_in, const int* in_sizes, int n_in,
                              void* d_out, int out_size, void* d_ws, size_t ws_size,
                              hipStream_t stream) {
    const float* x   = (const float*)d_in[0];
    const float* W1  = (const float*)d_in[1];
    const float* al1 = (const float*)d_in[2];
    const float* ar1 = (const float*)d_in[3];
    const float* b1  = (const float*)d_in[4];
    const float* W2  = (const float*)d_in[5];
    const float* al2 = (const float*)d_in[6];
    const float* ar2 = (const float*)d_in[7];
    const float* b2  = (const float*)d_in[8];
    const int*   src = (const int*)d_in[9];
    const int*   dst = (const int*)d_in[10];

    const int N = in_sizes[0] / F_IN;
    const int E = in_sizes[9];

    // workspace layout (256B-aligned regions)
    char* w = (char*)d_ws;
    size_t o = 0;
    auto alloc = [&](size_t bytes) { size_t cur = o; o += (bytes + 255) & ~255ULL; return cur; };
    int*   off   = (int*)  (w + alloc((size_t)(N + 1) * 4));
    int*   pos   = (int*)  (w + alloc((size_t)N * 4));
    int*   csr   = (int*)  (w + alloc((size_t)E * 4));
    float* feat1 = (float*)(w + alloc((size_t)N * F1 * 4));
    float* el1   = (float*)(w + alloc((size_t)N * H1 * 4));
    float* er1   = (float*)(w + alloc((size_t)N * H1 * 4));
    float* h1    = (float*)(w + alloc((size_t)N * F1 * 4));
    float* feat2 = (float*)(w + alloc((size_t)N * F2 * 4));
    float* el2   = (float*)(w + alloc((size_t)N * H2 * 4));
    float* er2   = (float*)(w + alloc((size_t)N * H2 * 4));
    (void)ws_size; (void)n_in; (void)out_size;

    // ---- CSR build (shared by both layers) ----
    hipMemsetAsync(pos, 0, (size_t)N * 4, stream);
    hist_kernel<<<(E + 255) / 256, 256, 0, stream>>>(dst, pos, E);
    scan_kernel<<<1, 1024, 0, stream>>>(pos, off, N);
    hipMemsetAsync(pos, 0, (size_t)N * 4, stream);
    scatter_kernel<<<(E + 255) / 256, 256, 0, stream>>>(src, dst, off, pos, csr, E);

    // ---- layer 1: GEMM 50000x256x128, tile 64x128, micro 4x8 ----
    gemm_rb<F_IN, F1, 64, 128, 8, 32><<<(N + 63) / 64, 256, 0, stream>>>(x, W1, feat1, N);
    elr_kernel<F1, H1><<<(N + 3) / 4, 256, 0, stream>>>(feat1, al1, ar1, el1, er1, N);
    agg1_kernel<<<(N + 3) / 4, 256, 0, stream>>>(off, csr, feat1, el1, er1, b1, h1, N);

    // ---- layer 2: GEMM 50000x128x32, tile 128x32, micro 4x4 ----
    gemm_rb<F1, F2, 128, 32, 4, 32><<<(N + 127) / 128, 256, 0, stream>>>(h1, W2, feat2, N);
    elr_kernel<F2, H2><<<(N + 15) / 16, 256, 0, stream>>>(feat2, al2, ar2, el2, er2, N);
    agg2_kernel<<<(N + 3) / 4, 256, 0, stream>>>(off, csr, feat2, el2, er2, b2, (float*)d_out, N);
}

// Round 4
// 316.807 us; speedup vs baseline: 1.4236x; 1.0559x over previous
//
#include <hip/hip_runtime.h>

// ---------------- problem constants (match reference) ----------------
constexpr int F_IN = 256;
constexpr int H1 = 4, D1 = 32, F1 = H1 * D1;   // 128
constexpr int H2 = 1, D2 = 32, F2 = H2 * D2;   // 32
constexpr float NEG = 0.2f;

typedef short short8 __attribute__((ext_vector_type(8)));
typedef float f32x4 __attribute__((ext_vector_type(4)));

// ---------------- CSR build ----------------
__global__ void hist_kernel(const int* __restrict__ dst, int* __restrict__ deg, int E) {
    int e = blockIdx.x * 256 + threadIdx.x;
    if (e < E) atomicAdd(&deg[dst[e]], 1);
}

__global__ void scan_kernel(const int* __restrict__ deg, int* __restrict__ off, int n) {
    __shared__ int sums[1024];
    int tid = threadIdx.x;
    int chunk = (n + 1023) / 1024;
    int start = tid * chunk;
    int end = min(start + chunk, n);
    int local = 0;
    for (int i = start; i < end; ++i) local += deg[i];
    sums[tid] = local;
    __syncthreads();
    for (int o = 1; o < 1024; o <<= 1) {
        int v = (tid >= o) ? sums[tid - o] : 0;
        __syncthreads();
        sums[tid] += v;
        __syncthreads();
    }
    int run = sums[tid] - local;           // exclusive prefix
    for (int i = start; i < end; ++i) { off[i] = run; run += deg[i]; }
    if (tid == 0) off[n] = sums[1023];
}

__global__ void scatter_kernel(const int* __restrict__ src, const int* __restrict__ dst,
                               const int* __restrict__ off, int* __restrict__ pos,
                               int* __restrict__ csr_src, int E) {
    int e = blockIdx.x * 256 + threadIdx.x;
    if (e < E) {
        int d = dst[e];
        int p = off[d] + atomicAdd(&pos[d], 1);
        csr_src[p] = src[e];
    }
}

// ---------------- W split: W[K][C] f32 -> Wh_t/Wl_t [C][K] bf16 hi/lo ----------------
__global__ void wsplit_kernel(const float* __restrict__ W,
                              unsigned short* __restrict__ Wh,
                              unsigned short* __restrict__ Wl, int K, int C) {
    int idx = blockIdx.x * 256 + threadIdx.x;
    if (idx >= K * C) return;
    int k = idx / C, c = idx % C;
    float v = W[idx];
    __bf16 h = (__bf16)v;
    float hv = (float)h;
    __bf16 lo = (__bf16)(v - hv);
    Wh[(size_t)c * K + k] = __builtin_bit_cast(unsigned short, h);
    Wl[(size_t)c * K + k] = __builtin_bit_cast(unsigned short, lo);
}

// ---------------- Layer-1 GEMM via split-bf16 MFMA ----------------
// out[n][128] = X[n][256] @ W. Block: 64 rows x 128 cols, 4 waves (2x2).
// Wave tile 32x64: mi=0..1 (16-row frags), ni=0..3 (16-col frags).
// A-frag: lane holds X[row0+wrow+mi*16+(l&15)][ks*32+(l>>4)*8 + j], j=0..7 (f32->bf16 hi/lo in-reg).
// B-frag: lane holds W[(ks*32+(l>>4)*8+j)][wcol+ni*16+(l&15)] from pre-transposed Wh_t/Wl_t.
// C/D: col=lane&15, row=(lane>>4)*4+reg  [m89-verified].
__global__ __launch_bounds__(256) void gemm1_mfma(
    const float* __restrict__ X,
    const unsigned short* __restrict__ Wh,
    const unsigned short* __restrict__ Wl,
    float* __restrict__ out, int n)
{
    const int lane = threadIdx.x & 63;
    const int wid  = threadIdx.x >> 6;
    const int wrow = (wid >> 1) * 32;       // 0 or 32
    const int wcol = (wid & 1) * 64;        // 0 or 64
    const int row0 = blockIdx.x * 64;
    const int l16  = lane & 15;
    const int khi  = lane >> 4;             // 0..3

    f32x4 acc[2][4];
#pragma unroll
    for (int mi = 0; mi < 2; ++mi)
#pragma unroll
        for (int ni = 0; ni < 4; ++ni) acc[mi][ni] = f32x4{0.f, 0.f, 0.f, 0.f};

    int ar[2];
#pragma unroll
    for (int mi = 0; mi < 2; ++mi) {
        int r = row0 + wrow + mi * 16 + l16;
        ar[mi] = r < n ? r : (n - 1);       // clamp loads; stores guarded
    }
    int bc[4];
#pragma unroll
    for (int ni = 0; ni < 4; ++ni) bc[ni] = wcol + ni * 16 + l16;

#pragma unroll 2
    for (int ks = 0; ks < 8; ++ks) {
        const int kbase = ks * 32 + khi * 8;

        short8 ah[2], al[2];
#pragma unroll
        for (int mi = 0; mi < 2; ++mi) {
            const float* ap = X + (size_t)ar[mi] * F_IN + kbase;
            float4 p0 = *(const float4*)ap;
            float4 p1 = *(const float4*)(ap + 4);
            float v[8] = {p0.x, p0.y, p0.z, p0.w, p1.x, p1.y, p1.z, p1.w};
#pragma unroll
            for (int j = 0; j < 8; ++j) {
                __bf16 h = (__bf16)v[j];
                float hv = (float)h;
                __bf16 lo = (__bf16)(v[j] - hv);
                ah[mi][j] = __builtin_bit_cast(short, h);
                al[mi][j] = __builtin_bit_cast(short, lo);
            }
        }

        short8 bh[4], bl[4];
#pragma unroll
        for (int ni = 0; ni < 4; ++ni) {
            bh[ni] = *(const short8*)(Wh + (size_t)bc[ni] * F_IN + kbase);
            bl[ni] = *(const short8*)(Wl + (size_t)bc[ni] * F_IN + kbase);
        }

#pragma unroll
        for (int mi = 0; mi < 2; ++mi)
#pragma unroll
            for (int ni = 0; ni < 4; ++ni) {
                acc[mi][ni] = __builtin_amdgcn_mfma_f32_16x16x32_bf16(al[mi], bh[ni], acc[mi][ni], 0, 0, 0);
                acc[mi][ni] = __builtin_amdgcn_mfma_f32_16x16x32_bf16(ah[mi], bl[ni], acc[mi][ni], 0, 0, 0);
                acc[mi][ni] = __builtin_amdgcn_mfma_f32_16x16x32_bf16(ah[mi], bh[ni], acc[mi][ni], 0, 0, 0);
            }
    }

#pragma unroll
    for (int mi = 0; mi < 2; ++mi) {
        int rbase = row0 + wrow + mi * 16 + khi * 4;
#pragma unroll
        for (int r = 0; r < 4; ++r) {
            int row = rbase + r;
            if (row < n) {
#pragma unroll
                for (int ni = 0; ni < 4; ++ni)
                    out[(size_t)row * F1 + wcol + ni * 16 + l16] = acc[mi][ni][r];
            }
        }
    }
}

// ---------------- Register-blocked f32 GEMM (layer 2) ----------------
template <int IN, int OUT, int BM, int BN, int TN, int KT>
__global__ __launch_bounds__(256) void gemm_rb(const float* __restrict__ X,
                                               const float* __restrict__ W,
                                               float* __restrict__ out, int n)
{
    constexpr int TM = 4;
    constexpr int RBLK = BM / TM;
    constexpr int CBLK = BN / TN;
    static_assert(RBLK * CBLK == 256, "block mapping");
    static_assert(BN == OUT, "full-width tiles");
    __shared__ float xs[KT][BM];
    __shared__ float ws[KT][BN];

    const int tid = threadIdx.x;
    const int rblk = tid % RBLK;
    const int cblk = tid / RBLK;
    const int row0 = blockIdx.x * BM;

    float acc[TM][TN];
#pragma unroll
    for (int i = 0; i < TM; ++i)
#pragma unroll
        for (int j = 0; j < TN; ++j) acc[i][j] = 0.f;

    constexpr int XQ = BM * KT / 4 / 256;
    constexpr int WQ = KT * BN / 4 / 256;
    float4 xreg[XQ], wreg[WQ];

    auto load_slice = [&](int k0) {
#pragma unroll
        for (int i = 0; i < XQ; ++i) {
            int idx = tid + i * 256;
            int xrow = idx % BM, xkc = idx / BM;
            int grow = row0 + xrow;
            if (grow < n)
                xreg[i] = *(const float4*)(X + (size_t)grow * IN + k0 + xkc * 4);
            else
                xreg[i] = float4{0.f, 0.f, 0.f, 0.f};
        }
#pragma unroll
        for (int i = 0; i < WQ; ++i) {
            int idx = tid + i * 256;
            int wk = idx / (BN / 4), wc4 = idx % (BN / 4);
            wreg[i] = *(const float4*)(W + (size_t)(k0 + wk) * OUT + wc4 * 4);
        }
    };
    auto store_slice = [&]() {
#pragma unroll
        for (int i = 0; i < XQ; ++i) {
            int idx = tid + i * 256;
            int xrow = idx % BM, xkc = idx / BM;
            xs[xkc * 4 + 0][xrow] = xreg[i].x;
            xs[xkc * 4 + 1][xrow] = xreg[i].y;
            xs[xkc * 4 + 2][xrow] = xreg[i].z;
            xs[xkc * 4 + 3][xrow] = xreg[i].w;
        }
#pragma unroll
        for (int i = 0; i < WQ; ++i) {
            int idx = tid + i * 256;
            int wk = idx / (BN / 4), wc4 = idx % (BN / 4);
            *(float4*)&ws[wk][wc4 * 4] = wreg[i];
        }
    };

    load_slice(0);
    int k0 = 0;
    while (true) {
        __syncthreads();
        store_slice();
        __syncthreads();
        int knext = k0 + KT;
        if (knext < IN) load_slice(knext);
#pragma unroll
        for (int kk = 0; kk < KT; ++kk) {
            float4 xv = *(const float4*)&xs[kk][rblk * 4];
            float xa[TM] = {xv.x, xv.y, xv.z, xv.w};
            float wv[TN];
#pragma unroll
            for (int j = 0; j < TN; j += 4) {
                float4 t = *(const float4*)&ws[kk][cblk * TN + j];
                wv[j] = t.x; wv[j + 1] = t.y; wv[j + 2] = t.z; wv[j + 3] = t.w;
            }
#pragma unroll
            for (int i2 = 0; i2 < TM; ++i2)
#pragma unroll
                for (int j = 0; j < TN; ++j)
                    acc[i2][j] = fmaf(xa[i2], wv[j], acc[i2][j]);
        }
        k0 = knext;
        if (k0 >= IN) break;
    }

#pragma unroll
    for (int i2 = 0; i2 < TM; ++i2) {
        int row = row0 + rblk * TM + i2;
        if (row < n) {
#pragma unroll
            for (int j = 0; j < TN; j += 4) {
                float4 t = {acc[i2][j], acc[i2][j + 1], acc[i2][j + 2], acc[i2][j + 3]};
                *(float4*)(out + (size_t)row * OUT + cblk * TN + j) = t;
            }
        }
    }
}

// ---------------- el/er pass: per-head attention dots over feat ----------------
template <int F, int H>
__global__ __launch_bounds__(256) void elr_kernel(const float* __restrict__ feat,
                                                  const float* __restrict__ al,
                                                  const float* __restrict__ ar,
                                                  float* __restrict__ el,
                                                  float* __restrict__ er, int n)
{
    constexpr int LPN = F / 2;       // lanes per node
    constexpr int NPW = 64 / LPN;    // nodes per wave
    int wid = (blockIdx.x * 256 + threadIdx.x) >> 6;
    int lane = threadIdx.x & 63;
    int node = wid * NPW + lane / LPN;
    int l2 = lane % LPN;
    int c0 = l2 * 2;
    if (node >= n) return;
    float2 f = *(const float2*)(feat + (size_t)node * F + c0);
    float2 a = *(const float2*)(al + c0);
    float2 r = *(const float2*)(ar + c0);
    float pel = f.x * a.x + f.y * a.y;
    float per = f.x * r.x + f.y * r.y;
#pragma unroll
    for (int o = 1; o < 16; o <<= 1) {
        pel += __shfl_xor(pel, o);
        per += __shfl_xor(per, o);
    }
    if ((l2 & 15) == 0) {
        int h = c0 / 32;
        el[(size_t)node * H + h] = pel;
        er[(size_t)node * H + h] = per;
    }
}

// ---------------- Aggregation layer 1 ----------------
__global__ __launch_bounds__(256) void agg1_kernel(
    const int* __restrict__ off, const int* __restrict__ csr_src,
    const float* __restrict__ feat, const float* __restrict__ el,
    const float* __restrict__ er, const float* __restrict__ b,
    float* __restrict__ out, int n)
{
    int wid = (blockIdx.x * 256 + threadIdx.x) >> 6;   // node
    int lane = threadIdx.x & 63;
    if (wid >= n) return;
    int c0 = (lane & 31) * 4;         // 32 lanes cover 128 cols
    int h = (lane & 31) >> 3;         // c0 / 32
    int half = lane >> 5;
    float erv = er[(size_t)wid * H1 + h];
    float sw = 0.f;
    float4 acc = {0.f, 0.f, 0.f, 0.f};
    int jb = off[wid], je = off[wid + 1];
    int j = jb + half;
    for (; j + 2 < je; j += 4) {
        int s0 = csr_src[j];
        int s1 = csr_src[j + 2];
        float4 f0 = *(const float4*)(feat + (size_t)s0 * F1 + c0);
        float4 f1 = *(const float4*)(feat + (size_t)s1 * F1 + c0);
        float t0 = el[(size_t)s0 * H1 + h] + erv;
        float t1 = el[(size_t)s1 * H1 + h] + erv;
        t0 = t0 > 0.f ? t0 : NEG * t0;
        t1 = t1 > 0.f ? t1 : NEG * t1;
        float w0 = __expf(t0);
        float w1 = __expf(t1);
        sw += w0 + w1;
        acc.x = fmaf(w0, f0.x, fmaf(w1, f1.x, acc.x));
        acc.y = fmaf(w0, f0.y, fmaf(w1, f1.y, acc.y));
        acc.z = fmaf(w0, f0.z, fmaf(w1, f1.z, acc.z));
        acc.w = fmaf(w0, f0.w, fmaf(w1, f1.w, acc.w));
    }
    for (; j < je; j += 2) {
        int s = csr_src[j];
        float4 f = *(const float4*)(feat + (size_t)s * F1 + c0);
        float t = el[(size_t)s * H1 + h] + erv;
        t = t > 0.f ? t : NEG * t;
        float w = __expf(t);
        sw += w;
        acc.x = fmaf(w, f.x, acc.x);
        acc.y = fmaf(w, f.y, acc.y);
        acc.z = fmaf(w, f.z, acc.z);
        acc.w = fmaf(w, f.w, acc.w);
    }
    acc.x += __shfl_xor(acc.x, 32);
    acc.y += __shfl_xor(acc.y, 32);
    acc.z += __shfl_xor(acc.z, 32);
    acc.w += __shfl_xor(acc.w, 32);
    sw    += __shfl_xor(sw, 32);
    if (half == 0) {
        float inv = 1.f / fmaxf(sw, 1e-16f);
        float4 bb = *(const float4*)(b + c0);
        float4 t = {acc.x * inv + bb.x, acc.y * inv + bb.y,
                    acc.z * inv + bb.z, acc.w * inv + bb.w};
        *(float4*)(out + (size_t)wid * F1 + c0) = t;
    }
}

// ---------------- Aggregation layer 2 ----------------
__global__ __launch_bounds__(256) void agg2_kernel(
    const int* __restrict__ off, const int* __restrict__ csr_src,
    const float* __restrict__ feat, const float* __restrict__ el,
    const float* __restrict__ er, const float* __restrict__ b,
    float* __restrict__ out, int n)
{
    int wid = (blockIdx.x * 256 + threadIdx.x) >> 6;   // node
    int lane = threadIdx.x & 63;
    if (wid >= n) return;
    int c0 = (lane & 7) * 4;          // 8 lanes cover 32 cols
    int grp = lane >> 3;              // 8 edge groups
    float erv = er[wid];
    float sw = 0.f;
    float4 acc = {0.f, 0.f, 0.f, 0.f};
    int jb = off[wid], je = off[wid + 1];
    int j = jb + grp;
    for (; j + 8 < je; j += 16) {
        int s0 = csr_src[j];
        int s1 = csr_src[j + 8];
        float4 f0 = *(const float4*)(feat + (size_t)s0 * F2 + c0);
        float4 f1 = *(const float4*)(feat + (size_t)s1 * F2 + c0);
        float t0 = el[s0] + erv;
        float t1 = el[s1] + erv;
        t0 = t0 > 0.f ? t0 : NEG * t0;
        t1 = t1 > 0.f ? t1 : NEG * t1;
        float w0 = __expf(t0);
        float w1 = __expf(t1);
        sw += w0 + w1;
        acc.x = fmaf(w0, f0.x, fmaf(w1, f1.x, acc.x));
        acc.y = fmaf(w0, f0.y, fmaf(w1, f1.y, acc.y));
        acc.z = fmaf(w0, f0.z, fmaf(w1, f1.z, acc.z));
        acc.w = fmaf(w0, f0.w, fmaf(w1, f1.w, acc.w));
    }
    for (; j < je; j += 8) {
        int s = csr_src[j];
        float4 f = *(const float4*)(feat + (size_t)s * F2 + c0);
        float t = el[s] + erv;
        t = t > 0.f ? t : NEG * t;
        float w = __expf(t);
        sw += w;
        acc.x = fmaf(w, f.x, acc.x);
        acc.y = fmaf(w, f.y, acc.y);
        acc.z = fmaf(w, f.z, acc.z);
        acc.w = fmaf(w, f.w, acc.w);
    }
#pragma unroll
    for (int o = 8; o < 64; o <<= 1) {
        acc.x += __shfl_xor(acc.x, o);
        acc.y += __shfl_xor(acc.y, o);
        acc.z += __shfl_xor(acc.z, o);
        acc.w += __shfl_xor(acc.w, o);
        sw    += __shfl_xor(sw, o);
    }
    if (lane < 8) {
        float inv = 1.f / fmaxf(sw, 1e-16f);
        float4 bb = *(const float4*)(b + c0);
        float4 t = {acc.x * inv + bb.x, acc.y * inv + bb.y,
                    acc.z * inv + bb.z, acc.w * inv + bb.w};
        *(float4*)(out + (size_t)wid * F2 + c0) = t;
    }
}

// ---------------- launch ----------------
extern "C" void kernel_launch(void* const* d_in, const int* in_sizes, int n_in,
                              void* d_out, int out_size, void* d_ws, size_t ws_size,
                              hipStream_t stream) {
    const float* x   = (const float*)d_in[0];
    const float* W1  = (const float*)d_in[1];
    const float* al1 = (const float*)d_in[2];
    const float* ar1 = (const float*)d_in[3];
    const float* b1  = (const float*)d_in[4];
    const float* W2  = (const float*)d_in[5];
    const float* al2 = (const float*)d_in[6];
    const float* ar2 = (const float*)d_in[7];
    const float* b2  = (const float*)d_in[8];
    const int*   src = (const int*)d_in[9];
    const int*   dst = (const int*)d_in[10];

    const int N = in_sizes[0] / F_IN;
    const int E = in_sizes[9];

    // workspace layout (256B-aligned regions)
    char* w = (char*)d_ws;
    size_t o = 0;
    auto alloc = [&](size_t bytes) { size_t cur = o; o += (bytes + 255) & ~255ULL; return cur; };
    int*   off   = (int*)  (w + alloc((size_t)(N + 1) * 4));
    int*   pos   = (int*)  (w + alloc((size_t)N * 4));
    int*   csr   = (int*)  (w + alloc((size_t)E * 4));
    float* feat1 = (float*)(w + alloc((size_t)N * F1 * 4));
    float* el1   = (float*)(w + alloc((size_t)N * H1 * 4));
    float* er1   = (float*)(w + alloc((size_t)N * H1 * 4));
    float* h1    = (float*)(w + alloc((size_t)N * F1 * 4));
    float* feat2 = (float*)(w + alloc((size_t)N * F2 * 4));
    float* el2   = (float*)(w + alloc((size_t)N * H2 * 4));
    float* er2   = (float*)(w + alloc((size_t)N * H2 * 4));
    unsigned short* W1h = (unsigned short*)(w + alloc((size_t)F_IN * F1 * 2));
    unsigned short* W1l = (unsigned short*)(w + alloc((size_t)F_IN * F1 * 2));
    (void)ws_size; (void)n_in; (void)out_size;

    // ---- CSR build (shared by both layers) ----
    hipMemsetAsync(pos, 0, (size_t)N * 4, stream);
    hist_kernel<<<(E + 255) / 256, 256, 0, stream>>>(dst, pos, E);
    scan_kernel<<<1, 1024, 0, stream>>>(pos, off, N);
    hipMemsetAsync(pos, 0, (size_t)N * 4, stream);
    scatter_kernel<<<(E + 255) / 256, 256, 0, stream>>>(src, dst, off, pos, csr, E);

    // ---- layer 1: split-bf16 MFMA GEMM 50000x256x128 ----
    wsplit_kernel<<<(F_IN * F1 + 255) / 256, 256, 0, stream>>>(W1, W1h, W1l, F_IN, F1);
    gemm1_mfma<<<(N + 63) / 64, 256, 0, stream>>>(x, W1h, W1l, feat1, N);
    elr_kernel<F1, H1><<<(N + 3) / 4, 256, 0, stream>>>(feat1, al1, ar1, el1, er1, N);
    agg1_kernel<<<(N + 3) / 4, 256, 0, stream>>>(off, csr, feat1, el1, er1, b1, h1, N);

    // ---- layer 2: f32 GEMM 50000x128x32, tile 128x32, micro 4x4 ----
    gemm_rb<F1, F2, 128, 32, 4, 32><<<(N + 127) / 128, 256, 0, stream>>>(h1, W2, feat2, N);
    elr_kernel<F2, H2><<<(N + 15) / 16, 256, 0, stream>>>(feat2, al2, ar2, el2, er2, N);
    agg2_kernel<<<(N + 3) / 4, 256, 0, stream>>>(off, csr, feat2, el2, er2, b2, (float*)d_out, N);
}

// Round 5
// 253.243 us; speedup vs baseline: 1.7809x; 1.2510x over previous
//
#include <hip/hip_runtime.h>

// ---------------- problem constants (match reference) ----------------
constexpr int F_IN = 256;
constexpr int H1 = 4, D1 = 32, F1 = H1 * D1;   // 128
constexpr int H2 = 1, D2 = 32, F2 = H2 * D2;   // 32
constexpr float NEG = 0.2f;

typedef short short8 __attribute__((ext_vector_type(8)));
typedef float f32x4 __attribute__((ext_vector_type(4)));

// ---------------- CSR build ----------------
__global__ void hist_kernel(const int* __restrict__ dst, int* __restrict__ deg, int E) {
    int e = blockIdx.x * 256 + threadIdx.x;
    if (e < E) atomicAdd(&deg[dst[e]], 1);
}

// generic small scan (used for the 49 block sums): 1 block, 1024 threads
__global__ void scan_kernel(const int* __restrict__ deg, int* __restrict__ off, int n) {
    __shared__ int sums[1024];
    int tid = threadIdx.x;
    int chunk = (n + 1023) / 1024;
    int start = tid * chunk;
    int end = min(start + chunk, n);
    int local = 0;
    for (int i = start; i < end; ++i) local += deg[i];
    sums[tid] = local;
    __syncthreads();
    for (int o = 1; o < 1024; o <<= 1) {
        int v = (tid >= o) ? sums[tid - o] : 0;
        __syncthreads();
        sums[tid] += v;
        __syncthreads();
    }
    int run = sums[tid] - local;           // exclusive prefix
    for (int i = start; i < end; ++i) { off[i] = run; run += deg[i]; }
    if (tid == 0) off[n] = sums[1023];
}

// phase 1: per-block (1024-elem) sums
__global__ __launch_bounds__(256) void scan_p1(const int* __restrict__ deg,
                                               int* __restrict__ bsum, int n) {
    int tid = threadIdx.x;
    int i0 = blockIdx.x * 1024 + tid * 4;
    int s = 0;
    if (i0 + 3 < n) {
        int4 v = *(const int4*)(deg + i0);
        s = v.x + v.y + v.z + v.w;
    } else {
        for (int j = 0; j < 4; ++j) if (i0 + j < n) s += deg[i0 + j];
    }
#pragma unroll
    for (int o = 1; o < 64; o <<= 1) s += __shfl_xor(s, o);
    __shared__ int ws[4];
    int lane = tid & 63, w = tid >> 6;
    if (lane == 0) ws[w] = s;
    __syncthreads();
    if (tid == 0) bsum[blockIdx.x] = ws[0] + ws[1] + ws[2] + ws[3];
}

// phase 3: local exclusive scan + scanned block base -> off[]
__global__ __launch_bounds__(256) void scan_p3(const int* __restrict__ deg,
                                               const int* __restrict__ bscan,
                                               int* __restrict__ off, int n, int total) {
    int tid = threadIdx.x;
    int i0 = blockIdx.x * 1024 + tid * 4;
    int v[4] = {0, 0, 0, 0};
    if (i0 + 3 < n) {
        int4 t = *(const int4*)(deg + i0);
        v[0] = t.x; v[1] = t.y; v[2] = t.z; v[3] = t.w;
    } else {
        for (int j = 0; j < 4; ++j) if (i0 + j < n) v[j] = deg[i0 + j];
    }
    int tsum = v[0] + v[1] + v[2] + v[3];
    int lane = tid & 63, w = tid >> 6;
    int incl = tsum;
#pragma unroll
    for (int o = 1; o < 64; o <<= 1) {
        int t = __shfl_up(incl, o);
        if (lane >= o) incl += t;
    }
    __shared__ int ws[4];
    if (lane == 63) ws[w] = incl;
    __syncthreads();
    int woff = 0;
#pragma unroll
    for (int i = 0; i < 4; ++i) if (i < w) woff += ws[i];
    int excl = bscan[blockIdx.x] + woff + incl - tsum;
#pragma unroll
    for (int j = 0; j < 4; ++j) {
        if (i0 + j < n) off[i0 + j] = excl;
        excl += v[j];
    }
    if (blockIdx.x == 0 && tid == 0) off[n] = total;
}

__global__ void scatter_kernel(const int* __restrict__ src, const int* __restrict__ dst,
                               const int* __restrict__ off, int* __restrict__ pos,
                               int* __restrict__ csr_src, int E) {
    int e = blockIdx.x * 256 + threadIdx.x;
    if (e < E) {
        int d = dst[e];
        int p = off[d] + atomicAdd(&pos[d], 1);
        csr_src[p] = src[e];
    }
}

// ---------------- W split: W[K][C] f32 -> Wh_t/Wl_t [C][K] bf16 hi/lo ----------------
__global__ void wsplit_kernel(const float* __restrict__ W,
                              unsigned short* __restrict__ Wh,
                              unsigned short* __restrict__ Wl, int K, int C) {
    int idx = blockIdx.x * 256 + threadIdx.x;
    if (idx >= K * C) return;
    int k = idx / C, c = idx % C;
    float v = W[idx];
    __bf16 h = (__bf16)v;
    float hv = (float)h;
    __bf16 lo = (__bf16)(v - hv);
    Wh[(size_t)c * K + k] = __builtin_bit_cast(unsigned short, h);
    Wl[(size_t)c * K + k] = __builtin_bit_cast(unsigned short, lo);
}

// ---------------- Layer-1 GEMM via split-bf16 MFMA ----------------
__global__ __launch_bounds__(256) void gemm1_mfma(
    const float* __restrict__ X,
    const unsigned short* __restrict__ Wh,
    const unsigned short* __restrict__ Wl,
    float* __restrict__ out, int n)
{
    const int lane = threadIdx.x & 63;
    const int wid  = threadIdx.x >> 6;
    const int wrow = (wid >> 1) * 32;       // 0 or 32
    const int wcol = (wid & 1) * 64;        // 0 or 64
    const int row0 = blockIdx.x * 64;
    const int l16  = lane & 15;
    const int khi  = lane >> 4;             // 0..3

    f32x4 acc[2][4];
#pragma unroll
    for (int mi = 0; mi < 2; ++mi)
#pragma unroll
        for (int ni = 0; ni < 4; ++ni) acc[mi][ni] = f32x4{0.f, 0.f, 0.f, 0.f};

    int ar[2];
#pragma unroll
    for (int mi = 0; mi < 2; ++mi) {
        int r = row0 + wrow + mi * 16 + l16;
        ar[mi] = r < n ? r : (n - 1);       // clamp loads; stores guarded
    }
    int bc[4];
#pragma unroll
    for (int ni = 0; ni < 4; ++ni) bc[ni] = wcol + ni * 16 + l16;

#pragma unroll 2
    for (int ks = 0; ks < 8; ++ks) {
        const int kbase = ks * 32 + khi * 8;

        short8 ah[2], al[2];
#pragma unroll
        for (int mi = 0; mi < 2; ++mi) {
            const float* ap = X + (size_t)ar[mi] * F_IN + kbase;
            float4 p0 = *(const float4*)ap;
            float4 p1 = *(const float4*)(ap + 4);
            float v[8] = {p0.x, p0.y, p0.z, p0.w, p1.x, p1.y, p1.z, p1.w};
#pragma unroll
            for (int j = 0; j < 8; ++j) {
                __bf16 h = (__bf16)v[j];
                float hv = (float)h;
                __bf16 lo = (__bf16)(v[j] - hv);
                ah[mi][j] = __builtin_bit_cast(short, h);
                al[mi][j] = __builtin_bit_cast(short, lo);
            }
        }

        short8 bh[4], bl[4];
#pragma unroll
        for (int ni = 0; ni < 4; ++ni) {
            bh[ni] = *(const short8*)(Wh + (size_t)bc[ni] * F_IN + kbase);
            bl[ni] = *(const short8*)(Wl + (size_t)bc[ni] * F_IN + kbase);
        }

#pragma unroll
        for (int mi = 0; mi < 2; ++mi)
#pragma unroll
            for (int ni = 0; ni < 4; ++ni) {
                acc[mi][ni] = __builtin_amdgcn_mfma_f32_16x16x32_bf16(al[mi], bh[ni], acc[mi][ni], 0, 0, 0);
                acc[mi][ni] = __builtin_amdgcn_mfma_f32_16x16x32_bf16(ah[mi], bl[ni], acc[mi][ni], 0, 0, 0);
                acc[mi][ni] = __builtin_amdgcn_mfma_f32_16x16x32_bf16(ah[mi], bh[ni], acc[mi][ni], 0, 0, 0);
            }
    }

#pragma unroll
    for (int mi = 0; mi < 2; ++mi) {
        int rbase = row0 + wrow + mi * 16 + khi * 4;
#pragma unroll
        for (int r = 0; r < 4; ++r) {
            int row = rbase + r;
            if (row < n) {
#pragma unroll
                for (int ni = 0; ni < 4; ++ni)
                    out[(size_t)row * F1 + wcol + ni * 16 + l16] = acc[mi][ni][r];
            }
        }
    }
}

// ---------------- Register-blocked f32 GEMM (layer 2) ----------------
template <int IN, int OUT, int BM, int BN, int TN, int KT>
__global__ __launch_bounds__(256) void gemm_rb(const float* __restrict__ X,
                                               const float* __restrict__ W,
                                               float* __restrict__ out, int n)
{
    constexpr int TM = 4;
    constexpr int RBLK = BM / TM;
    constexpr int CBLK = BN / TN;
    static_assert(RBLK * CBLK == 256, "block mapping");
    static_assert(BN == OUT, "full-width tiles");
    __shared__ float xs[KT][BM];
    __shared__ float ws[KT][BN];

    const int tid = threadIdx.x;
    const int rblk = tid % RBLK;
    const int cblk = tid / RBLK;
    const int row0 = blockIdx.x * BM;

    float acc[TM][TN];
#pragma unroll
    for (int i = 0; i < TM; ++i)
#pragma unroll
        for (int j = 0; j < TN; ++j) acc[i][j] = 0.f;

    constexpr int XQ = BM * KT / 4 / 256;
    constexpr int WQ = KT * BN / 4 / 256;
    float4 xreg[XQ], wreg[WQ];

    auto load_slice = [&](int k0) {
#pragma unroll
        for (int i = 0; i < XQ; ++i) {
            int idx = tid + i * 256;
            int xrow = idx % BM, xkc = idx / BM;
            int grow = row0 + xrow;
            if (grow < n)
                xreg[i] = *(const float4*)(X + (size_t)grow * IN + k0 + xkc * 4);
            else
                xreg[i] = float4{0.f, 0.f, 0.f, 0.f};
        }
#pragma unroll
        for (int i = 0; i < WQ; ++i) {
            int idx = tid + i * 256;
            int wk = idx / (BN / 4), wc4 = idx % (BN / 4);
            wreg[i] = *(const float4*)(W + (size_t)(k0 + wk) * OUT + wc4 * 4);
        }
    };
    auto store_slice = [&]() {
#pragma unroll
        for (int i = 0; i < XQ; ++i) {
            int idx = tid + i * 256;
            int xrow = idx % BM, xkc = idx / BM;
            xs[xkc * 4 + 0][xrow] = xreg[i].x;
            xs[xkc * 4 + 1][xrow] = xreg[i].y;
            xs[xkc * 4 + 2][xrow] = xreg[i].z;
            xs[xkc * 4 + 3][xrow] = xreg[i].w;
        }
#pragma unroll
        for (int i = 0; i < WQ; ++i) {
            int idx = tid + i * 256;
            int wk = idx / (BN / 4), wc4 = idx % (BN / 4);
            *(float4*)&ws[wk][wc4 * 4] = wreg[i];
        }
    };

    load_slice(0);
    int k0 = 0;
    while (true) {
        __syncthreads();
        store_slice();
        __syncthreads();
        int knext = k0 + KT;
        if (knext < IN) load_slice(knext);
#pragma unroll
        for (int kk = 0; kk < KT; ++kk) {
            float4 xv = *(const float4*)&xs[kk][rblk * 4];
            float xa[TM] = {xv.x, xv.y, xv.z, xv.w};
            float wv[TN];
#pragma unroll
            for (int j = 0; j < TN; j += 4) {
                float4 t = *(const float4*)&ws[kk][cblk * TN + j];
                wv[j] = t.x; wv[j + 1] = t.y; wv[j + 2] = t.z; wv[j + 3] = t.w;
            }
#pragma unroll
            for (int i2 = 0; i2 < TM; ++i2)
#pragma unroll
                for (int j = 0; j < TN; ++j)
                    acc[i2][j] = fmaf(xa[i2], wv[j], acc[i2][j]);
        }
        k0 = knext;
        if (k0 >= IN) break;
    }

#pragma unroll
    for (int i2 = 0; i2 < TM; ++i2) {
        int row = row0 + rblk * TM + i2;
        if (row < n) {
#pragma unroll
            for (int j = 0; j < TN; j += 4) {
                float4 t = {acc[i2][j], acc[i2][j + 1], acc[i2][j + 2], acc[i2][j + 3]};
                *(float4*)(out + (size_t)row * OUT + cblk * TN + j) = t;
            }
        }
    }
}

// ---------------- el/er pass: per-head attention dots over feat ----------------
template <int F, int H>
__global__ __launch_bounds__(256) void elr_kernel(const float* __restrict__ feat,
                                                  const float* __restrict__ al,
                                                  const float* __restrict__ ar,
                                                  float* __restrict__ el,
                                                  float* __restrict__ er, int n)
{
    constexpr int LPN = F / 2;       // lanes per node
    constexpr int NPW = 64 / LPN;    // nodes per wave
    int wid = (blockIdx.x * 256 + threadIdx.x) >> 6;
    int lane = threadIdx.x & 63;
    int node = wid * NPW + lane / LPN;
    int l2 = lane % LPN;
    int c0 = l2 * 2;
    if (node >= n) return;
    float2 f = *(const float2*)(feat + (size_t)node * F + c0);
    float2 a = *(const float2*)(al + c0);
    float2 r = *(const float2*)(ar + c0);
    float pel = f.x * a.x + f.y * a.y;
    float per = f.x * r.x + f.y * r.y;
#pragma unroll
    for (int o = 1; o < 16; o <<= 1) {
        pel += __shfl_xor(pel, o);
        per += __shfl_xor(per, o);
    }
    if ((l2 & 15) == 0) {
        int h = c0 / 32;
        el[(size_t)node * H + h] = pel;
        er[(size_t)node * H + h] = per;
    }
}

// ---------------- Aggregation layer 1 ----------------
__global__ __launch_bounds__(256) void agg1_kernel(
    const int* __restrict__ off, const int* __restrict__ csr_src,
    const float* __restrict__ feat, const float* __restrict__ el,
    const float* __restrict__ er, const float* __restrict__ b,
    float* __restrict__ out, int n)
{
    int wid = (blockIdx.x * 256 + threadIdx.x) >> 6;   // node
    int lane = threadIdx.x & 63;
    if (wid >= n) return;
    int c0 = (lane & 31) * 4;         // 32 lanes cover 128 cols
    int h = (lane & 31) >> 3;         // c0 / 32
    int half = lane >> 5;
    float erv = er[(size_t)wid * H1 + h];
    float sw = 0.f;
    float4 acc = {0.f, 0.f, 0.f, 0.f};
    int jb = off[wid], je = off[wid + 1];
    int j = jb + half;
    for (; j + 2 < je; j += 4) {
        int s0 = csr_src[j];
        int s1 = csr_src[j + 2];
        float4 f0 = *(const float4*)(feat + (size_t)s0 * F1 + c0);
        float4 f1 = *(const float4*)(feat + (size_t)s1 * F1 + c0);
        float t0 = el[(size_t)s0 * H1 + h] + erv;
        float t1 = el[(size_t)s1 * H1 + h] + erv;
        t0 = t0 > 0.f ? t0 : NEG * t0;
        t1 = t1 > 0.f ? t1 : NEG * t1;
        float w0 = __expf(t0);
        float w1 = __expf(t1);
        sw += w0 + w1;
        acc.x = fmaf(w0, f0.x, fmaf(w1, f1.x, acc.x));
        acc.y = fmaf(w0, f0.y, fmaf(w1, f1.y, acc.y));
        acc.z = fmaf(w0, f0.z, fmaf(w1, f1.z, acc.z));
        acc.w = fmaf(w0, f0.w, fmaf(w1, f1.w, acc.w));
    }
    for (; j < je; j += 2) {
        int s = csr_src[j];
        float4 f = *(const float4*)(feat + (size_t)s * F1 + c0);
        float t = el[(size_t)s * H1 + h] + erv;
        t = t > 0.f ? t : NEG * t;
        float w = __expf(t);
        sw += w;
        acc.x = fmaf(w, f.x, acc.x);
        acc.y = fmaf(w, f.y, acc.y);
        acc.z = fmaf(w, f.z, acc.z);
        acc.w = fmaf(w, f.w, acc.w);
    }
    acc.x += __shfl_xor(acc.x, 32);
    acc.y += __shfl_xor(acc.y, 32);
    acc.z += __shfl_xor(acc.z, 32);
    acc.w += __shfl_xor(acc.w, 32);
    sw    += __shfl_xor(sw, 32);
    if (half == 0) {
        float inv = 1.f / fmaxf(sw, 1e-16f);
        float4 bb = *(const float4*)(b + c0);
        float4 t = {acc.x * inv + bb.x, acc.y * inv + bb.y,
                    acc.z * inv + bb.z, acc.w * inv + bb.w};
        *(float4*)(out + (size_t)wid * F1 + c0) = t;
    }
}

// ---------------- Aggregation layer 2 ----------------
__global__ __launch_bounds__(256) void agg2_kernel(
    const int* __restrict__ off, const int* __restrict__ csr_src,
    const float* __restrict__ feat, const float* __restrict__ el,
    const float* __restrict__ er, const float* __restrict__ b,
    float* __restrict__ out, int n)
{
    int wid = (blockIdx.x * 256 + threadIdx.x) >> 6;   // node
    int lane = threadIdx.x & 63;
    if (wid >= n) return;
    int c0 = (lane & 7) * 4;          // 8 lanes cover 32 cols
    int grp = lane >> 3;              // 8 edge groups
    float erv = er[wid];
    float sw = 0.f;
    float4 acc = {0.f, 0.f, 0.f, 0.f};
    int jb = off[wid], je = off[wid + 1];
    int j = jb + grp;
    for (; j + 8 < je; j += 16) {
        int s0 = csr_src[j];
        int s1 = csr_src[j + 8];
        float4 f0 = *(const float4*)(feat + (size_t)s0 * F2 + c0);
        float4 f1 = *(const float4*)(feat + (size_t)s1 * F2 + c0);
        float t0 = el[s0] + erv;
        float t1 = el[s1] + erv;
        t0 = t0 > 0.f ? t0 : NEG * t0;
        t1 = t1 > 0.f ? t1 : NEG * t1;
        float w0 = __expf(t0);
        float w1 = __expf(t1);
        sw += w0 + w1;
        acc.x = fmaf(w0, f0.x, fmaf(w1, f1.x, acc.x));
        acc.y = fmaf(w0, f0.y, fmaf(w1, f1.y, acc.y));
        acc.z = fmaf(w0, f0.z, fmaf(w1, f1.z, acc.z));
        acc.w = fmaf(w0, f0.w, fmaf(w1, f1.w, acc.w));
    }
    for (; j < je; j += 8) {
        int s = csr_src[j];
        float4 f = *(const float4*)(feat + (size_t)s * F2 + c0);
        float t = el[s] + erv;
        t = t > 0.f ? t : NEG * t;
        float w = __expf(t);
        sw += w;
        acc.x = fmaf(w, f.x, acc.x);
        acc.y = fmaf(w, f.y, acc.y);
        acc.z = fmaf(w, f.z, acc.z);
        acc.w = fmaf(w, f.w, acc.w);
    }
#pragma unroll
    for (int o = 8; o < 64; o <<= 1) {
        acc.x += __shfl_xor(acc.x, o);
        acc.y += __shfl_xor(acc.y, o);
        acc.z += __shfl_xor(acc.z, o);
        acc.w += __shfl_xor(acc.w, o);
        sw    += __shfl_xor(sw, o);
    }
    if (lane < 8) {
        float inv = 1.f / fmaxf(sw, 1e-16f);
        float4 bb = *(const float4*)(b + c0);
        float4 t = {acc.x * inv + bb.x, acc.y * inv + bb.y,
                    acc.z * inv + bb.z, acc.w * inv + bb.w};
        *(float4*)(out + (size_t)wid * F2 + c0) = t;
    }
}

// ---------------- launch ----------------
extern "C" void kernel_launch(void* const* d_in, const int* in_sizes, int n_in,
                              void* d_out, int out_size, void* d_ws, size_t ws_size,
                              hipStream_t stream) {
    const float* x   = (const float*)d_in[0];
    const float* W1  = (const float*)d_in[1];
    const float* al1 = (const float*)d_in[2];
    const float* ar1 = (const float*)d_in[3];
    const float* b1  = (const float*)d_in[4];
    const float* W2  = (const float*)d_in[5];
    const float* al2 = (const float*)d_in[6];
    const float* ar2 = (const float*)d_in[7];
    const float* b2  = (const float*)d_in[8];
    const int*   src = (const int*)d_in[9];
    const int*   dst = (const int*)d_in[10];

    const int N = in_sizes[0] / F_IN;
    const int E = in_sizes[9];
    const int NB = (N + 1023) / 1024;

    // workspace layout (256B-aligned regions)
    char* w = (char*)d_ws;
    size_t o = 0;
    auto alloc = [&](size_t bytes) { size_t cur = o; o += (bytes + 255) & ~255ULL; return cur; };
    int*   off   = (int*)  (w + alloc((size_t)(N + 1) * 4));
    int*   pos   = (int*)  (w + alloc((size_t)N * 4));
    int*   csr   = (int*)  (w + alloc((size_t)E * 4));
    float* feat1 = (float*)(w + alloc((size_t)N * F1 * 4));
    float* el1   = (float*)(w + alloc((size_t)N * H1 * 4));
    float* er1   = (float*)(w + alloc((size_t)N * H1 * 4));
    float* h1    = (float*)(w + alloc((size_t)N * F1 * 4));
    float* feat2 = (float*)(w + alloc((size_t)N * F2 * 4));
    float* el2   = (float*)(w + alloc((size_t)N * H2 * 4));
    float* er2   = (float*)(w + alloc((size_t)N * H2 * 4));
    unsigned short* W1h = (unsigned short*)(w + alloc((size_t)F_IN * F1 * 2));
    unsigned short* W1l = (unsigned short*)(w + alloc((size_t)F_IN * F1 * 2));
    int*   bsum  = (int*)  (w + alloc((size_t)(NB + 1) * 4));
    int*   bscan = (int*)  (w + alloc((size_t)(NB + 1) * 4));
    (void)ws_size; (void)n_in; (void)out_size;

    // ---- CSR build (shared by both layers) ----
    hipMemsetAsync(pos, 0, (size_t)N * 4, stream);
    hist_kernel<<<(E + 255) / 256, 256, 0, stream>>>(dst, pos, E);
    scan_p1<<<NB, 256, 0, stream>>>(pos, bsum, N);
    scan_kernel<<<1, 1024, 0, stream>>>(bsum, bscan, NB);
    scan_p3<<<NB, 256, 0, stream>>>(pos, bscan, off, N, E);
    hipMemsetAsync(pos, 0, (size_t)N * 4, stream);
    scatter_kernel<<<(E + 255) / 256, 256, 0, stream>>>(src, dst, off, pos, csr, E);

    // ---- layer 1: split-bf16 MFMA GEMM 50000x256x128 ----
    wsplit_kernel<<<(F_IN * F1 + 255) / 256, 256, 0, stream>>>(W1, W1h, W1l, F_IN, F1);
    gemm1_mfma<<<(N + 63) / 64, 256, 0, stream>>>(x, W1h, W1l, feat1, N);
    elr_kernel<F1, H1><<<(N + 3) / 4, 256, 0, stream>>>(feat1, al1, ar1, el1, er1, N);
    agg1_kernel<<<(N + 3) / 4, 256, 0, stream>>>(off, csr, feat1, el1, er1, b1, h1, N);

    // ---- layer 2: f32 GEMM 50000x128x32, tile 128x32, micro 4x4 ----
    gemm_rb<F1, F2, 128, 32, 4, 32><<<(N + 127) / 128, 256, 0, stream>>>(h1, W2, feat2, N);
    elr_kernel<F2, H2><<<(N + 15) / 16, 256, 0, stream>>>(feat2, al2, ar2, el2, er2, N);
    agg2_kernel<<<(N + 3) / 4, 256, 0, stream>>>(off, csr, feat2, el2, er2, b2, (float*)d_out, N);
}

// Round 6
// 226.387 us; speedup vs baseline: 1.9922x; 1.1186x over previous
//
#include <hip/hip_runtime.h>

// ---------------- problem constants (match reference) ----------------
constexpr int F_IN = 256;
constexpr int H1 = 4, D1 = 32, F1 = H1 * D1;   // 128
constexpr int H2 = 1, D2 = 32, F2 = H2 * D2;   // 32
constexpr float NEG = 0.2f;

typedef short short8 __attribute__((ext_vector_type(8)));
typedef float f32x4 __attribute__((ext_vector_type(4)));

__device__ inline float bf2f(unsigned short u) {
    unsigned int x = ((unsigned int)u) << 16;
    return __builtin_bit_cast(float, x);
}
__device__ inline unsigned short f2bf(float f) {
    __bf16 h = (__bf16)f;                      // RNE
    return __builtin_bit_cast(unsigned short, h);
}

// ---------------- CSR build ----------------
__global__ void hist_kernel(const int* __restrict__ dst, int* __restrict__ deg, int E) {
    int e = blockIdx.x * 256 + threadIdx.x;
    if (e < E) atomicAdd(&deg[dst[e]], 1);
}

// generic small scan (used for the ~49 block sums): 1 block, 1024 threads
__global__ void scan_kernel(const int* __restrict__ deg, int* __restrict__ off, int n) {
    __shared__ int sums[1024];
    int tid = threadIdx.x;
    int chunk = (n + 1023) / 1024;
    int start = tid * chunk;
    int end = min(start + chunk, n);
    int local = 0;
    for (int i = start; i < end; ++i) local += deg[i];
    sums[tid] = local;
    __syncthreads();
    for (int o = 1; o < 1024; o <<= 1) {
        int v = (tid >= o) ? sums[tid - o] : 0;
        __syncthreads();
        sums[tid] += v;
        __syncthreads();
    }
    int run = sums[tid] - local;           // exclusive prefix
    for (int i = start; i < end; ++i) { off[i] = run; run += deg[i]; }
    if (tid == 0) off[n] = sums[1023];
}

__global__ __launch_bounds__(256) void scan_p1(const int* __restrict__ deg,
                                               int* __restrict__ bsum, int n) {
    int tid = threadIdx.x;
    int i0 = blockIdx.x * 1024 + tid * 4;
    int s = 0;
    if (i0 + 3 < n) {
        int4 v = *(const int4*)(deg + i0);
        s = v.x + v.y + v.z + v.w;
    } else {
        for (int j = 0; j < 4; ++j) if (i0 + j < n) s += deg[i0 + j];
    }
#pragma unroll
    for (int o = 1; o < 64; o <<= 1) s += __shfl_xor(s, o);
    __shared__ int ws[4];
    int lane = tid & 63, w = tid >> 6;
    if (lane == 0) ws[w] = s;
    __syncthreads();
    if (tid == 0) bsum[blockIdx.x] = ws[0] + ws[1] + ws[2] + ws[3];
}

__global__ __launch_bounds__(256) void scan_p3(const int* __restrict__ deg,
                                               const int* __restrict__ bscan,
                                               int* __restrict__ off, int n, int total) {
    int tid = threadIdx.x;
    int i0 = blockIdx.x * 1024 + tid * 4;
    int v[4] = {0, 0, 0, 0};
    if (i0 + 3 < n) {
        int4 t = *(const int4*)(deg + i0);
        v[0] = t.x; v[1] = t.y; v[2] = t.z; v[3] = t.w;
    } else {
        for (int j = 0; j < 4; ++j) if (i0 + j < n) v[j] = deg[i0 + j];
    }
    int tsum = v[0] + v[1] + v[2] + v[3];
    int lane = tid & 63, w = tid >> 6;
    int incl = tsum;
#pragma unroll
    for (int o = 1; o < 64; o <<= 1) {
        int t = __shfl_up(incl, o);
        if (lane >= o) incl += t;
    }
    __shared__ int ws[4];
    if (lane == 63) ws[w] = incl;
    __syncthreads();
    int woff = 0;
#pragma unroll
    for (int i = 0; i < 4; ++i) if (i < w) woff += ws[i];
    int excl = bscan[blockIdx.x] + woff + incl - tsum;
#pragma unroll
    for (int j = 0; j < 4; ++j) {
        if (i0 + j < n) off[i0 + j] = excl;
        excl += v[j];
    }
    if (blockIdx.x == 0 && tid == 0) off[n] = total;
}

__global__ void scatter_kernel(const int* __restrict__ src, const int* __restrict__ dst,
                               const int* __restrict__ off, int* __restrict__ pos,
                               int* __restrict__ csr_src, int E) {
    int e = blockIdx.x * 256 + threadIdx.x;
    if (e < E) {
        int d = dst[e];
        int p = off[d] + atomicAdd(&pos[d], 1);
        csr_src[p] = src[e];
    }
}

// ---------------- W split: W[K][C] f32 -> Wh_t/Wl_t [C][K] bf16 hi/lo ----------------
__global__ void wsplit_kernel(const float* __restrict__ W,
                              unsigned short* __restrict__ Wh,
                              unsigned short* __restrict__ Wl, int K, int C) {
    int idx = blockIdx.x * 256 + threadIdx.x;
    if (idx >= K * C) return;
    int k = idx / C, c = idx % C;
    float v = W[idx];
    __bf16 h = (__bf16)v;
    float hv = (float)h;
    __bf16 lo = (__bf16)(v - hv);
    Wh[(size_t)c * K + k] = __builtin_bit_cast(unsigned short, h);
    Wl[(size_t)c * K + k] = __builtin_bit_cast(unsigned short, lo);
}

// ---------------- Layer-1 GEMM via split-bf16 MFMA; epilogue stores bf16 ----------------
__global__ __launch_bounds__(256) void gemm1_mfma(
    const float* __restrict__ X,
    const unsigned short* __restrict__ Wh,
    const unsigned short* __restrict__ Wl,
    unsigned short* __restrict__ outb, int n)
{
    const int lane = threadIdx.x & 63;
    const int wid  = threadIdx.x >> 6;
    const int wrow = (wid >> 1) * 32;       // 0 or 32
    const int wcol = (wid & 1) * 64;        // 0 or 64
    const int row0 = blockIdx.x * 64;
    const int l16  = lane & 15;
    const int khi  = lane >> 4;             // 0..3

    f32x4 acc[2][4];
#pragma unroll
    for (int mi = 0; mi < 2; ++mi)
#pragma unroll
        for (int ni = 0; ni < 4; ++ni) acc[mi][ni] = f32x4{0.f, 0.f, 0.f, 0.f};

    int ar[2];
#pragma unroll
    for (int mi = 0; mi < 2; ++mi) {
        int r = row0 + wrow + mi * 16 + l16;
        ar[mi] = r < n ? r : (n - 1);       // clamp loads; stores guarded
    }
    int bc[4];
#pragma unroll
    for (int ni = 0; ni < 4; ++ni) bc[ni] = wcol + ni * 16 + l16;

#pragma unroll 2
    for (int ks = 0; ks < 8; ++ks) {
        const int kbase = ks * 32 + khi * 8;

        short8 ah[2], al[2];
#pragma unroll
        for (int mi = 0; mi < 2; ++mi) {
            const float* ap = X + (size_t)ar[mi] * F_IN + kbase;
            float4 p0 = *(const float4*)ap;
            float4 p1 = *(const float4*)(ap + 4);
            float v[8] = {p0.x, p0.y, p0.z, p0.w, p1.x, p1.y, p1.z, p1.w};
#pragma unroll
            for (int j = 0; j < 8; ++j) {
                __bf16 h = (__bf16)v[j];
                float hv = (float)h;
                __bf16 lo = (__bf16)(v[j] - hv);
                ah[mi][j] = __builtin_bit_cast(short, h);
                al[mi][j] = __builtin_bit_cast(short, lo);
            }
        }

        short8 bh[4], bl[4];
#pragma unroll
        for (int ni = 0; ni < 4; ++ni) {
            bh[ni] = *(const short8*)(Wh + (size_t)bc[ni] * F_IN + kbase);
            bl[ni] = *(const short8*)(Wl + (size_t)bc[ni] * F_IN + kbase);
        }

#pragma unroll
        for (int mi = 0; mi < 2; ++mi)
#pragma unroll
            for (int ni = 0; ni < 4; ++ni) {
                acc[mi][ni] = __builtin_amdgcn_mfma_f32_16x16x32_bf16(al[mi], bh[ni], acc[mi][ni], 0, 0, 0);
                acc[mi][ni] = __builtin_amdgcn_mfma_f32_16x16x32_bf16(ah[mi], bl[ni], acc[mi][ni], 0, 0, 0);
                acc[mi][ni] = __builtin_amdgcn_mfma_f32_16x16x32_bf16(ah[mi], bh[ni], acc[mi][ni], 0, 0, 0);
            }
    }

#pragma unroll
    for (int mi = 0; mi < 2; ++mi) {
        int rbase = row0 + wrow + mi * 16 + khi * 4;
#pragma unroll
        for (int r = 0; r < 4; ++r) {
            int row = rbase + r;
            if (row < n) {
#pragma unroll
                for (int ni = 0; ni < 4; ++ni)
                    outb[(size_t)row * F1 + wcol + ni * 16 + l16] = f2bf(acc[mi][ni][r]);
            }
        }
    }
}

// ---------------- Layer-2 GEMM via split-bf16 MFMA (IN=128, OUT=32), f32 out ----------------
__global__ __launch_bounds__(256) void gemm2_mfma(
    const float* __restrict__ X,
    const unsigned short* __restrict__ Wh,
    const unsigned short* __restrict__ Wl,
    float* __restrict__ out, int n)
{
    const int lane = threadIdx.x & 63;
    const int wid  = threadIdx.x >> 6;
    const int wrow = wid * 32;
    const int row0 = blockIdx.x * 128;
    const int l16  = lane & 15;
    const int khi  = lane >> 4;

    f32x4 acc[2][2];
#pragma unroll
    for (int mi = 0; mi < 2; ++mi)
#pragma unroll
        for (int ni = 0; ni < 2; ++ni) acc[mi][ni] = f32x4{0.f, 0.f, 0.f, 0.f};

    int ar[2];
#pragma unroll
    for (int mi = 0; mi < 2; ++mi) {
        int r = row0 + wrow + mi * 16 + l16;
        ar[mi] = r < n ? r : (n - 1);
    }
    int bc[2];
#pragma unroll
    for (int ni = 0; ni < 2; ++ni) bc[ni] = ni * 16 + l16;

#pragma unroll
    for (int ks = 0; ks < 4; ++ks) {
        const int kbase = ks * 32 + khi * 8;

        short8 ah[2], al[2];
#pragma unroll
        for (int mi = 0; mi < 2; ++mi) {
            const float* ap = X + (size_t)ar[mi] * F1 + kbase;
            float4 p0 = *(const float4*)ap;
            float4 p1 = *(const float4*)(ap + 4);
            float v[8] = {p0.x, p0.y, p0.z, p0.w, p1.x, p1.y, p1.z, p1.w};
#pragma unroll
            for (int j = 0; j < 8; ++j) {
                __bf16 h = (__bf16)v[j];
                float hv = (float)h;
                __bf16 lo = (__bf16)(v[j] - hv);
                ah[mi][j] = __builtin_bit_cast(short, h);
                al[mi][j] = __builtin_bit_cast(short, lo);
            }
        }

        short8 bh[2], bl[2];
#pragma unroll
        for (int ni = 0; ni < 2; ++ni) {
            bh[ni] = *(const short8*)(Wh + (size_t)bc[ni] * F1 + kbase);
            bl[ni] = *(const short8*)(Wl + (size_t)bc[ni] * F1 + kbase);
        }

#pragma unroll
        for (int mi = 0; mi < 2; ++mi)
#pragma unroll
            for (int ni = 0; ni < 2; ++ni) {
                acc[mi][ni] = __builtin_amdgcn_mfma_f32_16x16x32_bf16(al[mi], bh[ni], acc[mi][ni], 0, 0, 0);
                acc[mi][ni] = __builtin_amdgcn_mfma_f32_16x16x32_bf16(ah[mi], bl[ni], acc[mi][ni], 0, 0, 0);
                acc[mi][ni] = __builtin_amdgcn_mfma_f32_16x16x32_bf16(ah[mi], bh[ni], acc[mi][ni], 0, 0, 0);
            }
    }

#pragma unroll
    for (int mi = 0; mi < 2; ++mi) {
        int rbase = row0 + wrow + mi * 16 + khi * 4;
#pragma unroll
        for (int r = 0; r < 4; ++r) {
            int row = rbase + r;
            if (row < n) {
#pragma unroll
                for (int ni = 0; ni < 2; ++ni)
                    out[(size_t)row * F2 + ni * 16 + l16] = acc[mi][ni][r];
            }
        }
    }
}

// ---------------- el/er pass over bf16 feat (layer 1) ----------------
template <int F, int H>
__global__ __launch_bounds__(256) void elr_bf16(const unsigned short* __restrict__ featb,
                                                const float* __restrict__ al,
                                                const float* __restrict__ ar,
                                                float* __restrict__ el,
                                                float* __restrict__ er, int n)
{
    constexpr int LPN = F / 4;       // lanes per node (32 for F=128)
    constexpr int NPW = 64 / LPN;
    int wid = (blockIdx.x * 256 + threadIdx.x) >> 6;
    int lane = threadIdx.x & 63;
    int node = wid * NPW + lane / LPN;
    int l2 = lane % LPN;
    int c0 = l2 * 4;
    if (node >= n) return;
    ushort4 u = *(const ushort4*)(featb + (size_t)node * F + c0);
    float f0 = bf2f(u.x), f1 = bf2f(u.y), f2 = bf2f(u.z), f3 = bf2f(u.w);
    float4 a = *(const float4*)(al + c0);
    float4 r = *(const float4*)(ar + c0);
    float pel = f0 * a.x + f1 * a.y + f2 * a.z + f3 * a.w;
    float per = f0 * r.x + f1 * r.y + f2 * r.z + f3 * r.w;
#pragma unroll
    for (int o = 1; o < 8; o <<= 1) {    // head = 32 cols = 8 lanes
        pel += __shfl_xor(pel, o);
        per += __shfl_xor(per, o);
    }
    if ((l2 & 7) == 0) {
        int h = c0 / 32;
        el[(size_t)node * H + h] = pel;
        er[(size_t)node * H + h] = per;
    }
}

// ---------------- el/er pass over f32 feat (layer 2) ----------------
template <int F, int H>
__global__ __launch_bounds__(256) void elr_kernel(const float* __restrict__ feat,
                                                  const float* __restrict__ al,
                                                  const float* __restrict__ ar,
                                                  float* __restrict__ el,
                                                  float* __restrict__ er, int n)
{
    constexpr int LPN = F / 2;       // lanes per node
    constexpr int NPW = 64 / LPN;    // nodes per wave
    int wid = (blockIdx.x * 256 + threadIdx.x) >> 6;
    int lane = threadIdx.x & 63;
    int node = wid * NPW + lane / LPN;
    int l2 = lane % LPN;
    int c0 = l2 * 2;
    if (node >= n) return;
    float2 f = *(const float2*)(feat + (size_t)node * F + c0);
    float2 a = *(const float2*)(al + c0);
    float2 r = *(const float2*)(ar + c0);
    float pel = f.x * a.x + f.y * a.y;
    float per = f.x * r.x + f.y * r.y;
#pragma unroll
    for (int o = 1; o < 16; o <<= 1) {
        pel += __shfl_xor(pel, o);
        per += __shfl_xor(per, o);
    }
    if ((l2 & 15) == 0) {
        int h = c0 / 32;
        el[(size_t)node * H + h] = pel;
        er[(size_t)node * H + h] = per;
    }
}

// ---------------- Aggregation layer 1: bf16 gather, 8 edges in flight ----------------
__global__ __launch_bounds__(256) void agg1_kernel(
    const int* __restrict__ off, const int* __restrict__ csr_src,
    const unsigned short* __restrict__ featb, const float* __restrict__ el,
    const float* __restrict__ er, const float* __restrict__ b,
    float* __restrict__ out, int n)
{
    int wid = (blockIdx.x * 256 + threadIdx.x) >> 6;   // node
    int lane = threadIdx.x & 63;
    if (wid >= n) return;
    int c0 = (lane & 31) * 4;         // 32 lanes cover 128 cols
    int h = (lane & 31) >> 3;         // c0 / 32
    int half = lane >> 5;
    float erv = er[(size_t)wid * H1 + h];
    float sw = 0.f;
    float4 acc = {0.f, 0.f, 0.f, 0.f};
    int jb = off[wid], je = off[wid + 1];
    int j = jb + half;
    for (; j + 6 < je; j += 8) {
        int s0 = csr_src[j];
        int s1 = csr_src[j + 2];
        int s2 = csr_src[j + 4];
        int s3 = csr_src[j + 6];
        ushort4 u0 = *(const ushort4*)(featb + (size_t)s0 * F1 + c0);
        ushort4 u1 = *(const ushort4*)(featb + (size_t)s1 * F1 + c0);
        ushort4 u2 = *(const ushort4*)(featb + (size_t)s2 * F1 + c0);
        ushort4 u3 = *(const ushort4*)(featb + (size_t)s3 * F1 + c0);
        float t0 = el[(size_t)s0 * H1 + h] + erv;
        float t1 = el[(size_t)s1 * H1 + h] + erv;
        float t2 = el[(size_t)s2 * H1 + h] + erv;
        float t3 = el[(size_t)s3 * H1 + h] + erv;
        t0 = t0 > 0.f ? t0 : NEG * t0;
        t1 = t1 > 0.f ? t1 : NEG * t1;
        t2 = t2 > 0.f ? t2 : NEG * t2;
        t3 = t3 > 0.f ? t3 : NEG * t3;
        float w0 = __expf(t0), w1 = __expf(t1), w2 = __expf(t2), w3 = __expf(t3);
        sw += (w0 + w1) + (w2 + w3);
        acc.x = fmaf(w0, bf2f(u0.x), fmaf(w1, bf2f(u1.x), fmaf(w2, bf2f(u2.x), fmaf(w3, bf2f(u3.x), acc.x))));
        acc.y = fmaf(w0, bf2f(u0.y), fmaf(w1, bf2f(u1.y), fmaf(w2, bf2f(u2.y), fmaf(w3, bf2f(u3.y), acc.y))));
        acc.z = fmaf(w0, bf2f(u0.z), fmaf(w1, bf2f(u1.z), fmaf(w2, bf2f(u2.z), fmaf(w3, bf2f(u3.z), acc.z))));
        acc.w = fmaf(w0, bf2f(u0.w), fmaf(w1, bf2f(u1.w), fmaf(w2, bf2f(u2.w), fmaf(w3, bf2f(u3.w), acc.w))));
    }
    for (; j < je; j += 2) {
        int s = csr_src[j];
        ushort4 u = *(const ushort4*)(featb + (size_t)s * F1 + c0);
        float t = el[(size_t)s * H1 + h] + erv;
        t = t > 0.f ? t : NEG * t;
        float w = __expf(t);
        sw += w;
        acc.x = fmaf(w, bf2f(u.x), acc.x);
        acc.y = fmaf(w, bf2f(u.y), acc.y);
        acc.z = fmaf(w, bf2f(u.z), acc.z);
        acc.w = fmaf(w, bf2f(u.w), acc.w);
    }
    acc.x += __shfl_xor(acc.x, 32);
    acc.y += __shfl_xor(acc.y, 32);
    acc.z += __shfl_xor(acc.z, 32);
    acc.w += __shfl_xor(acc.w, 32);
    sw    += __shfl_xor(sw, 32);
    if (half == 0) {
        float inv = 1.f / fmaxf(sw, 1e-16f);
        float4 bb = *(const float4*)(b + c0);
        float4 t = {acc.x * inv + bb.x, acc.y * inv + bb.y,
                    acc.z * inv + bb.z, acc.w * inv + bb.w};
        *(float4*)(out + (size_t)wid * F1 + c0) = t;
    }
}

// ---------------- Aggregation layer 2: f32 gather, 16 edges in flight ----------------
__global__ __launch_bounds__(256) void agg2_kernel(
    const int* __restrict__ off, const int* __restrict__ csr_src,
    const float* __restrict__ feat, const float* __restrict__ el,
    const float* __restrict__ er, const float* __restrict__ b,
    float* __restrict__ out, int n)
{
    int wid = (blockIdx.x * 256 + threadIdx.x) >> 6;   // node
    int lane = threadIdx.x & 63;
    if (wid >= n) return;
    int c0 = (lane & 7) * 4;          // 8 lanes cover 32 cols
    int grp = lane >> 3;              // 8 edge groups
    float erv = er[wid];
    float sw = 0.f;
    float4 acc = {0.f, 0.f, 0.f, 0.f};
    int jb = off[wid], je = off[wid + 1];
    int j = jb + grp;
    for (; j + 8 < je; j += 16) {
        int s0 = csr_src[j];
        int s1 = csr_src[j + 8];
        float4 f0 = *(const float4*)(feat + (size_t)s0 * F2 + c0);
        float4 f1 = *(const float4*)(feat + (size_t)s1 * F2 + c0);
        float t0 = el[s0] + erv;
        float t1 = el[s1] + erv;
        t0 = t0 > 0.f ? t0 : NEG * t0;
        t1 = t1 > 0.f ? t1 : NEG * t1;
        float w0 = __expf(t0);
        float w1 = __expf(t1);
        sw += w0 + w1;
        acc.x = fmaf(w0, f0.x, fmaf(w1, f1.x, acc.x));
        acc.y = fmaf(w0, f0.y, fmaf(w1, f1.y, acc.y));
        acc.z = fmaf(w0, f0.z, fmaf(w1, f1.z, acc.z));
        acc.w = fmaf(w0, f0.w, fmaf(w1, f1.w, acc.w));
    }
    for (; j < je; j += 8) {
        int s = csr_src[j];
        float4 f = *(const float4*)(feat + (size_t)s * F2 + c0);
        float t = el[s] + erv;
        t = t > 0.f ? t : NEG * t;
        float w = __expf(t);
        sw += w;
        acc.x = fmaf(w, f.x, acc.x);
        acc.y = fmaf(w, f.y, acc.y);
        acc.z = fmaf(w, f.z, acc.z);
        acc.w = fmaf(w, f.w, acc.w);
    }
#pragma unroll
    for (int o = 8; o < 64; o <<= 1) {
        acc.x += __shfl_xor(acc.x, o);
        acc.y += __shfl_xor(acc.y, o);
        acc.z += __shfl_xor(acc.z, o);
        acc.w += __shfl_xor(acc.w, o);
        sw    += __shfl_xor(sw, o);
    }
    if (lane < 8) {
        float inv = 1.f / fmaxf(sw, 1e-16f);
        float4 bb = *(const float4*)(b + c0);
        float4 t = {acc.x * inv + bb.x, acc.y * inv + bb.y,
                    acc.z * inv + bb.z, acc.w * inv + bb.w};
        *(float4*)(out + (size_t)wid * F2 + c0) = t;
    }
}

// ---------------- launch ----------------
extern "C" void kernel_launch(void* const* d_in, const int* in_sizes, int n_in,
                              void* d_out, int out_size, void* d_ws, size_t ws_size,
                              hipStream_t stream) {
    const float* x   = (const float*)d_in[0];
    const float* W1  = (const float*)d_in[1];
    const float* al1 = (const float*)d_in[2];
    const float* ar1 = (const float*)d_in[3];
    const float* b1  = (const float*)d_in[4];
    const float* W2  = (const float*)d_in[5];
    const float* al2 = (const float*)d_in[6];
    const float* ar2 = (const float*)d_in[7];
    const float* b2  = (const float*)d_in[8];
    const int*   src = (const int*)d_in[9];
    const int*   dst = (const int*)d_in[10];

    const int N = in_sizes[0] / F_IN;
    const int E = in_sizes[9];
    const int NB = (N + 1023) / 1024;

    // workspace layout (256B-aligned regions)
    char* w = (char*)d_ws;
    size_t o = 0;
    auto alloc = [&](size_t bytes) { size_t cur = o; o += (bytes + 255) & ~255ULL; return cur; };
    int*   off   = (int*)  (w + alloc((size_t)(N + 1) * 4));
    int*   pos   = (int*)  (w + alloc((size_t)N * 4));
    int*   csr   = (int*)  (w + alloc((size_t)E * 4));
    unsigned short* feat1b = (unsigned short*)(w + alloc((size_t)N * F1 * 2));
    float* el1   = (float*)(w + alloc((size_t)N * H1 * 4));
    float* er1   = (float*)(w + alloc((size_t)N * H1 * 4));
    float* h1    = (float*)(w + alloc((size_t)N * F1 * 4));
    float* feat2 = (float*)(w + alloc((size_t)N * F2 * 4));
    float* el2   = (float*)(w + alloc((size_t)N * H2 * 4));
    float* er2   = (float*)(w + alloc((size_t)N * H2 * 4));
    unsigned short* W1h = (unsigned short*)(w + alloc((size_t)F_IN * F1 * 2));
    unsigned short* W1l = (unsigned short*)(w + alloc((size_t)F_IN * F1 * 2));
    unsigned short* W2h = (unsigned short*)(w + alloc((size_t)F1 * F2 * 2));
    unsigned short* W2l = (unsigned short*)(w + alloc((size_t)F1 * F2 * 2));
    int*   bsum  = (int*)  (w + alloc((size_t)(NB + 1) * 4));
    int*   bscan = (int*)  (w + alloc((size_t)(NB + 1) * 4));
    (void)ws_size; (void)n_in; (void)out_size;

    // ---- CSR build (shared by both layers) ----
    hipMemsetAsync(pos, 0, (size_t)N * 4, stream);
    hist_kernel<<<(E + 255) / 256, 256, 0, stream>>>(dst, pos, E);
    scan_p1<<<NB, 256, 0, stream>>>(pos, bsum, N);
    scan_kernel<<<1, 1024, 0, stream>>>(bsum, bscan, NB);
    scan_p3<<<NB, 256, 0, stream>>>(pos, bscan, off, N, E);
    hipMemsetAsync(pos, 0, (size_t)N * 4, stream);
    scatter_kernel<<<(E + 255) / 256, 256, 0, stream>>>(src, dst, off, pos, csr, E);

    // ---- weight splits ----
    wsplit_kernel<<<(F_IN * F1 + 255) / 256, 256, 0, stream>>>(W1, W1h, W1l, F_IN, F1);
    wsplit_kernel<<<(F1 * F2 + 255) / 256, 256, 0, stream>>>(W2, W2h, W2l, F1, F2);

    // ---- layer 1 ----
    gemm1_mfma<<<(N + 63) / 64, 256, 0, stream>>>(x, W1h, W1l, feat1b, N);
    elr_bf16<F1, H1><<<(N + 7) / 8, 256, 0, stream>>>(feat1b, al1, ar1, el1, er1, N);
    agg1_kernel<<<(N + 3) / 4, 256, 0, stream>>>(off, csr, feat1b, el1, er1, b1, h1, N);

    // ---- layer 2 ----
    gemm2_mfma<<<(N + 127) / 128, 256, 0, stream>>>(h1, W2h, W2l, feat2, N);
    elr_kernel<F2, H2><<<(N + 15) / 16, 256, 0, stream>>>(feat2, al2, ar2, el2, er2, N);
    agg2_kernel<<<(N + 3) / 4, 256, 0, stream>>>(off, csr, feat2, el2, er2, b2, (float*)d_out, N);
}

// Round 7
// 200.703 us; speedup vs baseline: 2.2471x; 1.1280x over previous
//
#include <hip/hip_runtime.h>

// ---------------- problem constants (match reference) ----------------
constexpr int F_IN = 256;
constexpr int H1 = 4, D1 = 32, F1 = H1 * D1;   // 128
constexpr int H2 = 1, D2 = 32, F2 = H2 * D2;   // 32
constexpr float NEG = 0.2f;

// CSR build params
constexpr int BW = 128;          // nodes per bucket
constexpr int NBUK_MAX = 512;    // >= ceil(N/BW) = 391
constexpr int CB = 128;          // coarse blocks

typedef short short8 __attribute__((ext_vector_type(8)));
typedef float f32x4 __attribute__((ext_vector_type(4)));

__device__ inline float bf2f(unsigned short u) {
    unsigned int x = ((unsigned int)u) << 16;
    return __builtin_bit_cast(float, x);
}
__device__ inline unsigned short f2bf(float f) {
    __bf16 h = (__bf16)f;                      // RNE
    return __builtin_bit_cast(unsigned short, h);
}

// ---------------- CSR build: bucketed two-level counting sort ----------------
// Phase 1: per-block LDS histogram over dst-buckets -> Hc[CB][nbuk]
__global__ __launch_bounds__(256) void chist(const int* __restrict__ dst,
                                             unsigned int* __restrict__ Hc,
                                             int E, int nbuk) {
    __shared__ unsigned int h[NBUK_MAX];
    int tid = threadIdx.x;
    for (int i = tid; i < nbuk; i += 256) h[i] = 0;
    __syncthreads();
    int epb = (E + CB - 1) / CB;
    int e0 = blockIdx.x * epb, e1 = min(e0 + epb, E);
    for (int e = e0 + tid; e < e1; e += 256)
        atomicAdd(&h[dst[e] / BW], 1u);
    __syncthreads();
    for (int i = tid; i < nbuk; i += 256) Hc[(size_t)blockIdx.x * nbuk + i] = h[i];
}

// Phase 2 (1 block, 512 thr): Bb[b][k] = prefix over blocks; S[k] = bucket starts
__global__ __launch_bounds__(512) void bscan(const unsigned int* __restrict__ Hc,
                                             unsigned int* __restrict__ Bb,
                                             unsigned int* __restrict__ S, int nbuk) {
    __shared__ unsigned int tot[NBUK_MAX];
    int t = threadIdx.x;
    unsigned int run = 0;
    if (t < nbuk) {
        for (int b = 0; b < CB; ++b) {
            Bb[(size_t)b * nbuk + t] = run;
            run += Hc[(size_t)b * nbuk + t];
        }
    }
    tot[t] = (t < nbuk) ? run : 0;
    __syncthreads();
    for (int o = 1; o < NBUK_MAX; o <<= 1) {
        unsigned int v = (t >= o) ? tot[t - o] : 0;
        __syncthreads();
        tot[t] += v;
        __syncthreads();
    }
    if (t < nbuk) S[t] = tot[t] - run;          // exclusive
    if (t == nbuk - 1) S[nbuk] = tot[t];        // == E
}

// Phase 3: coarse scatter of (src,dst) pairs into bucket-segmented, block-disjoint ranges
__global__ __launch_bounds__(256) void cscat(const int* __restrict__ src,
                                             const int* __restrict__ dst,
                                             const unsigned int* __restrict__ Bb,
                                             const unsigned int* __restrict__ S,
                                             int2* __restrict__ pairs, int E, int nbuk) {
    __shared__ unsigned int h[NBUK_MAX];
    int tid = threadIdx.x;
    for (int i = tid; i < nbuk; i += 256) h[i] = 0;
    __syncthreads();
    int epb = (E + CB - 1) / CB;
    int e0 = blockIdx.x * epb, e1 = min(e0 + epb, E);
    const unsigned int* bb = Bb + (size_t)blockIdx.x * nbuk;
    for (int e = e0 + tid; e < e1; e += 256) {
        int d = dst[e];
        int k = d / BW;
        unsigned int r = atomicAdd(&h[k], 1u);
        unsigned int p = S[k] + bb[k] + r;
        pairs[p] = make_int2(src[e], d);
    }
}

// Phase 4: per-bucket fine pass -> off[] and csr[] (coalesced-range writes)
__global__ __launch_bounds__(256) void fscat(const int2* __restrict__ pairs,
                                             const unsigned int* __restrict__ S,
                                             int* __restrict__ off, int* __restrict__ csr,
                                             int n, int E) {
    int k = blockIdx.x;
    int tid = threadIdx.x;
    unsigned int s0 = S[k], s1 = S[k + 1];
    __shared__ unsigned int cnt[BW];
    __shared__ unsigned int ex[BW];
    if (tid < BW) cnt[tid] = 0;
    __syncthreads();
    for (unsigned int i = s0 + tid; i < s1; i += 256)
        atomicAdd(&cnt[pairs[i].y - k * BW], 1u);
    __syncthreads();
    unsigned int orig = (tid < BW) ? cnt[tid] : 0;
    if (tid < BW) ex[tid] = orig;
    __syncthreads();
    for (int o = 1; o < BW; o <<= 1) {
        unsigned int v = (tid < BW && tid >= (unsigned)o) ? ex[tid - o] : 0;
        __syncthreads();
        if (tid < BW) ex[tid] += v;
        __syncthreads();
    }
    if (tid < BW) {
        ex[tid] -= orig;                        // exclusive within bucket
        int node = k * BW + tid;
        if (node < n) off[node] = (int)(s0 + ex[tid]);
    }
    if (tid < BW) cnt[tid] = 0;
    __syncthreads();
    for (unsigned int i = s0 + tid; i < s1; i += 256) {
        int2 pr = pairs[i];
        int loc = pr.y - k * BW;
        unsigned int r = atomicAdd(&cnt[loc], 1u);
        csr[s0 + ex[loc] + r] = pr.x;
    }
    if (k == 0 && tid == 0) off[n] = E;
}

// ---------------- W split: W[K][C] f32 -> Wh_t/Wl_t [C][K] bf16 hi/lo ----------------
__global__ void wsplit_kernel(const float* __restrict__ W,
                              unsigned short* __restrict__ Wh,
                              unsigned short* __restrict__ Wl, int K, int C) {
    int idx = blockIdx.x * 256 + threadIdx.x;
    if (idx >= K * C) return;
    int k = idx / C, c = idx % C;
    float v = W[idx];
    __bf16 h = (__bf16)v;
    float hv = (float)h;
    __bf16 lo = (__bf16)(v - hv);
    Wh[(size_t)c * K + k] = __builtin_bit_cast(unsigned short, h);
    Wl[(size_t)c * K + k] = __builtin_bit_cast(unsigned short, lo);
}

// ---------------- Layer-1 GEMM via split-bf16 MFMA; BM=32, X-prefetch ----------------
// Block: 32 rows x 128 cols, 4 waves; wave tile 16x64 (4 col frags).
__global__ __launch_bounds__(256) void gemm1_mfma(
    const float* __restrict__ X,
    const unsigned short* __restrict__ Wh,
    const unsigned short* __restrict__ Wl,
    unsigned short* __restrict__ outb, int n)
{
    const int lane = threadIdx.x & 63;
    const int wid  = threadIdx.x >> 6;
    const int wrow = (wid >> 1) * 16;       // 0 or 16
    const int wcol = (wid & 1) * 64;        // 0 or 64
    const int row0 = blockIdx.x * 32;
    const int l16  = lane & 15;
    const int khi  = lane >> 4;             // 0..3

    f32x4 acc[4];
#pragma unroll
    for (int ni = 0; ni < 4; ++ni) acc[ni] = f32x4{0.f, 0.f, 0.f, 0.f};

    int r = row0 + wrow + l16;
    int ar = r < n ? r : (n - 1);
    const float* ap = X + (size_t)ar * F_IN + khi * 8;
    int bc[4];
#pragma unroll
    for (int ni = 0; ni < 4; ++ni) bc[ni] = wcol + ni * 16 + l16;

    // prefetch ks=0 X fragment
    float4 xc0 = *(const float4*)ap;
    float4 xc1 = *(const float4*)(ap + 4);

#pragma unroll
    for (int ks = 0; ks < 8; ++ks) {
        float4 xn0, xn1;
        if (ks < 7) {                       // issue next X loads early (HBM latency)
            const float* apn = ap + (ks + 1) * 32;
            xn0 = *(const float4*)apn;
            xn1 = *(const float4*)(apn + 4);
        }

        const int kbase = ks * 32 + khi * 8;
        short8 bh[4], bl[4];
#pragma unroll
        for (int ni = 0; ni < 4; ++ni) {
            bh[ni] = *(const short8*)(Wh + (size_t)bc[ni] * F_IN + kbase);
            bl[ni] = *(const short8*)(Wl + (size_t)bc[ni] * F_IN + kbase);
        }

        float v[8] = {xc0.x, xc0.y, xc0.z, xc0.w, xc1.x, xc1.y, xc1.z, xc1.w};
        short8 ah, al;
#pragma unroll
        for (int j = 0; j < 8; ++j) {
            __bf16 h = (__bf16)v[j];
            float hv = (float)h;
            __bf16 lo = (__bf16)(v[j] - hv);
            ah[j] = __builtin_bit_cast(short, h);
            al[j] = __builtin_bit_cast(short, lo);
        }

#pragma unroll
        for (int ni = 0; ni < 4; ++ni) {
            acc[ni] = __builtin_amdgcn_mfma_f32_16x16x32_bf16(al, bh[ni], acc[ni], 0, 0, 0);
            acc[ni] = __builtin_amdgcn_mfma_f32_16x16x32_bf16(ah, bl[ni], acc[ni], 0, 0, 0);
            acc[ni] = __builtin_amdgcn_mfma_f32_16x16x32_bf16(ah, bh[ni], acc[ni], 0, 0, 0);
        }
        if (ks < 7) { xc0 = xn0; xc1 = xn1; }
    }

    int rbase = row0 + wrow + khi * 4;
#pragma unroll
    for (int rr = 0; rr < 4; ++rr) {
        int row = rbase + rr;
        if (row < n) {
#pragma unroll
            for (int ni = 0; ni < 4; ++ni)
                outb[(size_t)row * F1 + wcol + ni * 16 + l16] = f2bf(acc[ni][rr]);
        }
    }
}

// ---------------- Layer-2 GEMM via split-bf16 MFMA (IN=128, OUT=32), f32 out ----------------
__global__ __launch_bounds__(256) void gemm2_mfma(
    const float* __restrict__ X,
    const unsigned short* __restrict__ Wh,
    const unsigned short* __restrict__ Wl,
    float* __restrict__ out, int n)
{
    const int lane = threadIdx.x & 63;
    const int wid  = threadIdx.x >> 6;
    const int wrow = wid * 32;
    const int row0 = blockIdx.x * 128;
    const int l16  = lane & 15;
    const int khi  = lane >> 4;

    f32x4 acc[2][2];
#pragma unroll
    for (int mi = 0; mi < 2; ++mi)
#pragma unroll
        for (int ni = 0; ni < 2; ++ni) acc[mi][ni] = f32x4{0.f, 0.f, 0.f, 0.f};

    int ar[2];
#pragma unroll
    for (int mi = 0; mi < 2; ++mi) {
        int r = row0 + wrow + mi * 16 + l16;
        ar[mi] = r < n ? r : (n - 1);
    }
    int bc[2];
#pragma unroll
    for (int ni = 0; ni < 2; ++ni) bc[ni] = ni * 16 + l16;

#pragma unroll
    for (int ks = 0; ks < 4; ++ks) {
        const int kbase = ks * 32 + khi * 8;

        short8 ah[2], al[2];
#pragma unroll
        for (int mi = 0; mi < 2; ++mi) {
            const float* ap = X + (size_t)ar[mi] * F1 + kbase;
            float4 p0 = *(const float4*)ap;
            float4 p1 = *(const float4*)(ap + 4);
            float v[8] = {p0.x, p0.y, p0.z, p0.w, p1.x, p1.y, p1.z, p1.w};
#pragma unroll
            for (int j = 0; j < 8; ++j) {
                __bf16 h = (__bf16)v[j];
                float hv = (float)h;
                __bf16 lo = (__bf16)(v[j] - hv);
                ah[mi][j] = __builtin_bit_cast(short, h);
                al[mi][j] = __builtin_bit_cast(short, lo);
            }
        }

        short8 bh[2], bl[2];
#pragma unroll
        for (int ni = 0; ni < 2; ++ni) {
            bh[ni] = *(const short8*)(Wh + (size_t)bc[ni] * F1 + kbase);
            bl[ni] = *(const short8*)(Wl + (size_t)bc[ni] * F1 + kbase);
        }

#pragma unroll
        for (int mi = 0; mi < 2; ++mi)
#pragma unroll
            for (int ni = 0; ni < 2; ++ni) {
                acc[mi][ni] = __builtin_amdgcn_mfma_f32_16x16x32_bf16(al[mi], bh[ni], acc[mi][ni], 0, 0, 0);
                acc[mi][ni] = __builtin_amdgcn_mfma_f32_16x16x32_bf16(ah[mi], bl[ni], acc[mi][ni], 0, 0, 0);
                acc[mi][ni] = __builtin_amdgcn_mfma_f32_16x16x32_bf16(ah[mi], bh[ni], acc[mi][ni], 0, 0, 0);
            }
    }

#pragma unroll
    for (int mi = 0; mi < 2; ++mi) {
        int rbase = row0 + wrow + mi * 16 + khi * 4;
#pragma unroll
        for (int r2 = 0; r2 < 4; ++r2) {
            int row = rbase + r2;
            if (row < n) {
#pragma unroll
                for (int ni = 0; ni < 2; ++ni)
                    out[(size_t)row * F2 + ni * 16 + l16] = acc[mi][ni][r2];
            }
        }
    }
}

// ---------------- el/er pass over bf16 feat (layer 1) ----------------
template <int F, int H>
__global__ __launch_bounds__(256) void elr_bf16(const unsigned short* __restrict__ featb,
                                                const float* __restrict__ al,
                                                const float* __restrict__ ar,
                                                float* __restrict__ el,
                                                float* __restrict__ er, int n)
{
    constexpr int LPN = F / 4;       // lanes per node (32 for F=128)
    constexpr int NPW = 64 / LPN;
    int wid = (blockIdx.x * 256 + threadIdx.x) >> 6;
    int lane = threadIdx.x & 63;
    int node = wid * NPW + lane / LPN;
    int l2 = lane % LPN;
    int c0 = l2 * 4;
    if (node >= n) return;
    ushort4 u = *(const ushort4*)(featb + (size_t)node * F + c0);
    float f0 = bf2f(u.x), f1 = bf2f(u.y), f2 = bf2f(u.z), f3 = bf2f(u.w);
    float4 a = *(const float4*)(al + c0);
    float4 r = *(const float4*)(ar + c0);
    float pel = f0 * a.x + f1 * a.y + f2 * a.z + f3 * a.w;
    float per = f0 * r.x + f1 * r.y + f2 * r.z + f3 * r.w;
#pragma unroll
    for (int o = 1; o < 8; o <<= 1) {
        pel += __shfl_xor(pel, o);
        per += __shfl_xor(per, o);
    }
    if ((l2 & 7) == 0) {
        int h = c0 / 32;
        el[(size_t)node * H + h] = pel;
        er[(size_t)node * H + h] = per;
    }
}

// ---------------- el/er pass over f32 feat (layer 2) ----------------
template <int F, int H>
__global__ __launch_bounds__(256) void elr_kernel(const float* __restrict__ feat,
                                                  const float* __restrict__ al,
                                                  const float* __restrict__ ar,
                                                  float* __restrict__ el,
                                                  float* __restrict__ er, int n)
{
    constexpr int LPN = F / 2;
    constexpr int NPW = 64 / LPN;
    int wid = (blockIdx.x * 256 + threadIdx.x) >> 6;
    int lane = threadIdx.x & 63;
    int node = wid * NPW + lane / LPN;
    int l2 = lane % LPN;
    int c0 = l2 * 2;
    if (node >= n) return;
    float2 f = *(const float2*)(feat + (size_t)node * F + c0);
    float2 a = *(const float2*)(al + c0);
    float2 r = *(const float2*)(ar + c0);
    float pel = f.x * a.x + f.y * a.y;
    float per = f.x * r.x + f.y * r.y;
#pragma unroll
    for (int o = 1; o < 16; o <<= 1) {
        pel += __shfl_xor(pel, o);
        per += __shfl_xor(per, o);
    }
    if ((l2 & 15) == 0) {
        int h = c0 / 32;
        el[(size_t)node * H + h] = pel;
        er[(size_t)node * H + h] = per;
    }
}

// ---------------- Aggregation layer 1: bf16 gather, 8 edges in flight ----------------
__global__ __launch_bounds__(256) void agg1_kernel(
    const int* __restrict__ off, const int* __restrict__ csr_src,
    const unsigned short* __restrict__ featb, const float* __restrict__ el,
    const float* __restrict__ er, const float* __restrict__ b,
    float* __restrict__ out, int n)
{
    int wid = (blockIdx.x * 256 + threadIdx.x) >> 6;   // node
    int lane = threadIdx.x & 63;
    if (wid >= n) return;
    int c0 = (lane & 31) * 4;
    int h = (lane & 31) >> 3;
    int half = lane >> 5;
    float erv = er[(size_t)wid * H1 + h];
    float sw = 0.f;
    float4 acc = {0.f, 0.f, 0.f, 0.f};
    int jb = off[wid], je = off[wid + 1];
    int j = jb + half;
    for (; j + 6 < je; j += 8) {
        int s0 = csr_src[j];
        int s1 = csr_src[j + 2];
        int s2 = csr_src[j + 4];
        int s3 = csr_src[j + 6];
        ushort4 u0 = *(const ushort4*)(featb + (size_t)s0 * F1 + c0);
        ushort4 u1 = *(const ushort4*)(featb + (size_t)s1 * F1 + c0);
        ushort4 u2 = *(const ushort4*)(featb + (size_t)s2 * F1 + c0);
        ushort4 u3 = *(const ushort4*)(featb + (size_t)s3 * F1 + c0);
        float t0 = el[(size_t)s0 * H1 + h] + erv;
        float t1 = el[(size_t)s1 * H1 + h] + erv;
        float t2 = el[(size_t)s2 * H1 + h] + erv;
        float t3 = el[(size_t)s3 * H1 + h] + erv;
        t0 = t0 > 0.f ? t0 : NEG * t0;
        t1 = t1 > 0.f ? t1 : NEG * t1;
        t2 = t2 > 0.f ? t2 : NEG * t2;
        t3 = t3 > 0.f ? t3 : NEG * t3;
        float w0 = __expf(t0), w1 = __expf(t1), w2 = __expf(t2), w3 = __expf(t3);
        sw += (w0 + w1) + (w2 + w3);
        acc.x = fmaf(w0, bf2f(u0.x), fmaf(w1, bf2f(u1.x), fmaf(w2, bf2f(u2.x), fmaf(w3, bf2f(u3.x), acc.x))));
        acc.y = fmaf(w0, bf2f(u0.y), fmaf(w1, bf2f(u1.y), fmaf(w2, bf2f(u2.y), fmaf(w3, bf2f(u3.y), acc.y))));
        acc.z = fmaf(w0, bf2f(u0.z), fmaf(w1, bf2f(u1.z), fmaf(w2, bf2f(u2.z), fmaf(w3, bf2f(u3.z), acc.z))));
        acc.w = fmaf(w0, bf2f(u0.w), fmaf(w1, bf2f(u1.w), fmaf(w2, bf2f(u2.w), fmaf(w3, bf2f(u3.w), acc.w))));
    }
    for (; j < je; j += 2) {
        int s = csr_src[j];
        ushort4 u = *(const ushort4*)(featb + (size_t)s * F1 + c0);
        float t = el[(size_t)s * H1 + h] + erv;
        t = t > 0.f ? t : NEG * t;
        float w = __expf(t);
        sw += w;
        acc.x = fmaf(w, bf2f(u.x), acc.x);
        acc.y = fmaf(w, bf2f(u.y), acc.y);
        acc.z = fmaf(w, bf2f(u.z), acc.z);
        acc.w = fmaf(w, bf2f(u.w), acc.w);
    }
    acc.x += __shfl_xor(acc.x, 32);
    acc.y += __shfl_xor(acc.y, 32);
    acc.z += __shfl_xor(acc.z, 32);
    acc.w += __shfl_xor(acc.w, 32);
    sw    += __shfl_xor(sw, 32);
    if (half == 0) {
        float inv = 1.f / fmaxf(sw, 1e-16f);
        float4 bb = *(const float4*)(b + c0);
        float4 t = {acc.x * inv + bb.x, acc.y * inv + bb.y,
                    acc.z * inv + bb.z, acc.w * inv + bb.w};
        *(float4*)(out + (size_t)wid * F1 + c0) = t;
    }
}

// ---------------- Aggregation layer 2: f32 gather, 16 edges in flight ----------------
__global__ __launch_bounds__(256) void agg2_kernel(
    const int* __restrict__ off, const int* __restrict__ csr_src,
    const float* __restrict__ feat, const float* __restrict__ el,
    const float* __restrict__ er, const float* __restrict__ b,
    float* __restrict__ out, int n)
{
    int wid = (blockIdx.x * 256 + threadIdx.x) >> 6;   // node
    int lane = threadIdx.x & 63;
    if (wid >= n) return;
    int c0 = (lane & 7) * 4;
    int grp = lane >> 3;
    float erv = er[wid];
    float sw = 0.f;
    float4 acc = {0.f, 0.f, 0.f, 0.f};
    int jb = off[wid], je = off[wid + 1];
    int j = jb + grp;
    for (; j + 8 < je; j += 16) {
        int s0 = csr_src[j];
        int s1 = csr_src[j + 8];
        float4 f0 = *(const float4*)(feat + (size_t)s0 * F2 + c0);
        float4 f1 = *(const float4*)(feat + (size_t)s1 * F2 + c0);
        float t0 = el[s0] + erv;
        float t1 = el[s1] + erv;
        t0 = t0 > 0.f ? t0 : NEG * t0;
        t1 = t1 > 0.f ? t1 : NEG * t1;
        float w0 = __expf(t0);
        float w1 = __expf(t1);
        sw += w0 + w1;
        acc.x = fmaf(w0, f0.x, fmaf(w1, f1.x, acc.x));
        acc.y = fmaf(w0, f0.y, fmaf(w1, f1.y, acc.y));
        acc.z = fmaf(w0, f0.z, fmaf(w1, f1.z, acc.z));
        acc.w = fmaf(w0, f0.w, fmaf(w1, f1.w, acc.w));
    }
    for (; j < je; j += 8) {
        int s = csr_src[j];
        float4 f = *(const float4*)(feat + (size_t)s * F2 + c0);
        float t = el[s] + erv;
        t = t > 0.f ? t : NEG * t;
        float w = __expf(t);
        sw += w;
        acc.x = fmaf(w, f.x, acc.x);
        acc.y = fmaf(w, f.y, acc.y);
        acc.z = fmaf(w, f.z, acc.z);
        acc.w = fmaf(w, f.w, acc.w);
    }
#pragma unroll
    for (int o = 8; o < 64; o <<= 1) {
        acc.x += __shfl_xor(acc.x, o);
        acc.y += __shfl_xor(acc.y, o);
        acc.z += __shfl_xor(acc.z, o);
        acc.w += __shfl_xor(acc.w, o);
        sw    += __shfl_xor(sw, o);
    }
    if (lane < 8) {
        float inv = 1.f / fmaxf(sw, 1e-16f);
        float4 bb = *(const float4*)(b + c0);
        float4 t = {acc.x * inv + bb.x, acc.y * inv + bb.y,
                    acc.z * inv + bb.z, acc.w * inv + bb.w};
        *(float4*)(out + (size_t)wid * F2 + c0) = t;
    }
}

// ---------------- launch ----------------
extern "C" void kernel_launch(void* const* d_in, const int* in_sizes, int n_in,
                              void* d_out, int out_size, void* d_ws, size_t ws_size,
                              hipStream_t stream) {
    const float* x   = (const float*)d_in[0];
    const float* W1  = (const float*)d_in[1];
    const float* al1 = (const float*)d_in[2];
    const float* ar1 = (const float*)d_in[3];
    const float* b1  = (const float*)d_in[4];
    const float* W2  = (const float*)d_in[5];
    const float* al2 = (const float*)d_in[6];
    const float* ar2 = (const float*)d_in[7];
    const float* b2  = (const float*)d_in[8];
    const int*   src = (const int*)d_in[9];
    const int*   dst = (const int*)d_in[10];

    const int N = in_sizes[0] / F_IN;
    const int E = in_sizes[9];
    const int NBUK = (N + BW - 1) / BW;          // 391

    // workspace layout (256B-aligned regions)
    char* w = (char*)d_ws;
    size_t o = 0;
    auto alloc = [&](size_t bytes) { size_t cur = o; o += (bytes + 255) & ~255ULL; return cur; };
    int*   off   = (int*)  (w + alloc((size_t)(N + 1) * 4));
    int*   csr   = (int*)  (w + alloc((size_t)E * 4));
    int2*  pairs = (int2*) (w + alloc((size_t)E * 8));
    unsigned int* Hc = (unsigned int*)(w + alloc((size_t)CB * NBUK * 4));
    unsigned int* Bb = (unsigned int*)(w + alloc((size_t)CB * NBUK * 4));
    unsigned int* S  = (unsigned int*)(w + alloc((size_t)(NBUK + 1) * 4));
    unsigned short* feat1b = (unsigned short*)(w + alloc((size_t)N * F1 * 2));
    float* el1   = (float*)(w + alloc((size_t)N * H1 * 4));
    float* er1   = (float*)(w + alloc((size_t)N * H1 * 4));
    float* h1    = (float*)(w + alloc((size_t)N * F1 * 4));
    float* feat2 = (float*)(w + alloc((size_t)N * F2 * 4));
    float* el2   = (float*)(w + alloc((size_t)N * H2 * 4));
    float* er2   = (float*)(w + alloc((size_t)N * H2 * 4));
    unsigned short* W1h = (unsigned short*)(w + alloc((size_t)F_IN * F1 * 2));
    unsigned short* W1l = (unsigned short*)(w + alloc((size_t)F_IN * F1 * 2));
    unsigned short* W2h = (unsigned short*)(w + alloc((size_t)F1 * F2 * 2));
    unsigned short* W2l = (unsigned short*)(w + alloc((size_t)F1 * F2 * 2));
    (void)ws_size; (void)n_in; (void)out_size;

    // ---- CSR build: bucketed counting sort (no global atomics) ----
    chist<<<CB, 256, 0, stream>>>(dst, Hc, E, NBUK);
    bscan<<<1, 512, 0, stream>>>(Hc, Bb, S, NBUK);
    cscat<<<CB, 256, 0, stream>>>(src, dst, Bb, S, pairs, E, NBUK);
    fscat<<<NBUK, 256, 0, stream>>>(pairs, S, off, csr, N, E);

    // ---- weight splits ----
    wsplit_kernel<<<(F_IN * F1 + 255) / 256, 256, 0, stream>>>(W1, W1h, W1l, F_IN, F1);
    wsplit_kernel<<<(F1 * F2 + 255) / 256, 256, 0, stream>>>(W2, W2h, W2l, F1, F2);

    // ---- layer 1 ----
    gemm1_mfma<<<(N + 31) / 32, 256, 0, stream>>>(x, W1h, W1l, feat1b, N);
    elr_bf16<F1, H1><<<(N + 7) / 8, 256, 0, stream>>>(feat1b, al1, ar1, el1, er1, N);
    agg1_kernel<<<(N + 3) / 4, 256, 0, stream>>>(off, csr, feat1b, el1, er1, b1, h1, N);

    // ---- layer 2 ----
    gemm2_mfma<<<(N + 127) / 128, 256, 0, stream>>>(h1, W2h, W2l, feat2, N);
    elr_kernel<F2, H2><<<(N + 15) / 16, 256, 0, stream>>>(feat2, al2, ar2, el2, er2, N);
    agg2_kernel<<<(N + 3) / 4, 256, 0, stream>>>(off, csr, feat2, el2, er2, b2, (float*)d_out, N);
}

// Round 8
// 188.732 us; speedup vs baseline: 2.3896x; 1.0634x over previous
//
#include <hip/hip_runtime.h>

// ---------------- problem constants (match reference) ----------------
constexpr int F_IN = 256;
constexpr int H1 = 4, D1 = 32, F1 = H1 * D1;   // 128
constexpr int H2 = 1, D2 = 32, F2 = H2 * D2;   // 32
constexpr float NEG = 0.2f;

// CSR build params
constexpr int BW = 128;          // nodes per bucket
constexpr int NBUK_MAX = 512;    // >= ceil(N/BW) = 391
constexpr int CB = 128;          // coarse blocks

typedef short short8 __attribute__((ext_vector_type(8)));
typedef float f32x4 __attribute__((ext_vector_type(4)));

__device__ inline float bf2f(unsigned short u) {
    unsigned int x = ((unsigned int)u) << 16;
    return __builtin_bit_cast(float, x);
}
__device__ inline unsigned short f2bf(float f) {
    __bf16 h = (__bf16)f;                      // RNE
    return __builtin_bit_cast(unsigned short, h);
}

// ---------------- CSR build: bucketed two-level counting sort ----------------
__global__ __launch_bounds__(256) void chist(const int* __restrict__ dst,
                                             unsigned int* __restrict__ Hc,
                                             int E, int nbuk) {
    __shared__ unsigned int h[NBUK_MAX];
    int tid = threadIdx.x;
    for (int i = tid; i < nbuk; i += 256) h[i] = 0;
    __syncthreads();
    int epb = (E + CB - 1) / CB;
    int e0 = blockIdx.x * epb, e1 = min(e0 + epb, E);
    for (int e = e0 + tid; e < e1; e += 256)
        atomicAdd(&h[dst[e] / BW], 1u);
    __syncthreads();
    for (int i = tid; i < nbuk; i += 256) Hc[(size_t)blockIdx.x * nbuk + i] = h[i];
}

__global__ __launch_bounds__(512) void bscan(const unsigned int* __restrict__ Hc,
                                             unsigned int* __restrict__ Bb,
                                             unsigned int* __restrict__ S, int nbuk) {
    __shared__ unsigned int tot[NBUK_MAX];
    int t = threadIdx.x;
    unsigned int run = 0;
    if (t < nbuk) {
        for (int b = 0; b < CB; ++b) {
            Bb[(size_t)b * nbuk + t] = run;
            run += Hc[(size_t)b * nbuk + t];
        }
    }
    tot[t] = (t < nbuk) ? run : 0;
    __syncthreads();
    for (int o = 1; o < NBUK_MAX; o <<= 1) {
        unsigned int v = (t >= o) ? tot[t - o] : 0;
        __syncthreads();
        tot[t] += v;
        __syncthreads();
    }
    if (t < nbuk) S[t] = tot[t] - run;          // exclusive
    if (t == nbuk - 1) S[nbuk] = tot[t];        // == E
}

__global__ __launch_bounds__(256) void cscat(const int* __restrict__ src,
                                             const int* __restrict__ dst,
                                             const unsigned int* __restrict__ Bb,
                                             const unsigned int* __restrict__ S,
                                             int2* __restrict__ pairs, int E, int nbuk) {
    __shared__ unsigned int h[NBUK_MAX];
    int tid = threadIdx.x;
    for (int i = tid; i < nbuk; i += 256) h[i] = 0;
    __syncthreads();
    int epb = (E + CB - 1) / CB;
    int e0 = blockIdx.x * epb, e1 = min(e0 + epb, E);
    const unsigned int* bb = Bb + (size_t)blockIdx.x * nbuk;
    for (int e = e0 + tid; e < e1; e += 256) {
        int d = dst[e];
        int k = d / BW;
        unsigned int r = atomicAdd(&h[k], 1u);
        unsigned int p = S[k] + bb[k] + r;
        pairs[p] = make_int2(src[e], d);
    }
}

__global__ __launch_bounds__(256) void fscat(const int2* __restrict__ pairs,
                                             const unsigned int* __restrict__ S,
                                             int* __restrict__ off, int* __restrict__ csr,
                                             int n, int E) {
    int k = blockIdx.x;
    int tid = threadIdx.x;
    unsigned int s0 = S[k], s1 = S[k + 1];
    __shared__ unsigned int cnt[BW];
    __shared__ unsigned int ex[BW];
    if (tid < BW) cnt[tid] = 0;
    __syncthreads();
    for (unsigned int i = s0 + tid; i < s1; i += 256)
        atomicAdd(&cnt[pairs[i].y - k * BW], 1u);
    __syncthreads();
    unsigned int orig = (tid < BW) ? cnt[tid] : 0;
    if (tid < BW) ex[tid] = orig;
    __syncthreads();
    for (int o = 1; o < BW; o <<= 1) {
        unsigned int v = (tid < BW && tid >= (unsigned)o) ? ex[tid - o] : 0;
        __syncthreads();
        if (tid < BW) ex[tid] += v;
        __syncthreads();
    }
    if (tid < BW) {
        ex[tid] -= orig;                        // exclusive within bucket
        int node = k * BW + tid;
        if (node < n) off[node] = (int)(s0 + ex[tid]);
    }
    if (tid < BW) cnt[tid] = 0;
    __syncthreads();
    for (unsigned int i = s0 + tid; i < s1; i += 256) {
        int2 pr = pairs[i];
        int loc = pr.y - k * BW;
        unsigned int r = atomicAdd(&cnt[loc], 1u);
        csr[s0 + ex[loc] + r] = pr.x;
    }
    if (k == 0 && tid == 0) off[n] = E;
}

// ---------------- W split: W[K][C] f32 -> Wh_t/Wl_t [C][K] bf16 hi/lo ----------------
__global__ void wsplit_kernel(const float* __restrict__ W,
                              unsigned short* __restrict__ Wh,
                              unsigned short* __restrict__ Wl, int K, int C) {
    int idx = blockIdx.x * 256 + threadIdx.x;
    if (idx >= K * C) return;
    int k = idx / C, c = idx % C;
    float v = W[idx];
    __bf16 h = (__bf16)v;
    float hv = (float)h;
    __bf16 lo = (__bf16)(v - hv);
    Wh[(size_t)c * K + k] = __builtin_bit_cast(unsigned short, h);
    Wl[(size_t)c * K + k] = __builtin_bit_cast(unsigned short, lo);
}

// ---------------- Layer-1 GEMM: LDS-staged X (global_load_lds), split-bf16 MFMA ----------------
// Block: 32 rows x 128 cols, 4 waves in 2x2. LDS layout [kc][row]: 16B K-chunk kc (0..63)
// x 32 rows; staged linearly by global_load_lds (lane -> row within chunk pair),
// fragment ds_reads are 16 consecutive lanes at 16B stride -> conflict-free.
constexpr int BM1 = 32;
__global__ __launch_bounds__(256) void gemm1_mfma(
    const float* __restrict__ X,
    const unsigned short* __restrict__ Wh,
    const unsigned short* __restrict__ Wl,
    unsigned short* __restrict__ outb, int n)
{
    __shared__ float xs[64 * BM1 * 4];          // 32 KB
    const int tid  = threadIdx.x;
    const int lane = tid & 63;
    const int wid  = tid >> 6;
    const int wrow = (wid >> 1) * 16;           // 0 or 16
    const int wcol = (wid & 1) * 64;            // 0 or 64
    const int row0 = blockIdx.x * BM1;
    const int l16  = lane & 15;
    const int khi  = lane >> 4;                 // 0..3

    // ---- stage X tile: 64 chunk-columns, 2 chunks (1 KB) per wave-issue ----
    {
        int r = lane & 31;
        int sub = lane >> 5;                    // 0/1: which chunk of the pair
        int gr = row0 + r;
        gr = gr < n ? gr : (n - 1);
        const float* rowp = X + (size_t)gr * F_IN;
#pragma unroll
        for (int i = 0; i < 8; ++i) {
            int kc = wid * 16 + i * 2;          // uniform per wave
            const float* src = rowp + (kc + sub) * 4;
            float* dstf = &xs[kc * BM1 * 4];    // wave-uniform LDS base
            __builtin_amdgcn_global_load_lds(
                (const __attribute__((address_space(1))) unsigned int*)src,
                (__attribute__((address_space(3))) unsigned int*)dstf,
                16, 0, 0);
        }
    }
    asm volatile("s_waitcnt vmcnt(0)" ::: "memory");
    __syncthreads();

    f32x4 acc[4];
#pragma unroll
    for (int ni = 0; ni < 4; ++ni) acc[ni] = f32x4{0.f, 0.f, 0.f, 0.f};

    const int rt = wrow + l16;                  // row within tile
    int bc[4];
#pragma unroll
    for (int ni = 0; ni < 4; ++ni) bc[ni] = wcol + ni * 16 + l16;

#pragma unroll
    for (int ks = 0; ks < 8; ++ks) {
        const int kbase = ks * 32 + khi * 8;
        const int kc = ks * 8 + khi * 2;

        // W fragments from L2 (W is 128 KB total, L2-resident)
        short8 bh[4], bl[4];
#pragma unroll
        for (int ni = 0; ni < 4; ++ni) {
            bh[ni] = *(const short8*)(Wh + (size_t)bc[ni] * F_IN + kbase);
            bl[ni] = *(const short8*)(Wl + (size_t)bc[ni] * F_IN + kbase);
        }

        // X fragment from LDS: two conflict-free b128 reads
        float4 xa0 = *(const float4*)&xs[(kc + 0) * BM1 * 4 + rt * 4];
        float4 xa1 = *(const float4*)&xs[(kc + 1) * BM1 * 4 + rt * 4];
        float v[8] = {xa0.x, xa0.y, xa0.z, xa0.w, xa1.x, xa1.y, xa1.z, xa1.w};
        short8 ah, al;
#pragma unroll
        for (int j = 0; j < 8; ++j) {
            __bf16 h = (__bf16)v[j];
            float hv = (float)h;
            __bf16 lo = (__bf16)(v[j] - hv);
            ah[j] = __builtin_bit_cast(short, h);
            al[j] = __builtin_bit_cast(short, lo);
        }

#pragma unroll
        for (int ni = 0; ni < 4; ++ni) {
            acc[ni] = __builtin_amdgcn_mfma_f32_16x16x32_bf16(al, bh[ni], acc[ni], 0, 0, 0);
            acc[ni] = __builtin_amdgcn_mfma_f32_16x16x32_bf16(ah, bl[ni], acc[ni], 0, 0, 0);
            acc[ni] = __builtin_amdgcn_mfma_f32_16x16x32_bf16(ah, bh[ni], acc[ni], 0, 0, 0);
        }
    }

    int rbase = row0 + wrow + khi * 4;
#pragma unroll
    for (int rr = 0; rr < 4; ++rr) {
        int row = rbase + rr;
        if (row < n) {
#pragma unroll
            for (int ni = 0; ni < 4; ++ni)
                outb[(size_t)row * F1 + wcol + ni * 16 + l16] = f2bf(acc[ni][rr]);
        }
    }
}

// ---------------- Layer-2 GEMM via split-bf16 MFMA (IN=128, OUT=32), f32 out ----------------
__global__ __launch_bounds__(256) void gemm2_mfma(
    const float* __restrict__ X,
    const unsigned short* __restrict__ Wh,
    const unsigned short* __restrict__ Wl,
    float* __restrict__ out, int n)
{
    const int lane = threadIdx.x & 63;
    const int wid  = threadIdx.x >> 6;
    const int wrow = wid * 32;
    const int row0 = blockIdx.x * 128;
    const int l16  = lane & 15;
    const int khi  = lane >> 4;

    f32x4 acc[2][2];
#pragma unroll
    for (int mi = 0; mi < 2; ++mi)
#pragma unroll
        for (int ni = 0; ni < 2; ++ni) acc[mi][ni] = f32x4{0.f, 0.f, 0.f, 0.f};

    int ar[2];
#pragma unroll
    for (int mi = 0; mi < 2; ++mi) {
        int r = row0 + wrow + mi * 16 + l16;
        ar[mi] = r < n ? r : (n - 1);
    }
    int bc[2];
#pragma unroll
    for (int ni = 0; ni < 2; ++ni) bc[ni] = ni * 16 + l16;

#pragma unroll
    for (int ks = 0; ks < 4; ++ks) {
        const int kbase = ks * 32 + khi * 8;

        short8 ah[2], al[2];
#pragma unroll
        for (int mi = 0; mi < 2; ++mi) {
            const float* ap = X + (size_t)ar[mi] * F1 + kbase;
            float4 p0 = *(const float4*)ap;
            float4 p1 = *(const float4*)(ap + 4);
            float v[8] = {p0.x, p0.y, p0.z, p0.w, p1.x, p1.y, p1.z, p1.w};
#pragma unroll
            for (int j = 0; j < 8; ++j) {
                __bf16 h = (__bf16)v[j];
                float hv = (float)h;
                __bf16 lo = (__bf16)(v[j] - hv);
                ah[mi][j] = __builtin_bit_cast(short, h);
                al[mi][j] = __builtin_bit_cast(short, lo);
            }
        }

        short8 bh[2], bl[2];
#pragma unroll
        for (int ni = 0; ni < 2; ++ni) {
            bh[ni] = *(const short8*)(Wh + (size_t)bc[ni] * F1 + kbase);
            bl[ni] = *(const short8*)(Wl + (size_t)bc[ni] * F1 + kbase);
        }

#pragma unroll
        for (int mi = 0; mi < 2; ++mi)
#pragma unroll
            for (int ni = 0; ni < 2; ++ni) {
                acc[mi][ni] = __builtin_amdgcn_mfma_f32_16x16x32_bf16(al[mi], bh[ni], acc[mi][ni], 0, 0, 0);
                acc[mi][ni] = __builtin_amdgcn_mfma_f32_16x16x32_bf16(ah[mi], bl[ni], acc[mi][ni], 0, 0, 0);
                acc[mi][ni] = __builtin_amdgcn_mfma_f32_16x16x32_bf16(ah[mi], bh[ni], acc[mi][ni], 0, 0, 0);
            }
    }

#pragma unroll
    for (int mi = 0; mi < 2; ++mi) {
        int rbase = row0 + wrow + mi * 16 + khi * 4;
#pragma unroll
        for (int r2 = 0; r2 < 4; ++r2) {
            int row = rbase + r2;
            if (row < n) {
#pragma unroll
                for (int ni = 0; ni < 2; ++ni)
                    out[(size_t)row * F2 + ni * 16 + l16] = acc[mi][ni][r2];
            }
        }
    }
}

// ---------------- el/er pass over bf16 feat (layer 1) ----------------
template <int F, int H>
__global__ __launch_bounds__(256) void elr_bf16(const unsigned short* __restrict__ featb,
                                                const float* __restrict__ al,
                                                const float* __restrict__ ar,
                                                float* __restrict__ el,
                                                float* __restrict__ er, int n)
{
    constexpr int LPN = F / 4;
    constexpr int NPW = 64 / LPN;
    int wid = (blockIdx.x * 256 + threadIdx.x) >> 6;
    int lane = threadIdx.x & 63;
    int node = wid * NPW + lane / LPN;
    int l2 = lane % LPN;
    int c0 = l2 * 4;
    if (node >= n) return;
    ushort4 u = *(const ushort4*)(featb + (size_t)node * F + c0);
    float f0 = bf2f(u.x), f1 = bf2f(u.y), f2 = bf2f(u.z), f3 = bf2f(u.w);
    float4 a = *(const float4*)(al + c0);
    float4 r = *(const float4*)(ar + c0);
    float pel = f0 * a.x + f1 * a.y + f2 * a.z + f3 * a.w;
    float per = f0 * r.x + f1 * r.y + f2 * r.z + f3 * r.w;
#pragma unroll
    for (int o = 1; o < 8; o <<= 1) {
        pel += __shfl_xor(pel, o);
        per += __shfl_xor(per, o);
    }
    if ((l2 & 7) == 0) {
        int h = c0 / 32;
        el[(size_t)node * H + h] = pel;
        er[(size_t)node * H + h] = per;
    }
}

// ---------------- el/er pass over f32 feat (layer 2) ----------------
template <int F, int H>
__global__ __launch_bounds__(256) void elr_kernel(const float* __restrict__ feat,
                                                  const float* __restrict__ al,
                                                  const float* __restrict__ ar,
                                                  float* __restrict__ el,
                                                  float* __restrict__ er, int n)
{
    constexpr int LPN = F / 2;
    constexpr int NPW = 64 / LPN;
    int wid = (blockIdx.x * 256 + threadIdx.x) >> 6;
    int lane = threadIdx.x & 63;
    int node = wid * NPW + lane / LPN;
    int l2 = lane % LPN;
    int c0 = l2 * 2;
    if (node >= n) return;
    float2 f = *(const float2*)(feat + (size_t)node * F + c0);
    float2 a = *(const float2*)(al + c0);
    float2 r = *(const float2*)(ar + c0);
    float pel = f.x * a.x + f.y * a.y;
    float per = f.x * r.x + f.y * r.y;
#pragma unroll
    for (int o = 1; o < 16; o <<= 1) {
        pel += __shfl_xor(pel, o);
        per += __shfl_xor(per, o);
    }
    if ((l2 & 15) == 0) {
        int h = c0 / 32;
        el[(size_t)node * H + h] = pel;
        er[(size_t)node * H + h] = per;
    }
}

// ---------------- Aggregation layer 1: bf16 gather, 8 edges in flight ----------------
__global__ __launch_bounds__(256) void agg1_kernel(
    const int* __restrict__ off, const int* __restrict__ csr_src,
    const unsigned short* __restrict__ featb, const float* __restrict__ el,
    const float* __restrict__ er, const float* __restrict__ b,
    float* __restrict__ out, int n)
{
    int wid = (blockIdx.x * 256 + threadIdx.x) >> 6;   // node
    int lane = threadIdx.x & 63;
    if (wid >= n) return;
    int c0 = (lane & 31) * 4;
    int h = (lane & 31) >> 3;
    int half = lane >> 5;
    float erv = er[(size_t)wid * H1 + h];
    float sw = 0.f;
    float4 acc = {0.f, 0.f, 0.f, 0.f};
    int jb = off[wid], je = off[wid + 1];
    int j = jb + half;
    for (; j + 6 < je; j += 8) {
        int s0 = csr_src[j];
        int s1 = csr_src[j + 2];
        int s2 = csr_src[j + 4];
        int s3 = csr_src[j + 6];
        ushort4 u0 = *(const ushort4*)(featb + (size_t)s0 * F1 + c0);
        ushort4 u1 = *(const ushort4*)(featb + (size_t)s1 * F1 + c0);
        ushort4 u2 = *(const ushort4*)(featb + (size_t)s2 * F1 + c0);
        ushort4 u3 = *(const ushort4*)(featb + (size_t)s3 * F1 + c0);
        float t0 = el[(size_t)s0 * H1 + h] + erv;
        float t1 = el[(size_t)s1 * H1 + h] + erv;
        float t2 = el[(size_t)s2 * H1 + h] + erv;
        float t3 = el[(size_t)s3 * H1 + h] + erv;
        t0 = t0 > 0.f ? t0 : NEG * t0;
        t1 = t1 > 0.f ? t1 : NEG * t1;
        t2 = t2 > 0.f ? t2 : NEG * t2;
        t3 = t3 > 0.f ? t3 : NEG * t3;
        float w0 = __expf(t0), w1 = __expf(t1), w2 = __expf(t2), w3 = __expf(t3);
        sw += (w0 + w1) + (w2 + w3);
        acc.x = fmaf(w0, bf2f(u0.x), fmaf(w1, bf2f(u1.x), fmaf(w2, bf2f(u2.x), fmaf(w3, bf2f(u3.x), acc.x))));
        acc.y = fmaf(w0, bf2f(u0.y), fmaf(w1, bf2f(u1.y), fmaf(w2, bf2f(u2.y), fmaf(w3, bf2f(u3.y), acc.y))));
        acc.z = fmaf(w0, bf2f(u0.z), fmaf(w1, bf2f(u1.z), fmaf(w2, bf2f(u2.z), fmaf(w3, bf2f(u3.z), acc.z))));
        acc.w = fmaf(w0, bf2f(u0.w), fmaf(w1, bf2f(u1.w), fmaf(w2, bf2f(u2.w), fmaf(w3, bf2f(u3.w), acc.w))));
    }
    for (; j < je; j += 2) {
        int s = csr_src[j];
        ushort4 u = *(const ushort4*)(featb + (size_t)s * F1 + c0);
        float t = el[(size_t)s * H1 + h] + erv;
        t = t > 0.f ? t : NEG * t;
        float w = __expf(t);
        sw += w;
        acc.x = fmaf(w, bf2f(u.x), acc.x);
        acc.y = fmaf(w, bf2f(u.y), acc.y);
        acc.z = fmaf(w, bf2f(u.z), acc.z);
        acc.w = fmaf(w, bf2f(u.w), acc.w);
    }
    acc.x += __shfl_xor(acc.x, 32);
    acc.y += __shfl_xor(acc.y, 32);
    acc.z += __shfl_xor(acc.z, 32);
    acc.w += __shfl_xor(acc.w, 32);
    sw    += __shfl_xor(sw, 32);
    if (half == 0) {
        float inv = 1.f / fmaxf(sw, 1e-16f);
        float4 bb = *(const float4*)(b + c0);
        float4 t = {acc.x * inv + bb.x, acc.y * inv + bb.y,
                    acc.z * inv + bb.z, acc.w * inv + bb.w};
        *(float4*)(out + (size_t)wid * F1 + c0) = t;
    }
}

// ---------------- Aggregation layer 2: f32 gather, 16 edges in flight ----------------
__global__ __launch_bounds__(256) void agg2_kernel(
    const int* __restrict__ off, const int* __restrict__ csr_src,
    const float* __restrict__ feat, const float* __restrict__ el,
    const float* __restrict__ er, const float* __restrict__ b,
    float* __restrict__ out, int n)
{
    int wid = (blockIdx.x * 256 + threadIdx.x) >> 6;   // node
    int lane = threadIdx.x & 63;
    if (wid >= n) return;
    int c0 = (lane & 7) * 4;
    int grp = lane >> 3;
    float erv = er[wid];
    float sw = 0.f;
    float4 acc = {0.f, 0.f, 0.f, 0.f};
    int jb = off[wid], je = off[wid + 1];
    int j = jb + grp;
    for (; j + 8 < je; j += 16) {
        int s0 = csr_src[j];
        int s1 = csr_src[j + 8];
        float4 f0 = *(const float4*)(feat + (size_t)s0 * F2 + c0);
        float4 f1 = *(const float4*)(feat + (size_t)s1 * F2 + c0);
        float t0 = el[s0] + erv;
        float t1 = el[s1] + erv;
        t0 = t0 > 0.f ? t0 : NEG * t0;
        t1 = t1 > 0.f ? t1 : NEG * t1;
        float w0 = __expf(t0);
        float w1 = __expf(t1);
        sw += w0 + w1;
        acc.x = fmaf(w0, f0.x, fmaf(w1, f1.x, acc.x));
        acc.y = fmaf(w0, f0.y, fmaf(w1, f1.y, acc.y));
        acc.z = fmaf(w0, f0.z, fmaf(w1, f1.z, acc.z));
        acc.w = fmaf(w0, f0.w, fmaf(w1, f1.w, acc.w));
    }
    for (; j < je; j += 8) {
        int s = csr_src[j];
        float4 f = *(const float4*)(feat + (size_t)s * F2 + c0);
        float t = el[s] + erv;
        t = t > 0.f ? t : NEG * t;
        float w = __expf(t);
        sw += w;
        acc.x = fmaf(w, f.x, acc.x);
        acc.y = fmaf(w, f.y, acc.y);
        acc.z = fmaf(w, f.z, acc.z);
        acc.w = fmaf(w, f.w, acc.w);
    }
#pragma unroll
    for (int o = 8; o < 64; o <<= 1) {
        acc.x += __shfl_xor(acc.x, o);
        acc.y += __shfl_xor(acc.y, o);
        acc.z += __shfl_xor(acc.z, o);
        acc.w += __shfl_xor(acc.w, o);
        sw    += __shfl_xor(sw, o);
    }
    if (lane < 8) {
        float inv = 1.f / fmaxf(sw, 1e-16f);
        float4 bb = *(const float4*)(b + c0);
        float4 t = {acc.x * inv + bb.x, acc.y * inv + bb.y,
                    acc.z * inv + bb.z, acc.w * inv + bb.w};
        *(float4*)(out + (size_t)wid * F2 + c0) = t;
    }
}

// ---------------- launch ----------------
extern "C" void kernel_launch(void* const* d_in, const int* in_sizes, int n_in,
                              void* d_out, int out_size, void* d_ws, size_t ws_size,
                              hipStream_t stream) {
    const float* x   = (const float*)d_in[0];
    const float* W1  = (const float*)d_in[1];
    const float* al1 = (const float*)d_in[2];
    const float* ar1 = (const float*)d_in[3];
    const float* b1  = (const float*)d_in[4];
    const float* W2  = (const float*)d_in[5];
    const float* al2 = (const float*)d_in[6];
    const float* ar2 = (const float*)d_in[7];
    const float* b2  = (const float*)d_in[8];
    const int*   src = (const int*)d_in[9];
    const int*   dst = (const int*)d_in[10];

    const int N = in_sizes[0] / F_IN;
    const int E = in_sizes[9];
    const int NBUK = (N + BW - 1) / BW;          // 391

    // workspace layout (256B-aligned regions)
    char* w = (char*)d_ws;
    size_t o = 0;
    auto alloc = [&](size_t bytes) { size_t cur = o; o += (bytes + 255) & ~255ULL; return cur; };
    int*   off   = (int*)  (w + alloc((size_t)(N + 1) * 4));
    int*   csr   = (int*)  (w + alloc((size_t)E * 4));
    int2*  pairs = (int2*) (w + alloc((size_t)E * 8));
    unsigned int* Hc = (unsigned int*)(w + alloc((size_t)CB * NBUK * 4));
    unsigned int* Bb = (unsigned int*)(w + alloc((size_t)CB * NBUK * 4));
    unsigned int* S  = (unsigned int*)(w + alloc((size_t)(NBUK + 1) * 4));
    unsigned short* feat1b = (unsigned short*)(w + alloc((size_t)N * F1 * 2));
    float* el1   = (float*)(w + alloc((size_t)N * H1 * 4));
    float* er1   = (float*)(w + alloc((size_t)N * H1 * 4));
    float* h1    = (float*)(w + alloc((size_t)N * F1 * 4));
    float* feat2 = (float*)(w + alloc((size_t)N * F2 * 4));
    float* el2   = (float*)(w + alloc((size_t)N * H2 * 4));
    float* er2   = (float*)(w + alloc((size_t)N * H2 * 4));
    unsigned short* W1h = (unsigned short*)(w + alloc((size_t)F_IN * F1 * 2));
    unsigned short* W1l = (unsigned short*)(w + alloc((size_t)F_IN * F1 * 2));
    unsigned short* W2h = (unsigned short*)(w + alloc((size_t)F1 * F2 * 2));
    unsigned short* W2l = (unsigned short*)(w + alloc((size_t)F1 * F2 * 2));
    (void)ws_size; (void)n_in; (void)out_size;

    // ---- CSR build: bucketed counting sort (no global atomics) ----
    chist<<<CB, 256, 0, stream>>>(dst, Hc, E, NBUK);
    bscan<<<1, 512, 0, stream>>>(Hc, Bb, S, NBUK);
    cscat<<<CB, 256, 0, stream>>>(src, dst, Bb, S, pairs, E, NBUK);
    fscat<<<NBUK, 256, 0, stream>>>(pairs, S, off, csr, N, E);

    // ---- weight splits ----
    wsplit_kernel<<<(F_IN * F1 + 255) / 256, 256, 0, stream>>>(W1, W1h, W1l, F_IN, F1);
    wsplit_kernel<<<(F1 * F2 + 255) / 256, 256, 0, stream>>>(W2, W2h, W2l, F1, F2);

    // ---- layer 1 ----
    gemm1_mfma<<<(N + BM1 - 1) / BM1, 256, 0, stream>>>(x, W1h, W1l, feat1b, N);
    elr_bf16<F1, H1><<<(N + 7) / 8, 256, 0, stream>>>(feat1b, al1, ar1, el1, er1, N);
    agg1_kernel<<<(N + 3) / 4, 256, 0, stream>>>(off, csr, feat1b, el1, er1, b1, h1, N);

    // ---- layer 2 ----
    gemm2_mfma<<<(N + 127) / 128, 256, 0, stream>>>(h1, W2h, W2l, feat2, N);
    elr_kernel<F2, H2><<<(N + 15) / 16, 256, 0, stream>>>(feat2, al2, ar2, el2, er2, N);
    agg2_kernel<<<(N + 3) / 4, 256, 0, stream>>>(off, csr, feat2, el2, er2, b2, (float*)d_out, N);
}

// Round 9
// 155.144 us; speedup vs baseline: 2.9070x; 1.2165x over previous
//
#include <hip/hip_runtime.h>

// ---------------- problem constants (match reference) ----------------
constexpr int F_IN = 256;
constexpr int H1 = 4, D1 = 32, F1 = H1 * D1;   // 128
constexpr int H2 = 1, D2 = 32, F2 = H2 * D2;   // 32
constexpr float NEG = 0.2f;

// CSR build params
constexpr int BW = 128;          // nodes per bucket
constexpr int NBUK_MAX = 512;    // >= ceil(N/BW) = 391
constexpr int CB = 128;          // coarse blocks

typedef short short8 __attribute__((ext_vector_type(8)));
typedef float f32x4 __attribute__((ext_vector_type(4)));

__device__ inline float bf2f(unsigned short u) {
    unsigned int x = ((unsigned int)u) << 16;
    return __builtin_bit_cast(float, x);
}
__device__ inline unsigned short f2bf(float f) {
    __bf16 h = (__bf16)f;                      // RNE
    return __builtin_bit_cast(unsigned short, h);
}

// ---------------- CSR build: bucketed two-level counting sort ----------------
__global__ __launch_bounds__(256) void chist(const int* __restrict__ dst,
                                             unsigned int* __restrict__ Hc,
                                             int E, int nbuk) {
    __shared__ unsigned int h[NBUK_MAX];
    int tid = threadIdx.x;
    for (int i = tid; i < nbuk; i += 256) h[i] = 0;
    __syncthreads();
    int epb = (E + CB - 1) / CB;
    int e0 = blockIdx.x * epb, e1 = min(e0 + epb, E);
    for (int e = e0 + tid; e < e1; e += 256)
        atomicAdd(&h[dst[e] / BW], 1u);
    __syncthreads();
    for (int i = tid; i < nbuk; i += 256) Hc[(size_t)blockIdx.x * nbuk + i] = h[i];
}

__global__ __launch_bounds__(512) void bscan(const unsigned int* __restrict__ Hc,
                                             unsigned int* __restrict__ Bb,
                                             unsigned int* __restrict__ S, int nbuk) {
    __shared__ unsigned int tot[NBUK_MAX];
    int t = threadIdx.x;
    unsigned int run = 0;
    if (t < nbuk) {
        for (int b = 0; b < CB; ++b) {
            Bb[(size_t)b * nbuk + t] = run;
            run += Hc[(size_t)b * nbuk + t];
        }
    }
    tot[t] = (t < nbuk) ? run : 0;
    __syncthreads();
    for (int o = 1; o < NBUK_MAX; o <<= 1) {
        unsigned int v = (t >= o) ? tot[t - o] : 0;
        __syncthreads();
        tot[t] += v;
        __syncthreads();
    }
    if (t < nbuk) S[t] = tot[t] - run;          // exclusive
    if (t == nbuk - 1) S[nbuk] = tot[t];        // == E
}

__global__ __launch_bounds__(256) void cscat(const int* __restrict__ src,
                                             const int* __restrict__ dst,
                                             const unsigned int* __restrict__ Bb,
                                             const unsigned int* __restrict__ S,
                                             int2* __restrict__ pairs, int E, int nbuk) {
    __shared__ unsigned int h[NBUK_MAX];
    int tid = threadIdx.x;
    for (int i = tid; i < nbuk; i += 256) h[i] = 0;
    __syncthreads();
    int epb = (E + CB - 1) / CB;
    int e0 = blockIdx.x * epb, e1 = min(e0 + epb, E);
    const unsigned int* bb = Bb + (size_t)blockIdx.x * nbuk;
    for (int e = e0 + tid; e < e1; e += 256) {
        int d = dst[e];
        int k = d / BW;
        unsigned int r = atomicAdd(&h[k], 1u);
        unsigned int p = S[k] + bb[k] + r;
        pairs[p] = make_int2(src[e], d);
    }
}

__global__ __launch_bounds__(256) void fscat(const int2* __restrict__ pairs,
                                             const unsigned int* __restrict__ S,
                                             int* __restrict__ off, int* __restrict__ csr,
                                             int n, int E) {
    int k = blockIdx.x;
    int tid = threadIdx.x;
    unsigned int s0 = S[k], s1 = S[k + 1];
    __shared__ unsigned int cnt[BW];
    __shared__ unsigned int ex[BW];
    if (tid < BW) cnt[tid] = 0;
    __syncthreads();
    for (unsigned int i = s0 + tid; i < s1; i += 256)
        atomicAdd(&cnt[pairs[i].y - k * BW], 1u);
    __syncthreads();
    unsigned int orig = (tid < BW) ? cnt[tid] : 0;
    if (tid < BW) ex[tid] = orig;
    __syncthreads();
    for (int o = 1; o < BW; o <<= 1) {
        unsigned int v = (tid < BW && tid >= (unsigned)o) ? ex[tid - o] : 0;
        __syncthreads();
        if (tid < BW) ex[tid] += v;
        __syncthreads();
    }
    if (tid < BW) {
        ex[tid] -= orig;                        // exclusive within bucket
        int node = k * BW + tid;
        if (node < n) off[node] = (int)(s0 + ex[tid]);
    }
    if (tid < BW) cnt[tid] = 0;
    __syncthreads();
    for (unsigned int i = s0 + tid; i < s1; i += 256) {
        int2 pr = pairs[i];
        int loc = pr.y - k * BW;
        unsigned int r = atomicAdd(&cnt[loc], 1u);
        csr[s0 + ex[loc] + r] = pr.x;
    }
    if (k == 0 && tid == 0) off[n] = E;
}

// ---------------- W split + swizzle into MFMA B-fragment order ----------------
// out idx = ((ks*FC + fc)*64 + lane)*8 + j  <->  k = ks*32 + (lane>>4)*8 + j,
//                                                c = fc*16 + (lane&15)
// A wave's fragment load becomes base + lane*16B: fully coalesced.
__global__ void wsplit_swz(const float* __restrict__ W,
                           unsigned short* __restrict__ Wh,
                           unsigned short* __restrict__ Wl, int K, int C) {
    int idx = blockIdx.x * 256 + threadIdx.x;
    if (idx >= K * C) return;
    int j    = idx & 7;
    int lane = (idx >> 3) & 63;
    int t    = idx >> 9;
    int FC   = C >> 4;
    int fc   = t % FC, ks = t / FC;
    int k = ks * 32 + (lane >> 4) * 8 + j;
    int c = fc * 16 + (lane & 15);
    float v = W[(size_t)k * C + c];
    __bf16 h = (__bf16)v;
    float hv = (float)h;
    __bf16 lo = (__bf16)(v - hv);
    Wh[idx] = __builtin_bit_cast(unsigned short, h);
    Wl[idx] = __builtin_bit_cast(unsigned short, lo);
}

// ---------------- Layer-1 GEMM: LDS-staged X + coalesced swizzled-W, split-bf16 MFMA ----------------
constexpr int BM1 = 32;
__global__ __launch_bounds__(256) void gemm1_mfma(
    const float* __restrict__ X,
    const unsigned short* __restrict__ Wh,
    const unsigned short* __restrict__ Wl,
    unsigned short* __restrict__ outb, int n)
{
    __shared__ float xs[64 * BM1 * 4];          // 32 KB
    const int tid  = threadIdx.x;
    const int lane = tid & 63;
    const int wid  = tid >> 6;
    const int wrow = (wid >> 1) * 16;           // 0 or 16
    const int wcol = (wid & 1) * 64;            // 0 or 64
    const int wc16 = wcol >> 4;
    const int row0 = blockIdx.x * BM1;
    const int l16  = lane & 15;
    const int khi  = lane >> 4;                 // 0..3

    // ---- stage X tile (coalesced global_load_lds) ----
    {
        int r = lane & 31;
        int sub = lane >> 5;
        int gr = row0 + r;
        gr = gr < n ? gr : (n - 1);
        const float* rowp = X + (size_t)gr * F_IN;
#pragma unroll
        for (int i = 0; i < 8; ++i) {
            int kc = wid * 16 + i * 2;
            const float* src = rowp + (kc + sub) * 4;
            float* dstf = &xs[kc * BM1 * 4];
            __builtin_amdgcn_global_load_lds(
                (const __attribute__((address_space(1))) unsigned int*)src,
                (__attribute__((address_space(3))) unsigned int*)dstf,
                16, 0, 0);
        }
    }
    asm volatile("s_waitcnt vmcnt(0)" ::: "memory");
    __syncthreads();

    f32x4 acc[4];
#pragma unroll
    for (int ni = 0; ni < 4; ++ni) acc[ni] = f32x4{0.f, 0.f, 0.f, 0.f};

    const int rt = wrow + l16;

#pragma unroll
    for (int ks = 0; ks < 8; ++ks) {
        const int kc = ks * 8 + khi * 2;

        // W fragments: coalesced (lane-contiguous 16B) from swizzled layout
        short8 bh[4], bl[4];
#pragma unroll
        for (int ni = 0; ni < 4; ++ni) {
            int base = ((ks * 8 + wc16 + ni) * 64 + lane) * 8;
            bh[ni] = *(const short8*)(Wh + base);
            bl[ni] = *(const short8*)(Wl + base);
        }

        // X fragment from LDS
        float4 xa0 = *(const float4*)&xs[(kc + 0) * BM1 * 4 + rt * 4];
        float4 xa1 = *(const float4*)&xs[(kc + 1) * BM1 * 4 + rt * 4];
        float v[8] = {xa0.x, xa0.y, xa0.z, xa0.w, xa1.x, xa1.y, xa1.z, xa1.w};
        short8 ah, al;
#pragma unroll
        for (int j = 0; j < 8; ++j) {
            __bf16 h = (__bf16)v[j];
            float hv = (float)h;
            __bf16 lo = (__bf16)(v[j] - hv);
            ah[j] = __builtin_bit_cast(short, h);
            al[j] = __builtin_bit_cast(short, lo);
        }

#pragma unroll
        for (int ni = 0; ni < 4; ++ni) {
            acc[ni] = __builtin_amdgcn_mfma_f32_16x16x32_bf16(al, bh[ni], acc[ni], 0, 0, 0);
            acc[ni] = __builtin_amdgcn_mfma_f32_16x16x32_bf16(ah, bl[ni], acc[ni], 0, 0, 0);
            acc[ni] = __builtin_amdgcn_mfma_f32_16x16x32_bf16(ah, bh[ni], acc[ni], 0, 0, 0);
        }
    }

    int rbase = row0 + wrow + khi * 4;
#pragma unroll
    for (int rr = 0; rr < 4; ++rr) {
        int row = rbase + rr;
        if (row < n) {
#pragma unroll
            for (int ni = 0; ni < 4; ++ni)
                outb[(size_t)row * F1 + wcol + ni * 16 + l16] = f2bf(acc[ni][rr]);
        }
    }
}

// ---------------- Layer-2 GEMM: LDS-staged X + coalesced swizzled-W (IN=128, OUT=32) ----------------
constexpr int BM2 = 64;
__global__ __launch_bounds__(256) void gemm2_mfma(
    const float* __restrict__ X,
    const unsigned short* __restrict__ Wh,
    const unsigned short* __restrict__ Wl,
    float* __restrict__ out, int n)
{
    __shared__ float xs[32 * BM2 * 4];          // 32 KB
    const int tid  = threadIdx.x;
    const int lane = tid & 63;
    const int wid  = tid >> 6;
    const int wrow = wid * 16;
    const int row0 = blockIdx.x * BM2;
    const int l16  = lane & 15;
    const int khi  = lane >> 4;

    // ---- stage X tile: 32 chunk-columns of 16B x 64 rows; 1 KB per issue ----
    {
        int gr = row0 + lane;
        gr = gr < n ? gr : (n - 1);
        const float* rowp = X + (size_t)gr * F1;
#pragma unroll
        for (int i = 0; i < 8; ++i) {
            int kc = wid * 8 + i;
            const float* src = rowp + kc * 4;
            float* dstf = &xs[kc * BM2 * 4];
            __builtin_amdgcn_global_load_lds(
                (const __attribute__((address_space(1))) unsigned int*)src,
                (__attribute__((address_space(3))) unsigned int*)dstf,
                16, 0, 0);
        }
    }
    asm volatile("s_waitcnt vmcnt(0)" ::: "memory");
    __syncthreads();

    f32x4 acc[2];
#pragma unroll
    for (int ni = 0; ni < 2; ++ni) acc[ni] = f32x4{0.f, 0.f, 0.f, 0.f};

    const int rt = wrow + l16;

#pragma unroll
    for (int ks = 0; ks < 4; ++ks) {
        const int kc = ks * 8 + khi * 2;

        short8 bh[2], bl[2];
#pragma unroll
        for (int ni = 0; ni < 2; ++ni) {
            int base = ((ks * 2 + ni) * 64 + lane) * 8;
            bh[ni] = *(const short8*)(Wh + base);
            bl[ni] = *(const short8*)(Wl + base);
        }

        float4 xa0 = *(const float4*)&xs[(kc + 0) * BM2 * 4 + rt * 4];
        float4 xa1 = *(const float4*)&xs[(kc + 1) * BM2 * 4 + rt * 4];
        float v[8] = {xa0.x, xa0.y, xa0.z, xa0.w, xa1.x, xa1.y, xa1.z, xa1.w};
        short8 ah, al;
#pragma unroll
        for (int j = 0; j < 8; ++j) {
            __bf16 h = (__bf16)v[j];
            float hv = (float)h;
            __bf16 lo = (__bf16)(v[j] - hv);
            ah[j] = __builtin_bit_cast(short, h);
            al[j] = __builtin_bit_cast(short, lo);
        }

#pragma unroll
        for (int ni = 0; ni < 2; ++ni) {
            acc[ni] = __builtin_amdgcn_mfma_f32_16x16x32_bf16(al, bh[ni], acc[ni], 0, 0, 0);
            acc[ni] = __builtin_amdgcn_mfma_f32_16x16x32_bf16(ah, bl[ni], acc[ni], 0, 0, 0);
            acc[ni] = __builtin_amdgcn_mfma_f32_16x16x32_bf16(ah, bh[ni], acc[ni], 0, 0, 0);
        }
    }

    int rbase = row0 + wrow + khi * 4;
#pragma unroll
    for (int rr = 0; rr < 4; ++rr) {
        int row = rbase + rr;
        if (row < n) {
#pragma unroll
            for (int ni = 0; ni < 2; ++ni)
                out[(size_t)row * F2 + ni * 16 + l16] = acc[ni][rr];
        }
    }
}

// ---------------- el/er pass over bf16 feat (layer 1) ----------------
template <int F, int H>
__global__ __launch_bounds__(256) void elr_bf16(const unsigned short* __restrict__ featb,
                                                const float* __restrict__ al,
                                                const float* __restrict__ ar,
                                                float* __restrict__ el,
                                                float* __restrict__ er, int n)
{
    constexpr int LPN = F / 4;
    constexpr int NPW = 64 / LPN;
    int wid = (blockIdx.x * 256 + threadIdx.x) >> 6;
    int lane = threadIdx.x & 63;
    int node = wid * NPW + lane / LPN;
    int l2 = lane % LPN;
    int c0 = l2 * 4;
    if (node >= n) return;
    ushort4 u = *(const ushort4*)(featb + (size_t)node * F + c0);
    float f0 = bf2f(u.x), f1 = bf2f(u.y), f2 = bf2f(u.z), f3 = bf2f(u.w);
    float4 a = *(const float4*)(al + c0);
    float4 r = *(const float4*)(ar + c0);
    float pel = f0 * a.x + f1 * a.y + f2 * a.z + f3 * a.w;
    float per = f0 * r.x + f1 * r.y + f2 * r.z + f3 * r.w;
#pragma unroll
    for (int o = 1; o < 8; o <<= 1) {
        pel += __shfl_xor(pel, o);
        per += __shfl_xor(per, o);
    }
    if ((l2 & 7) == 0) {
        int h = c0 / 32;
        el[(size_t)node * H + h] = pel;
        er[(size_t)node * H + h] = per;
    }
}

// ---------------- el/er pass over f32 feat (layer 2) ----------------
template <int F, int H>
__global__ __launch_bounds__(256) void elr_kernel(const float* __restrict__ feat,
                                                  const float* __restrict__ al,
                                                  const float* __restrict__ ar,
                                                  float* __restrict__ el,
                                                  float* __restrict__ er, int n)
{
    constexpr int LPN = F / 2;
    constexpr int NPW = 64 / LPN;
    int wid = (blockIdx.x * 256 + threadIdx.x) >> 6;
    int lane = threadIdx.x & 63;
    int node = wid * NPW + lane / LPN;
    int l2 = lane % LPN;
    int c0 = l2 * 2;
    if (node >= n) return;
    float2 f = *(const float2*)(feat + (size_t)node * F + c0);
    float2 a = *(const float2*)(al + c0);
    float2 r = *(const float2*)(ar + c0);
    float pel = f.x * a.x + f.y * a.y;
    float per = f.x * r.x + f.y * r.y;
#pragma unroll
    for (int o = 1; o < 16; o <<= 1) {
        pel += __shfl_xor(pel, o);
        per += __shfl_xor(per, o);
    }
    if ((l2 & 15) == 0) {
        int h = c0 / 32;
        el[(size_t)node * H + h] = pel;
        er[(size_t)node * H + h] = per;
    }
}

// ---------------- Aggregation layer 1: bf16 gather, 8 edges in flight ----------------
__global__ __launch_bounds__(256) void agg1_kernel(
    const int* __restrict__ off, const int* __restrict__ csr_src,
    const unsigned short* __restrict__ featb, const float* __restrict__ el,
    const float* __restrict__ er, const float* __restrict__ b,
    float* __restrict__ out, int n)
{
    int wid = (blockIdx.x * 256 + threadIdx.x) >> 6;   // node
    int lane = threadIdx.x & 63;
    if (wid >= n) return;
    int c0 = (lane & 31) * 4;
    int h = (lane & 31) >> 3;
    int half = lane >> 5;
    float erv = er[(size_t)wid * H1 + h];
    float sw = 0.f;
    float4 acc = {0.f, 0.f, 0.f, 0.f};
    int jb = off[wid], je = off[wid + 1];
    int j = jb + half;
    for (; j + 6 < je; j += 8) {
        int s0 = csr_src[j];
        int s1 = csr_src[j + 2];
        int s2 = csr_src[j + 4];
        int s3 = csr_src[j + 6];
        ushort4 u0 = *(const ushort4*)(featb + (size_t)s0 * F1 + c0);
        ushort4 u1 = *(const ushort4*)(featb + (size_t)s1 * F1 + c0);
        ushort4 u2 = *(const ushort4*)(featb + (size_t)s2 * F1 + c0);
        ushort4 u3 = *(const ushort4*)(featb + (size_t)s3 * F1 + c0);
        float t0 = el[(size_t)s0 * H1 + h] + erv;
        float t1 = el[(size_t)s1 * H1 + h] + erv;
        float t2 = el[(size_t)s2 * H1 + h] + erv;
        float t3 = el[(size_t)s3 * H1 + h] + erv;
        t0 = t0 > 0.f ? t0 : NEG * t0;
        t1 = t1 > 0.f ? t1 : NEG * t1;
        t2 = t2 > 0.f ? t2 : NEG * t2;
        t3 = t3 > 0.f ? t3 : NEG * t3;
        float w0 = __expf(t0), w1 = __expf(t1), w2 = __expf(t2), w3 = __expf(t3);
        sw += (w0 + w1) + (w2 + w3);
        acc.x = fmaf(w0, bf2f(u0.x), fmaf(w1, bf2f(u1.x), fmaf(w2, bf2f(u2.x), fmaf(w3, bf2f(u3.x), acc.x))));
        acc.y = fmaf(w0, bf2f(u0.y), fmaf(w1, bf2f(u1.y), fmaf(w2, bf2f(u2.y), fmaf(w3, bf2f(u3.y), acc.y))));
        acc.z = fmaf(w0, bf2f(u0.z), fmaf(w1, bf2f(u1.z), fmaf(w2, bf2f(u2.z), fmaf(w3, bf2f(u3.z), acc.z))));
        acc.w = fmaf(w0, bf2f(u0.w), fmaf(w1, bf2f(u1.w), fmaf(w2, bf2f(u2.w), fmaf(w3, bf2f(u3.w), acc.w))));
    }
    for (; j < je; j += 2) {
        int s = csr_src[j];
        ushort4 u = *(const ushort4*)(featb + (size_t)s * F1 + c0);
        float t = el[(size_t)s * H1 + h] + erv;
        t = t > 0.f ? t : NEG * t;
        float w = __expf(t);
        sw += w;
        acc.x = fmaf(w, bf2f(u.x), acc.x);
        acc.y = fmaf(w, bf2f(u.y), acc.y);
        acc.z = fmaf(w, bf2f(u.z), acc.z);
        acc.w = fmaf(w, bf2f(u.w), acc.w);
    }
    acc.x += __shfl_xor(acc.x, 32);
    acc.y += __shfl_xor(acc.y, 32);
    acc.z += __shfl_xor(acc.z, 32);
    acc.w += __shfl_xor(acc.w, 32);
    sw    += __shfl_xor(sw, 32);
    if (half == 0) {
        float inv = 1.f / fmaxf(sw, 1e-16f);
        float4 bb = *(const float4*)(b + c0);
        float4 t = {acc.x * inv + bb.x, acc.y * inv + bb.y,
                    acc.z * inv + bb.z, acc.w * inv + bb.w};
        *(float4*)(out + (size_t)wid * F1 + c0) = t;
    }
}

// ---------------- Aggregation layer 2: f32 gather, 16 edges in flight ----------------
__global__ __launch_bounds__(256) void agg2_kernel(
    const int* __restrict__ off, const int* __restrict__ csr_src,
    const float* __restrict__ feat, const float* __restrict__ el,
    const float* __restrict__ er, const float* __restrict__ b,
    float* __restrict__ out, int n)
{
    int wid = (blockIdx.x * 256 + threadIdx.x) >> 6;   // node
    int lane = threadIdx.x & 63;
    if (wid >= n) return;
    int c0 = (lane & 7) * 4;
    int grp = lane >> 3;
    float erv = er[wid];
    float sw = 0.f;
    float4 acc = {0.f, 0.f, 0.f, 0.f};
    int jb = off[wid], je = off[wid + 1];
    int j = jb + grp;
    for (; j + 8 < je; j += 16) {
        int s0 = csr_src[j];
        int s1 = csr_src[j + 8];
        float4 f0 = *(const float4*)(feat + (size_t)s0 * F2 + c0);
        float4 f1 = *(const float4*)(feat + (size_t)s1 * F2 + c0);
        float t0 = el[s0] + erv;
        float t1 = el[s1] + erv;
        t0 = t0 > 0.f ? t0 : NEG * t0;
        t1 = t1 > 0.f ? t1 : NEG * t1;
        float w0 = __expf(t0);
        float w1 = __expf(t1);
        sw += w0 + w1;
        acc.x = fmaf(w0, f0.x, fmaf(w1, f1.x, acc.x));
        acc.y = fmaf(w0, f0.y, fmaf(w1, f1.y, acc.y));
        acc.z = fmaf(w0, f0.z, fmaf(w1, f1.z, acc.z));
        acc.w = fmaf(w0, f0.w, fmaf(w1, f1.w, acc.w));
    }
    for (; j < je; j += 8) {
        int s = csr_src[j];
        float4 f = *(const float4*)(feat + (size_t)s * F2 + c0);
        float t = el[s] + erv;
        t = t > 0.f ? t : NEG * t;
        float w = __expf(t);
        sw += w;
        acc.x = fmaf(w, f.x, acc.x);
        acc.y = fmaf(w, f.y, acc.y);
        acc.z = fmaf(w, f.z, acc.z);
        acc.w = fmaf(w, f.w, acc.w);
    }
#pragma unroll
    for (int o = 8; o < 64; o <<= 1) {
        acc.x += __shfl_xor(acc.x, o);
        acc.y += __shfl_xor(acc.y, o);
        acc.z += __shfl_xor(acc.z, o);
        acc.w += __shfl_xor(acc.w, o);
        sw    += __shfl_xor(sw, o);
    }
    if (lane < 8) {
        float inv = 1.f / fmaxf(sw, 1e-16f);
        float4 bb = *(const float4*)(b + c0);
        float4 t = {acc.x * inv + bb.x, acc.y * inv + bb.y,
                    acc.z * inv + bb.z, acc.w * inv + bb.w};
        *(float4*)(out + (size_t)wid * F2 + c0) = t;
    }
}

// ---------------- launch ----------------
extern "C" void kernel_launch(void* const* d_in, const int* in_sizes, int n_in,
                              void* d_out, int out_size, void* d_ws, size_t ws_size,
                              hipStream_t stream) {
    const float* x   = (const float*)d_in[0];
    const float* W1  = (const float*)d_in[1];
    const float* al1 = (const float*)d_in[2];
    const float* ar1 = (const float*)d_in[3];
    const float* b1  = (const float*)d_in[4];
    const float* W2  = (const float*)d_in[5];
    const float* al2 = (const float*)d_in[6];
    const float* ar2 = (const float*)d_in[7];
    const float* b2  = (const float*)d_in[8];
    const int*   src = (const int*)d_in[9];
    const int*   dst = (const int*)d_in[10];

    const int N = in_sizes[0] / F_IN;
    const int E = in_sizes[9];
    const int NBUK = (N + BW - 1) / BW;          // 391

    // workspace layout (256B-aligned regions)
    char* w = (char*)d_ws;
    size_t o = 0;
    auto alloc = [&](size_t bytes) { size_t cur = o; o += (bytes + 255) & ~255ULL; return cur; };
    int*   off   = (int*)  (w + alloc((size_t)(N + 1) * 4));
    int*   csr   = (int*)  (w + alloc((size_t)E * 4));
    int2*  pairs = (int2*) (w + alloc((size_t)E * 8));
    unsigned int* Hc = (unsigned int*)(w + alloc((size_t)CB * NBUK * 4));
    unsigned int* Bb = (unsigned int*)(w + alloc((size_t)CB * NBUK * 4));
    unsigned int* S  = (unsigned int*)(w + alloc((size_t)(NBUK + 1) * 4));
    unsigned short* feat1b = (unsigned short*)(w + alloc((size_t)N * F1 * 2));
    float* el1   = (float*)(w + alloc((size_t)N * H1 * 4));
    float* er1   = (float*)(w + alloc((size_t)N * H1 * 4));
    float* h1    = (float*)(w + alloc((size_t)N * F1 * 4));
    float* feat2 = (float*)(w + alloc((size_t)N * F2 * 4));
    float* el2   = (float*)(w + alloc((size_t)N * H2 * 4));
    float* er2   = (float*)(w + alloc((size_t)N * H2 * 4));
    unsigned short* W1h = (unsigned short*)(w + alloc((size_t)F_IN * F1 * 2));
    unsigned short* W1l = (unsigned short*)(w + alloc((size_t)F_IN * F1 * 2));
    unsigned short* W2h = (unsigned short*)(w + alloc((size_t)F1 * F2 * 2));
    unsigned short* W2l = (unsigned short*)(w + alloc((size_t)F1 * F2 * 2));
    (void)ws_size; (void)n_in; (void)out_size;

    // ---- CSR build: bucketed counting sort (no global atomics) ----
    chist<<<CB, 256, 0, stream>>>(dst, Hc, E, NBUK);
    bscan<<<1, 512, 0, stream>>>(Hc, Bb, S, NBUK);
    cscat<<<CB, 256, 0, stream>>>(src, dst, Bb, S, pairs, E, NBUK);
    fscat<<<NBUK, 256, 0, stream>>>(pairs, S, off, csr, N, E);

    // ---- weight split + swizzle ----
    wsplit_swz<<<(F_IN * F1 + 255) / 256, 256, 0, stream>>>(W1, W1h, W1l, F_IN, F1);
    wsplit_swz<<<(F1 * F2 + 255) / 256, 256, 0, stream>>>(W2, W2h, W2l, F1, F2);

    // ---- layer 1 ----
    gemm1_mfma<<<(N + BM1 - 1) / BM1, 256, 0, stream>>>(x, W1h, W1l, feat1b, N);
    elr_bf16<F1, H1><<<(N + 7) / 8, 256, 0, stream>>>(feat1b, al1, ar1, el1, er1, N);
    agg1_kernel<<<(N + 3) / 4, 256, 0, stream>>>(off, csr, feat1b, el1, er1, b1, h1, N);

    // ---- layer 2 ----
    gemm2_mfma<<<(N + BM2 - 1) / BM2, 256, 0, stream>>>(h1, W2h, W2l, feat2, N);
    elr_kernel<F2, H2><<<(N + 15) / 16, 256, 0, stream>>>(feat2, al2, ar2, el2, er2, N);
    agg2_kernel<<<(N + 3) / 4, 256, 0, stream>>>(off, csr, feat2, el2, er2, b2, (float*)d_out, N);
}

// Round 10
// 149.662 us; speedup vs baseline: 3.0135x; 1.0366x over previous
//
#include <hip/hip_runtime.h>

// ---------------- problem constants (match reference) ----------------
constexpr int F_IN = 256;
constexpr int H1 = 4, D1 = 32, F1 = H1 * D1;   // 128
constexpr int H2 = 1, D2 = 32, F2 = H2 * D2;   // 32
constexpr float NEG = 0.2f;

// CSR build params
constexpr int BW = 128;          // nodes per bucket (pow2)
constexpr int NBUK_MAX = 512;    // >= ceil(N/BW) = 391
constexpr int CB = 128;          // coarse blocks

typedef short short8 __attribute__((ext_vector_type(8)));
typedef float f32x4 __attribute__((ext_vector_type(4)));

__device__ inline float bf2f(unsigned short u) {
    unsigned int x = ((unsigned int)u) << 16;
    return __builtin_bit_cast(float, x);
}
__device__ inline unsigned short f2bf(float f) {
    __bf16 h = (__bf16)f;                      // RNE
    return __builtin_bit_cast(unsigned short, h);
}

// ---------------- CSR build: bucketed two-level counting sort ----------------
// Phase 1: per-block LDS histogram, written TRANSPOSED: HcT[bucket][block]
__global__ __launch_bounds__(256) void chist(const int* __restrict__ dst,
                                             unsigned int* __restrict__ HcT,
                                             int E, int nbuk) {
    __shared__ unsigned int h[NBUK_MAX];
    int tid = threadIdx.x;
    for (int i = tid; i < nbuk; i += 256) h[i] = 0;
    __syncthreads();
    int epb = (E + CB - 1) / CB;
    int e0 = blockIdx.x * epb, e1 = min(e0 + epb, E);
    for (int e = e0 + tid; e < e1; e += 256)
        atomicAdd(&h[dst[e] >> 7], 1u);
    __syncthreads();
    for (int i = tid; i < nbuk; i += 256) HcT[(size_t)i * CB + blockIdx.x] = h[i];
}

// Phase 2 (1 block, 512 thr): Bb[b][k] = prefix over blocks; S[k] = bucket starts
__global__ __launch_bounds__(512) void bscan(const unsigned int* __restrict__ HcT,
                                             unsigned int* __restrict__ Bb,
                                             unsigned int* __restrict__ S, int nbuk) {
    __shared__ unsigned int tot[NBUK_MAX];
    int t = threadIdx.x;
    unsigned int run = 0;
    if (t < nbuk) {
        const uint4* row = (const uint4*)(HcT + (size_t)t * CB);
#pragma unroll 8
        for (int b4 = 0; b4 < CB / 4; ++b4) {
            uint4 v = row[b4];
            int b = b4 * 4;
            Bb[(size_t)(b + 0) * nbuk + t] = run; run += v.x;
            Bb[(size_t)(b + 1) * nbuk + t] = run; run += v.y;
            Bb[(size_t)(b + 2) * nbuk + t] = run; run += v.z;
            Bb[(size_t)(b + 3) * nbuk + t] = run; run += v.w;
        }
    }
    tot[t] = (t < nbuk) ? run : 0;
    __syncthreads();
    for (int o = 1; o < NBUK_MAX; o <<= 1) {
        unsigned int v = (t >= o) ? tot[t - o] : 0;
        __syncthreads();
        tot[t] += v;
        __syncthreads();
    }
    if (t < nbuk) S[t] = tot[t] - run;          // exclusive
    if (t == nbuk - 1) S[nbuk] = tot[t];        // == E
}

// Phase 3: coarse scatter of packed (loc<<17 | src) into block-disjoint bucket ranges
__global__ __launch_bounds__(256) void cscat(const int* __restrict__ src,
                                             const int* __restrict__ dst,
                                             const unsigned int* __restrict__ Bb,
                                             const unsigned int* __restrict__ S,
                                             unsigned int* __restrict__ pairs, int E, int nbuk) {
    __shared__ unsigned int h[NBUK_MAX];
    int tid = threadIdx.x;
    for (int i = tid; i < nbuk; i += 256) h[i] = 0;
    __syncthreads();
    int epb = (E + CB - 1) / CB;
    int e0 = blockIdx.x * epb, e1 = min(e0 + epb, E);
    const unsigned int* bb = Bb + (size_t)blockIdx.x * nbuk;
    for (int e = e0 + tid; e < e1; e += 256) {
        int d = dst[e];
        int k = d >> 7;
        unsigned int r = atomicAdd(&h[k], 1u);
        unsigned int p = S[k] + bb[k] + r;
        pairs[p] = ((unsigned int)(d & 127) << 17) | (unsigned int)src[e];
    }
}

// Phase 4: per-bucket fine pass -> off[] and csr[]
__global__ __launch_bounds__(256) void fscat(const unsigned int* __restrict__ pairs,
                                             const unsigned int* __restrict__ S,
                                             int* __restrict__ off, int* __restrict__ csr,
                                             int n, int E) {
    int k = blockIdx.x;
    int tid = threadIdx.x;
    unsigned int s0 = S[k], s1 = S[k + 1];
    __shared__ unsigned int cnt[BW];
    __shared__ unsigned int ex[BW];
    if (tid < BW) cnt[tid] = 0;
    __syncthreads();
    for (unsigned int i = s0 + tid; i < s1; i += 256)
        atomicAdd(&cnt[pairs[i] >> 17], 1u);
    __syncthreads();
    unsigned int orig = (tid < BW) ? cnt[tid] : 0;
    if (tid < BW) ex[tid] = orig;
    __syncthreads();
    for (int o = 1; o < BW; o <<= 1) {
        unsigned int v = (tid < BW && tid >= (unsigned)o) ? ex[tid - o] : 0;
        __syncthreads();
        if (tid < BW) ex[tid] += v;
        __syncthreads();
    }
    if (tid < BW) {
        ex[tid] -= orig;                        // exclusive within bucket
        int node = k * BW + tid;
        if (node < n) off[node] = (int)(s0 + ex[tid]);
    }
    if (tid < BW) cnt[tid] = 0;
    __syncthreads();
    for (unsigned int i = s0 + tid; i < s1; i += 256) {
        unsigned int pr = pairs[i];
        int loc = pr >> 17;
        unsigned int r = atomicAdd(&cnt[loc], 1u);
        csr[s0 + ex[loc] + r] = (int)(pr & 0x1FFFFu);
    }
    if (k == 0 && tid == 0) off[n] = E;
}

// ---------------- W split+swizzle (both weights in one launch) ----------------
// out idx = ((ks*FC + fc)*64 + lane)*8 + j  <->  k = ks*32 + (lane>>4)*8 + j,
//                                                c = fc*16 + (lane&15)
__device__ inline void wsplit_one(const float* W, unsigned short* Wh, unsigned short* Wl,
                                  int idx, int C) {
    int j    = idx & 7;
    int lane = (idx >> 3) & 63;
    int t    = idx >> 9;
    int FC   = C >> 4;
    int fc   = t % FC, ks = t / FC;
    int k = ks * 32 + (lane >> 4) * 8 + j;
    int c = fc * 16 + (lane & 15);
    float v = W[(size_t)k * C + c];
    __bf16 h = (__bf16)v;
    float hv = (float)h;
    __bf16 lo = (__bf16)(v - hv);
    Wh[idx] = __builtin_bit_cast(unsigned short, h);
    Wl[idx] = __builtin_bit_cast(unsigned short, lo);
}
__global__ void wsplit_swz2(const float* __restrict__ W1, unsigned short* __restrict__ W1h,
                            unsigned short* __restrict__ W1l,
                            const float* __restrict__ W2, unsigned short* __restrict__ W2h,
                            unsigned short* __restrict__ W2l) {
    int idx = blockIdx.x * 256 + threadIdx.x;
    constexpr int N1 = F_IN * F1;
    if (idx < N1) wsplit_one(W1, W1h, W1l, idx, F1);
    else if (idx < N1 + F1 * F2) wsplit_one(W2, W2h, W2l, idx - N1, F2);
}

// ---------------- Layer-1 GEMM: LDS-staged X + swizzled W + fused el/er ----------------
constexpr int BM1 = 32;
__global__ __launch_bounds__(256) void gemm1_mfma(
    const float* __restrict__ X,
    const unsigned short* __restrict__ Wh,
    const unsigned short* __restrict__ Wl,
    const float* __restrict__ alv, const float* __restrict__ arv,
    unsigned short* __restrict__ outb,
    float* __restrict__ el, float* __restrict__ er, int n)
{
    __shared__ float xs[64 * BM1 * 4];          // 32 KB
    const int tid  = threadIdx.x;
    const int lane = tid & 63;
    const int wid  = tid >> 6;
    const int wrow = (wid >> 1) * 16;           // 0 or 16
    const int wcol = (wid & 1) * 64;            // 0 or 64
    const int wc16 = wcol >> 4;
    const int row0 = blockIdx.x * BM1;
    const int l16  = lane & 15;
    const int khi  = lane >> 4;                 // 0..3

    // ---- stage X tile (coalesced global_load_lds) ----
    {
        int r = lane & 31;
        int sub = lane >> 5;
        int gr = row0 + r;
        gr = gr < n ? gr : (n - 1);
        const float* rowp = X + (size_t)gr * F_IN;
#pragma unroll
        for (int i = 0; i < 8; ++i) {
            int kc = wid * 16 + i * 2;
            const float* srcp = rowp + (kc + sub) * 4;
            float* dstf = &xs[kc * BM1 * 4];
            __builtin_amdgcn_global_load_lds(
                (const __attribute__((address_space(1))) unsigned int*)srcp,
                (__attribute__((address_space(3))) unsigned int*)dstf,
                16, 0, 0);
        }
    }
    asm volatile("s_waitcnt vmcnt(0)" ::: "memory");
    __syncthreads();

    f32x4 acc[4];
#pragma unroll
    for (int ni = 0; ni < 4; ++ni) acc[ni] = f32x4{0.f, 0.f, 0.f, 0.f};

    const int rt = wrow + l16;

#pragma unroll
    for (int ks = 0; ks < 8; ++ks) {
        const int kc = ks * 8 + khi * 2;

        short8 bh[4], bl[4];
#pragma unroll
        for (int ni = 0; ni < 4; ++ni) {
            int base = ((ks * 8 + wc16 + ni) * 64 + lane) * 8;
            bh[ni] = *(const short8*)(Wh + base);
            bl[ni] = *(const short8*)(Wl + base);
        }

        float4 xa0 = *(const float4*)&xs[(kc + 0) * BM1 * 4 + rt * 4];
        float4 xa1 = *(const float4*)&xs[(kc + 1) * BM1 * 4 + rt * 4];
        float v[8] = {xa0.x, xa0.y, xa0.z, xa0.w, xa1.x, xa1.y, xa1.z, xa1.w};
        short8 ah, al8;
#pragma unroll
        for (int j = 0; j < 8; ++j) {
            __bf16 h = (__bf16)v[j];
            float hv = (float)h;
            __bf16 lo = (__bf16)(v[j] - hv);
            ah[j] = __builtin_bit_cast(short, h);
            al8[j] = __builtin_bit_cast(short, lo);
        }

#pragma unroll
        for (int ni = 0; ni < 4; ++ni) {
            acc[ni] = __builtin_amdgcn_mfma_f32_16x16x32_bf16(al8, bh[ni], acc[ni], 0, 0, 0);
            acc[ni] = __builtin_amdgcn_mfma_f32_16x16x32_bf16(ah, bl[ni], acc[ni], 0, 0, 0);
            acc[ni] = __builtin_amdgcn_mfma_f32_16x16x32_bf16(ah, bh[ni], acc[ni], 0, 0, 0);
        }
    }

    // ---- epilogue: store bf16 feat + fused el/er (per-head dots) ----
    const int hh0 = wcol >> 5;                  // first head this wave covers (0 or 2)
    float alr[2][2], arr[2][2];
#pragma unroll
    for (int t = 0; t < 2; ++t) {
        int head = hh0 + t;
        alr[t][0] = alv[head * 32 + l16];
        alr[t][1] = alv[head * 32 + 16 + l16];
        arr[t][0] = arv[head * 32 + l16];
        arr[t][1] = arv[head * 32 + 16 + l16];
    }

    int rbase = row0 + wrow + khi * 4;
#pragma unroll
    for (int rr = 0; rr < 4; ++rr) {
        int row = rbase + rr;
        bool ok = row < n;
        if (ok) {
#pragma unroll
            for (int ni = 0; ni < 4; ++ni)
                outb[(size_t)row * F1 + wcol + ni * 16 + l16] = f2bf(acc[ni][rr]);
        }
#pragma unroll
        for (int t = 0; t < 2; ++t) {
            float pel = acc[2 * t][rr] * alr[t][0] + acc[2 * t + 1][rr] * alr[t][1];
            float per = acc[2 * t][rr] * arr[t][0] + acc[2 * t + 1][rr] * arr[t][1];
#pragma unroll
            for (int o = 1; o < 16; o <<= 1) {
                pel += __shfl_xor(pel, o);
                per += __shfl_xor(per, o);
            }
            if (ok && l16 == 0) {
                el[(size_t)row * H1 + hh0 + t] = pel;
                er[(size_t)row * H1 + hh0 + t] = per;
            }
        }
    }
}

// ---------------- Layer-2 GEMM: LDS-staged X + swizzled W + fused el/er ----------------
constexpr int BM2 = 64;
__global__ __launch_bounds__(256) void gemm2_mfma(
    const float* __restrict__ X,
    const unsigned short* __restrict__ Wh,
    const unsigned short* __restrict__ Wl,
    const float* __restrict__ alv, const float* __restrict__ arv,
    float* __restrict__ out,
    float* __restrict__ el, float* __restrict__ er, int n)
{
    __shared__ float xs[32 * BM2 * 4];          // 32 KB
    const int tid  = threadIdx.x;
    const int lane = tid & 63;
    const int wid  = tid >> 6;
    const int wrow = wid * 16;
    const int row0 = blockIdx.x * BM2;
    const int l16  = lane & 15;
    const int khi  = lane >> 4;

    {
        int gr = row0 + lane;
        gr = gr < n ? gr : (n - 1);
        const float* rowp = X + (size_t)gr * F1;
#pragma unroll
        for (int i = 0; i < 8; ++i) {
            int kc = wid * 8 + i;
            const float* srcp = rowp + kc * 4;
            float* dstf = &xs[kc * BM2 * 4];
            __builtin_amdgcn_global_load_lds(
                (const __attribute__((address_space(1))) unsigned int*)srcp,
                (__attribute__((address_space(3))) unsigned int*)dstf,
                16, 0, 0);
        }
    }
    asm volatile("s_waitcnt vmcnt(0)" ::: "memory");
    __syncthreads();

    f32x4 acc[2];
#pragma unroll
    for (int ni = 0; ni < 2; ++ni) acc[ni] = f32x4{0.f, 0.f, 0.f, 0.f};

    const int rt = wrow + l16;

#pragma unroll
    for (int ks = 0; ks < 4; ++ks) {
        const int kc = ks * 8 + khi * 2;

        short8 bh[2], bl[2];
#pragma unroll
        for (int ni = 0; ni < 2; ++ni) {
            int base = ((ks * 2 + ni) * 64 + lane) * 8;
            bh[ni] = *(const short8*)(Wh + base);
            bl[ni] = *(const short8*)(Wl + base);
        }

        float4 xa0 = *(const float4*)&xs[(kc + 0) * BM2 * 4 + rt * 4];
        float4 xa1 = *(const float4*)&xs[(kc + 1) * BM2 * 4 + rt * 4];
        float v[8] = {xa0.x, xa0.y, xa0.z, xa0.w, xa1.x, xa1.y, xa1.z, xa1.w};
        short8 ah, al8;
#pragma unroll
        for (int j = 0; j < 8; ++j) {
            __bf16 h = (__bf16)v[j];
            float hv = (float)h;
            __bf16 lo = (__bf16)(v[j] - hv);
            ah[j] = __builtin_bit_cast(short, h);
            al8[j] = __builtin_bit_cast(short, lo);
        }

#pragma unroll
        for (int ni = 0; ni < 2; ++ni) {
            acc[ni] = __builtin_amdgcn_mfma_f32_16x16x32_bf16(al8, bh[ni], acc[ni], 0, 0, 0);
            acc[ni] = __builtin_amdgcn_mfma_f32_16x16x32_bf16(ah, bl[ni], acc[ni], 0, 0, 0);
            acc[ni] = __builtin_amdgcn_mfma_f32_16x16x32_bf16(ah, bh[ni], acc[ni], 0, 0, 0);
        }
    }

    float al0 = alv[l16], al1c = alv[16 + l16];
    float ar0 = arv[l16], ar1c = arv[16 + l16];

    int rbase = row0 + wrow + khi * 4;
#pragma unroll
    for (int rr = 0; rr < 4; ++rr) {
        int row = rbase + rr;
        bool ok = row < n;
        if (ok) {
#pragma unroll
            for (int ni = 0; ni < 2; ++ni)
                out[(size_t)row * F2 + ni * 16 + l16] = acc[ni][rr];
        }
        float pel = acc[0][rr] * al0 + acc[1][rr] * al1c;
        float per = acc[0][rr] * ar0 + acc[1][rr] * ar1c;
#pragma unroll
        for (int o = 1; o < 16; o <<= 1) {
            pel += __shfl_xor(pel, o);
            per += __shfl_xor(per, o);
        }
        if (ok && l16 == 0) {
            el[row] = pel;
            er[row] = per;
        }
    }
}

// ---------------- Aggregation layer 1: bf16 gather, 8 edges in flight ----------------
__global__ __launch_bounds__(256) void agg1_kernel(
    const int* __restrict__ off, const int* __restrict__ csr_src,
    const unsigned short* __restrict__ featb, const float* __restrict__ el,
    const float* __restrict__ er, const float* __restrict__ b,
    float* __restrict__ out, int n)
{
    int wid = (blockIdx.x * 256 + threadIdx.x) >> 6;   // node
    int lane = threadIdx.x & 63;
    if (wid >= n) return;
    int c0 = (lane & 31) * 4;
    int h = (lane & 31) >> 3;
    int half = lane >> 5;
    float erv = er[(size_t)wid * H1 + h];
    float sw = 0.f;
    float4 acc = {0.f, 0.f, 0.f, 0.f};
    int jb = off[wid], je = off[wid + 1];
    int j = jb + half;
    for (; j + 6 < je; j += 8) {
        int s0 = csr_src[j];
        int s1 = csr_src[j + 2];
        int s2 = csr_src[j + 4];
        int s3 = csr_src[j + 6];
        ushort4 u0 = *(const ushort4*)(featb + (size_t)s0 * F1 + c0);
        ushort4 u1 = *(const ushort4*)(featb + (size_t)s1 * F1 + c0);
        ushort4 u2 = *(const ushort4*)(featb + (size_t)s2 * F1 + c0);
        ushort4 u3 = *(const ushort4*)(featb + (size_t)s3 * F1 + c0);
        float t0 = el[(size_t)s0 * H1 + h] + erv;
        float t1 = el[(size_t)s1 * H1 + h] + erv;
        float t2 = el[(size_t)s2 * H1 + h] + erv;
        float t3 = el[(size_t)s3 * H1 + h] + erv;
        t0 = t0 > 0.f ? t0 : NEG * t0;
        t1 = t1 > 0.f ? t1 : NEG * t1;
        t2 = t2 > 0.f ? t2 : NEG * t2;
        t3 = t3 > 0.f ? t3 : NEG * t3;
        float w0 = __expf(t0), w1 = __expf(t1), w2 = __expf(t2), w3 = __expf(t3);
        sw += (w0 + w1) + (w2 + w3);
        acc.x = fmaf(w0, bf2f(u0.x), fmaf(w1, bf2f(u1.x), fmaf(w2, bf2f(u2.x), fmaf(w3, bf2f(u3.x), acc.x))));
        acc.y = fmaf(w0, bf2f(u0.y), fmaf(w1, bf2f(u1.y), fmaf(w2, bf2f(u2.y), fmaf(w3, bf2f(u3.y), acc.y))));
        acc.z = fmaf(w0, bf2f(u0.z), fmaf(w1, bf2f(u1.z), fmaf(w2, bf2f(u2.z), fmaf(w3, bf2f(u3.z), acc.z))));
        acc.w = fmaf(w0, bf2f(u0.w), fmaf(w1, bf2f(u1.w), fmaf(w2, bf2f(u2.w), fmaf(w3, bf2f(u3.w), acc.w))));
    }
    for (; j < je; j += 2) {
        int s = csr_src[j];
        ushort4 u = *(const ushort4*)(featb + (size_t)s * F1 + c0);
        float t = el[(size_t)s * H1 + h] + erv;
        t = t > 0.f ? t : NEG * t;
        float w = __expf(t);
        sw += w;
        acc.x = fmaf(w, bf2f(u.x), acc.x);
        acc.y = fmaf(w, bf2f(u.y), acc.y);
        acc.z = fmaf(w, bf2f(u.z), acc.z);
        acc.w = fmaf(w, bf2f(u.w), acc.w);
    }
    acc.x += __shfl_xor(acc.x, 32);
    acc.y += __shfl_xor(acc.y, 32);
    acc.z += __shfl_xor(acc.z, 32);
    acc.w += __shfl_xor(acc.w, 32);
    sw    += __shfl_xor(sw, 32);
    if (half == 0) {
        float inv = 1.f / fmaxf(sw, 1e-16f);
        float4 bb = *(const float4*)(b + c0);
        float4 t = {acc.x * inv + bb.x, acc.y * inv + bb.y,
                    acc.z * inv + bb.z, acc.w * inv + bb.w};
        *(float4*)(out + (size_t)wid * F1 + c0) = t;
    }
}

// ---------------- Aggregation layer 2: f32 gather, 16 edges in flight ----------------
__global__ __launch_bounds__(256) void agg2_kernel(
    const int* __restrict__ off, const int* __restrict__ csr_src,
    const float* __restrict__ feat, const float* __restrict__ el,
    const float* __restrict__ er, const float* __restrict__ b,
    float* __restrict__ out, int n)
{
    int wid = (blockIdx.x * 256 + threadIdx.x) >> 6;   // node
    int lane = threadIdx.x & 63;
    if (wid >= n) return;
    int c0 = (lane & 7) * 4;
    int grp = lane >> 3;
    float erv = er[wid];
    float sw = 0.f;
    float4 acc = {0.f, 0.f, 0.f, 0.f};
    int jb = off[wid], je = off[wid + 1];
    int j = jb + grp;
    for (; j + 8 < je; j += 16) {
        int s0 = csr_src[j];
        int s1 = csr_src[j + 8];
        float4 f0 = *(const float4*)(feat + (size_t)s0 * F2 + c0);
        float4 f1 = *(const float4*)(feat + (size_t)s1 * F2 + c0);
        float t0 = el[s0] + erv;
        float t1 = el[s1] + erv;
        t0 = t0 > 0.f ? t0 : NEG * t0;
        t1 = t1 > 0.f ? t1 : NEG * t1;
        float w0 = __expf(t0);
        float w1 = __expf(t1);
        sw += w0 + w1;
        acc.x = fmaf(w0, f0.x, fmaf(w1, f1.x, acc.x));
        acc.y = fmaf(w0, f0.y, fmaf(w1, f1.y, acc.y));
        acc.z = fmaf(w0, f0.z, fmaf(w1, f1.z, acc.z));
        acc.w = fmaf(w0, f0.w, fmaf(w1, f1.w, acc.w));
    }
    for (; j < je; j += 8) {
        int s = csr_src[j];
        float4 f = *(const float4*)(feat + (size_t)s * F2 + c0);
        float t = el[s] + erv;
        t = t > 0.f ? t : NEG * t;
        float w = __expf(t);
        sw += w;
        acc.x = fmaf(w, f.x, acc.x);
        acc.y = fmaf(w, f.y, acc.y);
        acc.z = fmaf(w, f.z, acc.z);
        acc.w = fmaf(w, f.w, acc.w);
    }
#pragma unroll
    for (int o = 8; o < 64; o <<= 1) {
        acc.x += __shfl_xor(acc.x, o);
        acc.y += __shfl_xor(acc.y, o);
        acc.z += __shfl_xor(acc.z, o);
        acc.w += __shfl_xor(acc.w, o);
        sw    += __shfl_xor(sw, o);
    }
    if (lane < 8) {
        float inv = 1.f / fmaxf(sw, 1e-16f);
        float4 bb = *(const float4*)(b + c0);
        float4 t = {acc.x * inv + bb.x, acc.y * inv + bb.y,
                    acc.z * inv + bb.z, acc.w * inv + bb.w};
        *(float4*)(out + (size_t)wid * F2 + c0) = t;
    }
}

// ---------------- launch ----------------
extern "C" void kernel_launch(void* const* d_in, const int* in_sizes, int n_in,
                              void* d_out, int out_size, void* d_ws, size_t ws_size,
                              hipStream_t stream) {
    const float* x   = (const float*)d_in[0];
    const float* W1  = (const float*)d_in[1];
    const float* al1 = (const float*)d_in[2];
    const float* ar1 = (const float*)d_in[3];
    const float* b1  = (const float*)d_in[4];
    const float* W2  = (const float*)d_in[5];
    const float* al2 = (const float*)d_in[6];
    const float* ar2 = (const float*)d_in[7];
    const float* b2  = (const float*)d_in[8];
    const int*   src = (const int*)d_in[9];
    const int*   dst = (const int*)d_in[10];

    const int N = in_sizes[0] / F_IN;
    const int E = in_sizes[9];
    const int NBUK = (N + BW - 1) / BW;          // 391

    // workspace layout (256B-aligned regions)
    char* w = (char*)d_ws;
    size_t o = 0;
    auto alloc = [&](size_t bytes) { size_t cur = o; o += (bytes + 255) & ~255ULL; return cur; };
    int*   off   = (int*)  (w + alloc((size_t)(N + 1) * 4));
    int*   csr   = (int*)  (w + alloc((size_t)E * 4));
    unsigned int* pairs = (unsigned int*)(w + alloc((size_t)E * 4));
    unsigned int* HcT = (unsigned int*)(w + alloc((size_t)CB * NBUK * 4));
    unsigned int* Bb  = (unsigned int*)(w + alloc((size_t)CB * NBUK * 4));
    unsigned int* S   = (unsigned int*)(w + alloc((size_t)(NBUK + 1) * 4));
    unsigned short* feat1b = (unsigned short*)(w + alloc((size_t)N * F1 * 2));
    float* el1   = (float*)(w + alloc((size_t)N * H1 * 4));
    float* er1   = (float*)(w + alloc((size_t)N * H1 * 4));
    float* h1    = (float*)(w + alloc((size_t)N * F1 * 4));
    float* feat2 = (float*)(w + alloc((size_t)N * F2 * 4));
    float* el2   = (float*)(w + alloc((size_t)N * H2 * 4));
    float* er2   = (float*)(w + alloc((size_t)N * H2 * 4));
    unsigned short* W1h = (unsigned short*)(w + alloc((size_t)F_IN * F1 * 2));
    unsigned short* W1l = (unsigned short*)(w + alloc((size_t)F_IN * F1 * 2));
    unsigned short* W2h = (unsigned short*)(w + alloc((size_t)F1 * F2 * 2));
    unsigned short* W2l = (unsigned short*)(w + alloc((size_t)F1 * F2 * 2));
    (void)ws_size; (void)n_in; (void)out_size;

    // ---- CSR build: bucketed counting sort (no global atomics) ----
    chist<<<CB, 256, 0, stream>>>(dst, HcT, E, NBUK);
    bscan<<<1, 512, 0, stream>>>(HcT, Bb, S, NBUK);
    cscat<<<CB, 256, 0, stream>>>(src, dst, Bb, S, pairs, E, NBUK);
    fscat<<<NBUK, 256, 0, stream>>>(pairs, S, off, csr, N, E);

    // ---- weight split + swizzle (single launch) ----
    wsplit_swz2<<<(F_IN * F1 + F1 * F2 + 255) / 256, 256, 0, stream>>>(
        W1, W1h, W1l, W2, W2h, W2l);

    // ---- layer 1 ----
    gemm1_mfma<<<(N + BM1 - 1) / BM1, 256, 0, stream>>>(
        x, W1h, W1l, al1, ar1, feat1b, el1, er1, N);
    agg1_kernel<<<(N + 3) / 4, 256, 0, stream>>>(off, csr, feat1b, el1, er1, b1, h1, N);

    // ---- layer 2 ----
    gemm2_mfma<<<(N + BM2 - 1) / BM2, 256, 0, stream>>>(
        h1, W2h, W2l, al2, ar2, feat2, el2, er2, N);
    agg2_kernel<<<(N + 3) / 4, 256, 0, stream>>>(off, csr, feat2, el2, er2, b2, (float*)d_out, N);
}